// Round 2
// baseline (492.208 us; speedup 1.0000x reference)
//
#include <hip/hip_runtime.h>
#include <cstddef>

// Problem constants (fixed by setup_inputs)
static constexpr int Wd  = 256;   // sequence length (width)
static constexpr int NBd = 128;   // batch = hn*bs
static constexpr int Cd  = 128;   // channels
static constexpr int BSd = 2;     // bs
static constexpr int HNd = 64;    // hn
static constexpr size_t SEQF = (size_t)Wd * NBd * Cd;  // 4,194,304 elements

typedef __attribute__((ext_vector_type(8))) short bf16x8;
typedef __attribute__((ext_vector_type(4))) short bf16x4;
typedef __attribute__((ext_vector_type(4))) float f32x4;
typedef __attribute__((ext_vector_type(2))) float f32x2;

__device__ inline short f2bf(float f) {
  union { float f; unsigned u; } v; v.f = f;
  return (short)((v.u + 0x7FFFu + ((v.u >> 16) & 1u)) >> 16);
}

// ---------------- fused to_seq + LayerNorm ----------------
// feat (bs,c,hn,w) -> seq fp32 (w,n,c) AND ln(seq) bf16. grid (8 wtiles, 256 z).
__global__ __launch_bounds__(256) void k_to_seq_ln(
    const float* __restrict__ fA, const float* __restrict__ fB,
    float* __restrict__ seqA, float* __restrict__ seqB,
    short* __restrict__ lnA, short* __restrict__ lnB,
    const float* __restrict__ g, const float* __restrict__ bb) {
  __shared__ float red[2][8][33];
  __shared__ float mv[2][32];
  const int z = blockIdx.y;
  const float* feat = (z < 128) ? fA : fB;
  float* seq = (z < 128) ? seqA : seqB;
  short* lno = (z < 128) ? lnA : lnB;
  const int hb = z & 127;
  const int h = hb >> 1, b = hb & 1;
  const int n = h * BSd + b;
  const int w0 = blockIdx.x * 32;
  const int t = threadIdx.x;
  const int wl = t & 31, cg = t >> 5, c0 = cg * 16;
  float v[16];
  float s1 = 0.f, s2 = 0.f;
#pragma unroll
  for (int r = 0; r < 16; ++r) {
    v[r] = feat[(((size_t)b * Cd + c0 + r) * HNd + h) * Wd + w0 + wl];
    s1 += v[r]; s2 += v[r] * v[r];
  }
  red[0][cg][wl] = s1; red[1][cg][wl] = s2;
  __syncthreads();
  if (t < 32) {
    float a1 = 0.f, a2 = 0.f;
#pragma unroll
    for (int k = 0; k < 8; ++k) { a1 += red[0][k][t]; a2 += red[1][k][t]; }
    float mean = a1 * (1.0f / Cd);
    float var = a2 * (1.0f / Cd) - mean * mean;
    mv[0][t] = mean; mv[1][t] = rsqrtf(var + 1e-5f);
  }
  __syncthreads();
  const float mean = mv[0][wl], rstd = mv[1][wl];
  float* so = &seq[((size_t)(w0 + wl) * NBd + n) * Cd + c0];
  short* bo_ = &lno[((size_t)(w0 + wl) * NBd + n) * Cd + c0];
#pragma unroll
  for (int r = 0; r < 16; ++r) so[r] = v[r];
#pragma unroll
  for (int r = 0; r < 16; ++r)
    bo_[r] = f2bf((v[r] - mean) * rstd * g[c0 + r] + bb[c0 + r]);
}

// ---------------- from_seq: merged for both tensors ----------------
__global__ __launch_bounds__(256) void k_from_seq2(const float* __restrict__ seqA,
                                                   const float* __restrict__ seqB,
                                                   float* __restrict__ featA,
                                                   float* __restrict__ featB) {
  __shared__ float tile[32][33];
  int wi0 = blockIdx.x * 32, ci0 = blockIdx.y * 32;
  int z = blockIdx.z;
  const float* seq = (z < 128) ? seqA : seqB;
  float* feat = (z < 128) ? featA : featB;
  int hb = z & 127;
  int h = hb >> 1, b = hb & 1;
  int n = h * BSd + b;
  int tx = threadIdx.x, ty = threadIdx.y;
#pragma unroll
  for (int r = 0; r < 4; ++r) {
    int wi = wi0 + ty + r * 8;
    tile[ty + r * 8][tx] = seq[((size_t)wi * NBd + n) * Cd + ci0 + tx];
  }
  __syncthreads();
#pragma unroll
  for (int r = 0; r < 4; ++r) {
    int ci = ci0 + ty + r * 8;
    feat[(((size_t)b * Cd + ci) * HNd + h) * Wd + wi0 + tx] = tile[tx][ty + r * 8];
  }
}

// ---------------- one-shot fp32->bf16 weight/pos convert ----------------
__global__ __launch_bounds__(256) void k_cvt(const float* __restrict__ w1, short* d1,  // 49152
                                             const float* __restrict__ w2, short* d2,  // 16384
                                             const float* __restrict__ w3, short* d3)  // 65408
{
  int i = blockIdx.x * 256 + threadIdx.x;
  if (i < 49152) d1[i] = f2bf(w1[i]);
  if (i < 16384) d2[i] = f2bf(w2[i]);
  if (i < 65408) d3[i] = f2bf(w3[i]);
}

// ---------------- bf16 MFMA GEMM, K=128, no LDS, no barriers ----------------
__global__ __launch_bounds__(256) void k_gemm_bf(
    const short* __restrict__ A, const short* __restrict__ Wt,
    const float* __restrict__ bias, float* __restrict__ outF,
    short* __restrict__ outB, int M, int ldout, int scaleN0, float scale,
    const short* __restrict__ A2, short* __restrict__ outB2, int ldout2, int yCut) {
  const int t = threadIdx.x;
  const int lane = t & 63, wv = t >> 6;
  const int ml = lane & 15, quad = lane >> 4;
  const int m0 = blockIdx.x * 64;
  int yb = blockIdx.y;
  const short* Ap = A;
  short* oB = outB;
  float* oF = outF;
  int ld = ldout;
  int nblk = yb;
  if (yb >= yCut) { Ap = A2; oB = outB2; oF = nullptr; ld = ldout2; nblk = 0; }
  const int n0 = nblk * 128 + wv * 32;
  const bf16x8 zero8 = {0, 0, 0, 0, 0, 0, 0, 0};

  bf16x8 Bfr[2][4];
#pragma unroll
  for (int nf = 0; nf < 2; ++nf)
#pragma unroll
    for (int ks = 0; ks < 4; ++ks)
      Bfr[nf][ks] = *(const bf16x8*)&Wt[(size_t)(n0 + nf * 16 + ml) * 128 + ks * 32 + quad * 8];

  f32x4 acc[4][2];
#pragma unroll
  for (int mf = 0; mf < 4; ++mf)
#pragma unroll
    for (int nf = 0; nf < 2; ++nf) acc[mf][nf] = {0.f, 0.f, 0.f, 0.f};

#pragma unroll
  for (int ks = 0; ks < 4; ++ks) {
    bf16x8 Af[4];
#pragma unroll
    for (int mf = 0; mf < 4; ++mf) {
      int m = m0 + mf * 16 + ml;
      Af[mf] = (m < M) ? *(const bf16x8*)&Ap[(size_t)m * 128 + ks * 32 + quad * 8] : zero8;
    }
#pragma unroll
    for (int mf = 0; mf < 4; ++mf)
#pragma unroll
      for (int nf = 0; nf < 2; ++nf)
        acc[mf][nf] = __builtin_amdgcn_mfma_f32_16x16x32_bf16(Af[mf], Bfr[nf][ks], acc[mf][nf], 0, 0, 0);
  }

#pragma unroll
  for (int nf = 0; nf < 2; ++nf) {
    int n = n0 + nf * 16 + ml;
    float bi = bias[n];
    float sc = (n < scaleN0) ? scale : 1.0f;
#pragma unroll
    for (int mf = 0; mf < 4; ++mf) {
#pragma unroll
      for (int r = 0; r < 4; ++r) {
        int m = m0 + mf * 16 + quad * 4 + r;
        if (m >= M) continue;
        float v = (acc[mf][nf][r] + bi) * sc;
        if (oF) oF[(size_t)m * ld + n] = v;
        if (oB) oB[(size_t)m * ld + n] = f2bf(v);
      }
    }
  }
}

// ---------------- Wo GEMM + residual + optional fused LayerNorm ----------------
// A (= attention output) is in OT layout [n][e][i][cc] (see k_attn_mfma); the
// fragment read below maps c = 32*ks + 8*quad -> (e2 = c>>4, off = c&15), which is
// identical to the old contiguous (m,c) read. res/outF/outLN stay in (w,n,c).
__global__ __launch_bounds__(256) void k_gemm_wo_ln(
    const short* __restrict__ A, const short* __restrict__ Wt,
    const float* __restrict__ bias, const float* __restrict__ res,
    float* __restrict__ outF, short* __restrict__ outLN,
    const float* __restrict__ lng, const float* __restrict__ lnb) {
  const int t = threadIdx.x;
  const int lane = t & 63, wv = t >> 6;
  const int ml = lane & 15, quad = lane >> 4;
  const int m0 = blockIdx.x * 64 + wv * 16;
  const int ii = m0 >> 7;              // w index (fixed across the 16 lanes)
  const int nn = (m0 & 127) + ml;      // n index (per-lane)

  f32x4 acc[8];
#pragma unroll
  for (int nf = 0; nf < 8; ++nf) acc[nf] = {0.f, 0.f, 0.f, 0.f};
#pragma unroll
  for (int ks = 0; ks < 4; ++ks) {
    bf16x8 Af = *(const bf16x8*)&A[(((size_t)nn * 8 + ks * 2 + (quad >> 1)) * 256 + ii) * 16 +
                                   (quad & 1) * 8];
#pragma unroll
    for (int nf = 0; nf < 8; ++nf) {
      bf16x8 Bf = *(const bf16x8*)&Wt[(size_t)(nf * 16 + ml) * 128 + ks * 32 + quad * 8];
      acc[nf] = __builtin_amdgcn_mfma_f32_16x16x32_bf16(Af, Bf, acc[nf], 0, 0, 0);
    }
  }
  float val[8][4];
#pragma unroll
  for (int nf = 0; nf < 8; ++nf) {
    float bi = bias[nf * 16 + ml];
#pragma unroll
    for (int r = 0; r < 4; ++r) {
      int m = m0 + quad * 4 + r;
      val[nf][r] = acc[nf][r] + bi + res[(size_t)m * 128 + nf * 16 + ml];
      outF[(size_t)m * 128 + nf * 16 + ml] = val[nf][r];
    }
  }
  if (outLN) {
#pragma unroll
    for (int r = 0; r < 4; ++r) {
      float s1 = 0.f, s2 = 0.f;
#pragma unroll
      for (int nf = 0; nf < 8; ++nf) { s1 += val[nf][r]; s2 += val[nf][r] * val[nf][r]; }
#pragma unroll
      for (int mk = 1; mk < 16; mk <<= 1) { s1 += __shfl_xor(s1, mk); s2 += __shfl_xor(s2, mk); }
      float mean = s1 * (1.0f / 128.f);
      float var = s2 * (1.0f / 128.f) - mean * mean;
      float rstd = rsqrtf(var + 1e-5f);
      int m = m0 + quad * 4 + r;
#pragma unroll
      for (int nf = 0; nf < 8; ++nf) {
        int nn2 = nf * 16 + ml;
        outLN[(size_t)m * 128 + nn2] = f2bf((val[nf][r] - mean) * rstd * lng[nn2] + lnb[nn2]);
      }
    }
  }
}

// ---------------- MFMA fused attention, head-split + i-panel loop ----------------
// Grid (n=128, e=8, ip-pairs=2). K/V^T staged once per block, reused across 2 i-panels.
// Round-2 latency rewrite:
//  * One-tile software pipeline: iteration i issues tile-i MFMAs and CONSUMES
//    tile i-1 (scores carried in registers / aged LDS banks). MFMA issue of tile i
//    overlaps the exp/pack/PV of tile i-1 (separate pipes).
//  * R3 LDS round trip replaced by ds_bpermute on the held MFMA result regs
//    (producer/consumer layouts share quad and reg index; only lane varies).
//    R3T buffer deleted (-11.3 KB -> LDS 26.9 KB -> 5 blocks/CU w/ bounds(256,5)).
//  * R2 keeps the 2-bank LDS scheme; under the 1-tile delay both consumed banks
//    are >= 1 full iteration old. The new R2 write is placed AFTER the consume
//    reads (same-wave DS order) to avoid the bank-(i&1) WAR clobber.
//  * ip-panel loop split 2-way across blockIdx.z for occupancy (grid 2048).
// PASS==2: p = i-j+255. PASS==1: p = j-i+255 (flipped pos).
template <int PASS>
__global__ __launch_bounds__(256, 5) void k_attn_mfma(
    const short* __restrict__ Qg, int ldq,
    const short* __restrict__ Kg, const short* __restrict__ Vg, int ldkv,
    const short* __restrict__ PP, short* __restrict__ OT) {
  __shared__ short Ks[256][16];
  __shared__ short VTs[16][264];
  __shared__ float R2T[4][2][16][20];  // [wave][bank][pm][i + pad4]

  const int t = threadIdx.x;
  const int n = blockIdx.x;
  const int e = blockIdx.y;
  const int lane = t & 63, wv = t >> 6;
  const int ml = lane & 15, quad = lane >> 4;
  const bool lo = lane < 32;
  const bf16x8 zero8 = {0, 0, 0, 0, 0, 0, 0, 0};
  const f32x4 z4 = {0.f, 0.f, 0.f, 0.f};

#pragma unroll
  for (int it = 0; it < 4; ++it) {  // K rows: 256 rows x 4 chunks of 4 shorts
    int idx = t + it * 256;
    int r = idx >> 2, c4 = idx & 3;
    *(bf16x4*)&Ks[r][c4 * 4] =
        *(const bf16x4*)&Kg[((size_t)r * NBd + n) * ldkv + e * 16 + c4 * 4];
  }
#pragma unroll
  for (int it = 0; it < 4; ++it) {  // V transposed: row-linear lanes
    bf16x4 vv = *(const bf16x4*)&Vg[((size_t)t * NBd + n) * ldkv + e * 16 + it * 4];
    VTs[it * 4 + 0][t] = vv[0];
    VTs[it * 4 + 1][t] = vv[1];
    VTs[it * 4 + 2][t] = vv[2];
    VTs[it * 4 + 3][t] = vv[3];
  }
  __syncthreads();

  // Loop-invariant consume constants: pcol = band index, bpa = bpermute byte addr
  // (source lane = (pcol&15) | (quad<<4); same quad, same reg index).
  int bpa[4], hiR[4], colR[4];
#pragma unroll
  for (int r = 0; r < 4; ++r) {
    int jl = quad * 4 + r;
    int pcol = (PASS == 2) ? (ml - jl + 15) : (jl - ml + 15);
    hiR[r] = pcol >> 4;
    colR[r] = pcol & 15;
    bpa[r] = ((pcol & 15) | (quad << 4)) << 2;
  }

  const short* PPe = PP + e * 16;
  short* OTb = OT + (size_t)(n * 8 + e) * 256 * 16;

  for (int ipl = 0; ipl < 2; ++ipl) {
    const int i0p = ((int)blockIdx.z * 2 + ipl) * 64;
    const int wb = (PASS == 2) ? i0p : (192 - i0p);
    bf16x8 bQ = lo ? *(const bf16x8*)&Qg[((size_t)(i0p + 16 * wv + ml) * NBd + n) * ldq +
                                         e * 16 + quad * 8]
                   : zero8;
    f32x4 Ot = {0.f, 0.f, 0.f, 0.f};
    float den = 0.f;

    // init "tile -1" R2 half -> bank 1
    bf16x8 fPQprev;
    {
      int pp = (PASS == 2) ? (wb + 16 * wv + 256 + ml) : (wb - 16 * wv + 48 + ml);
      if (pp > 510) pp = 510;
      const short* pr = &PPe[(size_t)pp * 256];
      bf16x8 fPK0 = lo ? *(const bf16x8*)&pr[128 + quad * 8] : zero8;
      fPQprev     = lo ? *(const bf16x8*)&pr[quad * 8] : zero8;
      f32x4 R2i = __builtin_amdgcn_mfma_f32_16x16x32_bf16(bQ, fPK0, z4, 0, 0, 0);
      *(f32x4*)&R2T[wv][1][ml][quad * 4] = R2i;
    }
    // preload PP row for tile 0
    bf16x8 fPK, fPQf;
    {
      int pf = (PASS == 2) ? (wb + 16 * wv + 240 + ml) : (wb - 16 * wv + 64 + ml);
      if (pf > 510) pf = 510;
      const short* prf = &PPe[(size_t)pf * 256];
      fPK  = lo ? *(const bf16x8*)&prf[128 + quad * 8] : zero8;
      fPQf = lo ? *(const bf16x8*)&prf[quad * 8] : zero8;
    }

    // carried (pipelined) tile state
    f32x4 St_p, R3a_p, R3b_p;
    unsigned pA0 = 0, pA1 = 0;

    // ---- compute tile 0 (no consume) ----
    {
      bf16x8 aK = lo ? *(const bf16x8*)&Ks[ml][quad * 8] : zero8;
      St_p = __builtin_amdgcn_mfma_f32_16x16x32_bf16(aK, bQ, z4, 0, 0, 0);
      f32x4 R2c = __builtin_amdgcn_mfma_f32_16x16x32_bf16(bQ, fPK, z4, 0, 0, 0);
      if (PASS == 2) {
        R3a_p = __builtin_amdgcn_mfma_f32_16x16x32_bf16(aK, fPQf, z4, 0, 0, 0);
        R3b_p = __builtin_amdgcn_mfma_f32_16x16x32_bf16(aK, fPQprev, z4, 0, 0, 0);
      } else {
        R3b_p = __builtin_amdgcn_mfma_f32_16x16x32_bf16(aK, fPQf, z4, 0, 0, 0);
        R3a_p = __builtin_amdgcn_mfma_f32_16x16x32_bf16(aK, fPQprev, z4, 0, 0, 0);
      }
      fPQprev = fPQf;
      {  // prefetch PP row for tile 1
        int pf = (PASS == 2) ? (wb + 16 * wv - 16 + 240 + ml) : (wb - 16 * wv + 16 + 64 + ml);
        if (pf > 510) pf = 510;
        const short* prf = &PPe[(size_t)pf * 256];
        fPK  = lo ? *(const bf16x8*)&prf[128 + quad * 8] : zero8;
        fPQf = lo ? *(const bf16x8*)&prf[quad * 8] : zero8;
      }
      *(f32x4*)&R2T[wv][0][ml][quad * 4] = R2c;
    }

    // consume tile T (reads aged R2 banks, bpermutes held R3 regs, exp, pack, PV)
    auto consume = [&](int T) {
      float pe4[4];
#pragma unroll
      for (int r = 0; r < 4; ++r) {
        int bk = (T & 1) ^ hiR[r] ^ (PASS == 1 ? 1 : 0);
        float r2 = R2T[wv][bk][colR[r]][ml];
        float va = __int_as_float(
            __builtin_amdgcn_ds_bpermute(bpa[r], __float_as_int(R3a_p[r])));
        float vb = __int_as_float(
            __builtin_amdgcn_ds_bpermute(bpa[r], __float_as_int(R3b_p[r])));
        float s = St_p[r] + r2 + (hiR[r] ? vb : va);
        pe4[r] = __expf(s);
        den += pe4[r];
      }
      unsigned d0, d1;
      asm("v_cvt_pk_bf16_f32 %0, %1, %2" : "=v"(d0) : "v"(pe4[0]), "v"(pe4[1]));
      asm("v_cvt_pk_bf16_f32 %0, %1, %2" : "=v"(d1) : "v"(pe4[2]), "v"(pe4[3]));
      if ((T & 1) == 0) {
        pA0 = d0;
        pA1 = d1;
      } else {
        unsigned b0 = pA0, b2 = d0, b1 = pA1, b3 = d1;
        asm("v_permlane32_swap_b32 %0, %1" : "+v"(b0), "+v"(b2));
        asm("v_permlane16_swap_b32 %0, %1" : "+v"(b0), "+v"(b2));
        asm("v_permlane32_swap_b32 %0, %1" : "+v"(b1), "+v"(b3));
        asm("v_permlane16_swap_b32 %0, %1" : "+v"(b1), "+v"(b3));
        union { unsigned u[4]; bf16x8 v8; } bp;
        bp.u[0] = b0; bp.u[1] = b1; bp.u[2] = b2; bp.u[3] = b3;
        bf16x8 aVT = *(const bf16x8*)&VTs[ml][(T >> 1) * 32 + quad * 8];
        Ot = __builtin_amdgcn_mfma_f32_16x16x32_bf16(aVT, bp.v8, Ot, 0, 0, 0);
      }
    };

#pragma unroll
    for (int i = 1; i < 16; ++i) {
      const int j0 = i * 16;
      // ---- issue tile i MFMAs ----
      bf16x8 aK = lo ? *(const bf16x8*)&Ks[j0 + ml][quad * 8] : zero8;
      f32x4 St_c = __builtin_amdgcn_mfma_f32_16x16x32_bf16(aK, bQ, z4, 0, 0, 0);
      f32x4 R2c  = __builtin_amdgcn_mfma_f32_16x16x32_bf16(bQ, fPK, z4, 0, 0, 0);
      f32x4 R3A, R3B;
      if (PASS == 2) {
        R3A = __builtin_amdgcn_mfma_f32_16x16x32_bf16(aK, fPQf, z4, 0, 0, 0);
        R3B = __builtin_amdgcn_mfma_f32_16x16x32_bf16(aK, fPQprev, z4, 0, 0, 0);
      } else {
        R3B = __builtin_amdgcn_mfma_f32_16x16x32_bf16(aK, fPQf, z4, 0, 0, 0);
        R3A = __builtin_amdgcn_mfma_f32_16x16x32_bf16(aK, fPQprev, z4, 0, 0, 0);
      }
      fPQprev = fPQf;
      if (i < 15) {  // prefetch PP row for tile i+1
        int pf = (PASS == 2) ? (wb + 16 * wv - (j0 + 16) + 240 + ml)
                             : (wb - 16 * wv + (j0 + 16) + 64 + ml);
        if (pf > 510) pf = 510;
        const short* prf = &PPe[(size_t)pf * 256];
        fPK  = lo ? *(const bf16x8*)&prf[128 + quad * 8] : zero8;
        fPQf = lo ? *(const bf16x8*)&prf[quad * 8] : zero8;
      }
      // ---- consume tile i-1 (before the bank-(i&1) overwrite below) ----
      consume(i - 1);
      *(f32x4*)&R2T[wv][i & 1][ml][quad * 4] = R2c;
      St_p = St_c; R3a_p = R3A; R3b_p = R3B;
    }
    // ---- epilogue: consume tile 15 (odd -> fires the last PV) ----
    consume(15);

    den += __shfl_xor(den, 16);
    den += __shfl_xor(den, 32);
    float inv = 1.f / den;
    bf16x4 ob;
    ob[0] = f2bf(Ot[0] * inv); ob[1] = f2bf(Ot[1] * inv);
    ob[2] = f2bf(Ot[2] * inv); ob[3] = f2bf(Ot[3] * inv);
    // OT[n][e][i][cc]: 16 rows x 32B = 512B contiguous per wave store
    *(bf16x4*)&OTb[(size_t)(i0p + 16 * wv + ml) * 16 + quad * 4] = ob;
  }
}

// ---------------- raw = sum_e pre-softmax scores, dense K=128 ----------------
// Banded reuse: R2 second half = prev jq's first-half RESULT (aQ invariant);
// PQ fragments carried across jq (saves loads). Grid (4 i-panels, 128 n, 4 j-quarters).
__global__ __launch_bounds__(256, 4) void k_raw(
    const short* __restrict__ Qf, const short* __restrict__ Kf,
    const short* __restrict__ PP, float* __restrict__ raw) {
  __shared__ float R2s[4][2][16][17];
  __shared__ float R3s[4][16][34];
  const int t = threadIdx.x;
  const int n = blockIdx.y;
  const int lane = t & 63, wv = t >> 6;
  const int ml = lane & 15, quad = lane >> 4;
  const int it0 = blockIdx.x * 64 + wv * 16;
  const int jt0 = blockIdx.z * 4;
  const f32x4 z4 = {0.f, 0.f, 0.f, 0.f};

  bf16x8 aQ[4];
#pragma unroll
  for (int kc = 0; kc < 4; ++kc)
    aQ[kc] = *(const bf16x8*)&Qf[((size_t)(it0 + ml) * NBd + n) * 384 + kc * 32 + quad * 8];

  float* rbase = &raw[(((size_t)(n & 1) * HNd + (n >> 1)) * Wd + it0) * Wd];

  bf16x8 fPQprev[4];
  {
    int pp = it0 - jt0 * 16 + 256 + ml;
    if (pp > 510) pp = 510;
    const short* pr = &PP[(size_t)pp * 256];
    f32x4 R2i = z4;
#pragma unroll
    for (int kc = 0; kc < 4; ++kc) {
      bf16x8 fPK = *(const bf16x8*)&pr[128 + kc * 32 + quad * 8];
      R2i = __builtin_amdgcn_mfma_f32_16x16x32_bf16(aQ[kc], fPK, R2i, 0, 0, 0);
      fPQprev[kc] = *(const bf16x8*)&pr[kc * 32 + quad * 8];
    }
#pragma unroll
    for (int r = 0; r < 4; ++r) R2s[wv][1][quad * 4 + r][ml] = R2i[r];
  }

#pragma unroll
  for (int jq = 0; jq < 4; ++jq) {
    const int j0 = (jt0 + jq) * 16;
    bf16x8 aK[4];
#pragma unroll
    for (int kc = 0; kc < 4; ++kc)
      aK[kc] = *(const bf16x8*)&Kf[((size_t)(j0 + ml) * NBd + n) * 256 + kc * 32 + quad * 8];
    const int p0 = it0 - j0 + 240 + ml;  // in [0,495] always
    const short* pr0 = &PP[(size_t)p0 * 256];
    f32x4 St = z4, R2f = z4, R3a = z4, R3b = z4;
    bf16x8 fPQ0[4];
#pragma unroll
    for (int kc = 0; kc < 4; ++kc)
      St = __builtin_amdgcn_mfma_f32_16x16x32_bf16(aQ[kc], aK[kc], St, 0, 0, 0);
#pragma unroll
    for (int kc = 0; kc < 4; ++kc) {
      bf16x8 fPK0 = *(const bf16x8*)&pr0[128 + kc * 32 + quad * 8];
      R2f = __builtin_amdgcn_mfma_f32_16x16x32_bf16(aQ[kc], fPK0, R2f, 0, 0, 0);
    }
#pragma unroll
    for (int kc = 0; kc < 4; ++kc) {
      fPQ0[kc] = *(const bf16x8*)&pr0[kc * 32 + quad * 8];
      R3a = __builtin_amdgcn_mfma_f32_16x16x32_bf16(aK[kc], fPQ0[kc], R3a, 0, 0, 0);
    }
#pragma unroll
    for (int kc = 0; kc < 4; ++kc)
      R3b = __builtin_amdgcn_mfma_f32_16x16x32_bf16(aK[kc], fPQprev[kc], R3b, 0, 0, 0);
#pragma unroll
    for (int kc = 0; kc < 4; ++kc) fPQprev[kc] = fPQ0[kc];
#pragma unroll
    for (int r = 0; r < 4; ++r) {
      R2s[wv][jq & 1][quad * 4 + r][ml] = R2f[r];
      R3s[wv][quad * 4 + r][ml]      = R3a[r];
      R3s[wv][quad * 4 + r][ml + 16] = R3b[r];
    }
#pragma unroll
    for (int r = 0; r < 4; ++r) {
      const int il = quad * 4 + r;
      const int pcol = il - ml + 15;
      const int hi = pcol >> 4, col = pcol & 15;
      const int bk = (jq & 1) ^ hi;
      rbase[(size_t)il * Wd + j0 + ml] = St[r] + R2s[wv][bk][il][col] + R3s[wv][ml][pcol];
    }
  }
}

extern "C" void kernel_launch(void* const* d_in, const int* in_sizes, int n_in,
                              void* d_out, int out_size, void* d_ws, size_t ws_size,
                              hipStream_t stream) {
  const float* feat_l = (const float*)d_in[0];
  const float* feat_r = (const float*)d_in[1];
  const float* pos    = (const float*)d_in[2];
  // d_in[3] = pos_indexes (int) -- structure known analytically, unused.
  const float* Wqkv = (const float*)d_in[4];
  const float* bqkv = (const float*)d_in[5];
  const float* Wo   = (const float*)d_in[6];
  const float* bo   = (const float*)d_in[7];
  const float* g1   = (const float*)d_in[8];
  const float* b1   = (const float*)d_in[9];
  const float* g2   = (const float*)d_in[10];
  const float* b2   = (const float*)d_in[11];
  float* out = (float*)d_out;

  float* ws = (float*)d_ws;
  float* fl_seq = ws;                 // fp32
  float* fr_seq = ws + SEQF;          // fp32
  float* fr2_f  = ws + 2 * SEQF;      // fp32 (fr_new)
  float* fl_new = ws + 3 * SEQF;      // fp32
  short* wsb    = (short*)(ws + 4 * SEQF);
  short* fl2_b   = wsb;               // SEQF bf16
  short* fr2_b   = wsb + SEQF;
  short* frb2_b  = wsb + 2 * SEQF;
  short* QKVl_b  = wsb + 3 * SEQF;    // 3*SEQF
  short* Qr_b    = wsb + 6 * SEQF;
  short* KVr2_b  = wsb + 7 * SEQF;    // 2*SEQF
  short* O_b     = wsb + 9 * SEQF;    // OT layout [n][e][i][cc]
  short* PP_b    = wsb + 10 * SEQF;   // 511*256
  short* Wb      = PP_b + 131072;     // Wqkv (49152) then Wo (16384)
  short* pos_b   = Wb + 65536;        // 511*128

  // to_seq + LN(g1,b1) fused, both tensors
  k_to_seq_ln<<<dim3(8, 256), 256, 0, stream>>>(feat_l, feat_r, fl_seq, fr_seq,
                                                fl2_b, fr2_b, g1, b1);
  k_cvt<<<256, 256, 0, stream>>>(Wqkv, Wb, Wo, Wb + 49152, pos, pos_b);

  // PP = [PQ(scaled)|PK] projections of the 511 pos rows (bf16 out)
  k_gemm_bf<<<dim3(8, 2), 256, 0, stream>>>(pos_b, Wb, bqkv, nullptr, PP_b,
                                            511, 256, 128, 0.25f,
                                            nullptr, nullptr, 0, 999);
  // QKV of fl2 (Q scaled) + Q of fr2 (scaled), merged
  k_gemm_bf<<<dim3(512, 4), 256, 0, stream>>>(fl2_b, Wb, bqkv, nullptr, QKVl_b,
                                              32768, 384, 128, 0.25f,
                                              fr2_b, Qr_b, 128, 3);

  // mha1: q=fr2-proj, kv=fl2-proj, flipped pos => p = j-i+255
  k_attn_mfma<1><<<dim3(128, 8, 2), 256, 0, stream>>>(
      Qr_b, Cd, QKVl_b + 128, QKVl_b + 256, 384, PP_b, O_b);
  // fr_new = fr_seq + O @ Wo^T + bo  (+ fused LN(g2,b2) -> frb2_b)
  k_gemm_wo_ln<<<512, 256, 0, stream>>>(O_b, Wb + 49152, bo, fr_seq, fr2_f,
                                        frb2_b, g2, b2);
  // KV of frb2
  k_gemm_bf<<<dim3(512, 2), 256, 0, stream>>>(frb2_b, Wb + 16384, bqkv + 128, nullptr,
                                              KVr2_b, 32768, 256, 0, 1.0f,
                                              nullptr, nullptr, 0, 999);
  // mha2: q=fl2-proj (in QKVl), kv=frb2-proj; p = i-j+255
  k_attn_mfma<2><<<dim3(128, 8, 2), 256, 0, stream>>>(
      QKVl_b, 384, KVr2_b, KVr2_b + 128, 256, PP_b, O_b);
  // raw = sum over heads of pre-softmax scores (dense K=128 formulation)
  k_raw<<<dim3(4, 128, 4), 256, 0, stream>>>(QKVl_b, KVr2_b, PP_b, out + 2 * SEQF);
  // fl_new = fl_seq + O @ Wo^T + bo (no LN)
  k_gemm_wo_ln<<<512, 256, 0, stream>>>(O_b, Wb + 49152, bo, fl_seq, fl_new,
                                        nullptr, nullptr, nullptr);

  k_from_seq2<<<dim3(8, 4, 256), dim3(32, 8), 0, stream>>>(fl_new, fr2_f, out, out + SEQF);

  (void)in_sizes; (void)n_in; (void)out_size; (void)ws_size;
}

// Round 3
// 440.111 us; speedup vs baseline: 1.1184x; 1.1184x over previous
//
#include <hip/hip_runtime.h>
#include <cstddef>

// Problem constants (fixed by setup_inputs)
static constexpr int Wd  = 256;   // sequence length (width)
static constexpr int NBd = 128;   // batch = hn*bs
static constexpr int Cd  = 128;   // channels
static constexpr int BSd = 2;     // bs
static constexpr int HNd = 64;    // hn
static constexpr size_t SEQF = (size_t)Wd * NBd * Cd;  // 4,194,304 elements

typedef __attribute__((ext_vector_type(8))) short bf16x8;
typedef __attribute__((ext_vector_type(4))) short bf16x4;
typedef __attribute__((ext_vector_type(4))) float f32x4;
typedef __attribute__((ext_vector_type(2))) float f32x2;

__device__ inline short f2bf(float f) {
  union { float f; unsigned u; } v; v.f = f;
  return (short)((v.u + 0x7FFFu + ((v.u >> 16) & 1u)) >> 16);
}

// ---------------- fused to_seq + LayerNorm ----------------
// feat (bs,c,hn,w) -> seq fp32 (w,n,c) AND ln(seq) bf16. grid (8 wtiles, 256 z).
__global__ __launch_bounds__(256) void k_to_seq_ln(
    const float* __restrict__ fA, const float* __restrict__ fB,
    float* __restrict__ seqA, float* __restrict__ seqB,
    short* __restrict__ lnA, short* __restrict__ lnB,
    const float* __restrict__ g, const float* __restrict__ bb) {
  __shared__ float red[2][8][33];
  __shared__ float mv[2][32];
  const int z = blockIdx.y;
  const float* feat = (z < 128) ? fA : fB;
  float* seq = (z < 128) ? seqA : seqB;
  short* lno = (z < 128) ? lnA : lnB;
  const int hb = z & 127;
  const int h = hb >> 1, b = hb & 1;
  const int n = h * BSd + b;
  const int w0 = blockIdx.x * 32;
  const int t = threadIdx.x;
  const int wl = t & 31, cg = t >> 5, c0 = cg * 16;
  float v[16];
  float s1 = 0.f, s2 = 0.f;
#pragma unroll
  for (int r = 0; r < 16; ++r) {
    v[r] = feat[(((size_t)b * Cd + c0 + r) * HNd + h) * Wd + w0 + wl];
    s1 += v[r]; s2 += v[r] * v[r];
  }
  red[0][cg][wl] = s1; red[1][cg][wl] = s2;
  __syncthreads();
  if (t < 32) {
    float a1 = 0.f, a2 = 0.f;
#pragma unroll
    for (int k = 0; k < 8; ++k) { a1 += red[0][k][t]; a2 += red[1][k][t]; }
    float mean = a1 * (1.0f / Cd);
    float var = a2 * (1.0f / Cd) - mean * mean;
    mv[0][t] = mean; mv[1][t] = rsqrtf(var + 1e-5f);
  }
  __syncthreads();
  const float mean = mv[0][wl], rstd = mv[1][wl];
  float* so = &seq[((size_t)(w0 + wl) * NBd + n) * Cd + c0];
  short* bo_ = &lno[((size_t)(w0 + wl) * NBd + n) * Cd + c0];
#pragma unroll
  for (int r = 0; r < 16; ++r) so[r] = v[r];
#pragma unroll
  for (int r = 0; r < 16; ++r)
    bo_[r] = f2bf((v[r] - mean) * rstd * g[c0 + r] + bb[c0 + r]);
}

// ---------------- from_seq: merged for both tensors ----------------
__global__ __launch_bounds__(256) void k_from_seq2(const float* __restrict__ seqA,
                                                   const float* __restrict__ seqB,
                                                   float* __restrict__ featA,
                                                   float* __restrict__ featB) {
  __shared__ float tile[32][33];
  int wi0 = blockIdx.x * 32, ci0 = blockIdx.y * 32;
  int z = blockIdx.z;
  const float* seq = (z < 128) ? seqA : seqB;
  float* feat = (z < 128) ? featA : featB;
  int hb = z & 127;
  int h = hb >> 1, b = hb & 1;
  int n = h * BSd + b;
  int tx = threadIdx.x, ty = threadIdx.y;
#pragma unroll
  for (int r = 0; r < 4; ++r) {
    int wi = wi0 + ty + r * 8;
    tile[ty + r * 8][tx] = seq[((size_t)wi * NBd + n) * Cd + ci0 + tx];
  }
  __syncthreads();
#pragma unroll
  for (int r = 0; r < 4; ++r) {
    int ci = ci0 + ty + r * 8;
    feat[(((size_t)b * Cd + ci) * HNd + h) * Wd + wi0 + tx] = tile[tx][ty + r * 8];
  }
}

// ---------------- one-shot fp32->bf16 weight/pos convert ----------------
__global__ __launch_bounds__(256) void k_cvt(const float* __restrict__ w1, short* d1,  // 49152
                                             const float* __restrict__ w2, short* d2,  // 16384
                                             const float* __restrict__ w3, short* d3)  // 65408
{
  int i = blockIdx.x * 256 + threadIdx.x;
  if (i < 49152) d1[i] = f2bf(w1[i]);
  if (i < 16384) d2[i] = f2bf(w2[i]);
  if (i < 65408) d3[i] = f2bf(w3[i]);
}

// ---------------- bf16 MFMA GEMM, K=128, no LDS, no barriers ----------------
__global__ __launch_bounds__(256) void k_gemm_bf(
    const short* __restrict__ A, const short* __restrict__ Wt,
    const float* __restrict__ bias, float* __restrict__ outF,
    short* __restrict__ outB, int M, int ldout, int scaleN0, float scale,
    const short* __restrict__ A2, short* __restrict__ outB2, int ldout2, int yCut) {
  const int t = threadIdx.x;
  const int lane = t & 63, wv = t >> 6;
  const int ml = lane & 15, quad = lane >> 4;
  const int m0 = blockIdx.x * 64;
  int yb = blockIdx.y;
  const short* Ap = A;
  short* oB = outB;
  float* oF = outF;
  int ld = ldout;
  int nblk = yb;
  if (yb >= yCut) { Ap = A2; oB = outB2; oF = nullptr; ld = ldout2; nblk = 0; }
  const int n0 = nblk * 128 + wv * 32;
  const bf16x8 zero8 = {0, 0, 0, 0, 0, 0, 0, 0};

  bf16x8 Bfr[2][4];
#pragma unroll
  for (int nf = 0; nf < 2; ++nf)
#pragma unroll
    for (int ks = 0; ks < 4; ++ks)
      Bfr[nf][ks] = *(const bf16x8*)&Wt[(size_t)(n0 + nf * 16 + ml) * 128 + ks * 32 + quad * 8];

  f32x4 acc[4][2];
#pragma unroll
  for (int mf = 0; mf < 4; ++mf)
#pragma unroll
    for (int nf = 0; nf < 2; ++nf) acc[mf][nf] = {0.f, 0.f, 0.f, 0.f};

#pragma unroll
  for (int ks = 0; ks < 4; ++ks) {
    bf16x8 Af[4];
#pragma unroll
    for (int mf = 0; mf < 4; ++mf) {
      int m = m0 + mf * 16 + ml;
      Af[mf] = (m < M) ? *(const bf16x8*)&Ap[(size_t)m * 128 + ks * 32 + quad * 8] : zero8;
    }
#pragma unroll
    for (int mf = 0; mf < 4; ++mf)
#pragma unroll
      for (int nf = 0; nf < 2; ++nf)
        acc[mf][nf] = __builtin_amdgcn_mfma_f32_16x16x32_bf16(Af[mf], Bfr[nf][ks], acc[mf][nf], 0, 0, 0);
  }

#pragma unroll
  for (int nf = 0; nf < 2; ++nf) {
    int n = n0 + nf * 16 + ml;
    float bi = bias[n];
    float sc = (n < scaleN0) ? scale : 1.0f;
#pragma unroll
    for (int mf = 0; mf < 4; ++mf) {
#pragma unroll
      for (int r = 0; r < 4; ++r) {
        int m = m0 + mf * 16 + quad * 4 + r;
        if (m >= M) continue;
        float v = (acc[mf][nf][r] + bi) * sc;
        if (oF) oF[(size_t)m * ld + n] = v;
        if (oB) oB[(size_t)m * ld + n] = f2bf(v);
      }
    }
  }
}

// ---------------- Wo GEMM + residual + optional fused LayerNorm ----------------
// A (= attention output) is in OT layout [n][e][i][cc] (see k_attn_mfma); the
// fragment read below maps c = 32*ks + 8*quad -> (e2 = c>>4, off = c&15), which is
// identical to the old contiguous (m,c) read. res/outF/outLN stay in (w,n,c).
__global__ __launch_bounds__(256) void k_gemm_wo_ln(
    const short* __restrict__ A, const short* __restrict__ Wt,
    const float* __restrict__ bias, const float* __restrict__ res,
    float* __restrict__ outF, short* __restrict__ outLN,
    const float* __restrict__ lng, const float* __restrict__ lnb) {
  const int t = threadIdx.x;
  const int lane = t & 63, wv = t >> 6;
  const int ml = lane & 15, quad = lane >> 4;
  const int m0 = blockIdx.x * 64 + wv * 16;
  const int ii = m0 >> 7;              // w index (fixed across the 16 lanes)
  const int nn = (m0 & 127) + ml;      // n index (per-lane)

  f32x4 acc[8];
#pragma unroll
  for (int nf = 0; nf < 8; ++nf) acc[nf] = {0.f, 0.f, 0.f, 0.f};
#pragma unroll
  for (int ks = 0; ks < 4; ++ks) {
    bf16x8 Af = *(const bf16x8*)&A[(((size_t)nn * 8 + ks * 2 + (quad >> 1)) * 256 + ii) * 16 +
                                   (quad & 1) * 8];
#pragma unroll
    for (int nf = 0; nf < 8; ++nf) {
      bf16x8 Bf = *(const bf16x8*)&Wt[(size_t)(nf * 16 + ml) * 128 + ks * 32 + quad * 8];
      acc[nf] = __builtin_amdgcn_mfma_f32_16x16x32_bf16(Af, Bf, acc[nf], 0, 0, 0);
    }
  }
  float val[8][4];
#pragma unroll
  for (int nf = 0; nf < 8; ++nf) {
    float bi = bias[nf * 16 + ml];
#pragma unroll
    for (int r = 0; r < 4; ++r) {
      int m = m0 + quad * 4 + r;
      val[nf][r] = acc[nf][r] + bi + res[(size_t)m * 128 + nf * 16 + ml];
      outF[(size_t)m * 128 + nf * 16 + ml] = val[nf][r];
    }
  }
  if (outLN) {
#pragma unroll
    for (int r = 0; r < 4; ++r) {
      float s1 = 0.f, s2 = 0.f;
#pragma unroll
      for (int nf = 0; nf < 8; ++nf) { s1 += val[nf][r]; s2 += val[nf][r] * val[nf][r]; }
#pragma unroll
      for (int mk = 1; mk < 16; mk <<= 1) { s1 += __shfl_xor(s1, mk); s2 += __shfl_xor(s2, mk); }
      float mean = s1 * (1.0f / 128.f);
      float var = s2 * (1.0f / 128.f) - mean * mean;
      float rstd = rsqrtf(var + 1e-5f);
      int m = m0 + quad * 4 + r;
#pragma unroll
      for (int nf = 0; nf < 8; ++nf) {
        int nn2 = nf * 16 + ml;
        outLN[(size_t)m * 128 + nn2] = f2bf((val[nf][r] - mean) * rstd * lng[nn2] + lnb[nn2]);
      }
    }
  }
}

// ---------------- MFMA fused attention, head-split + i-panel loop ----------------
// Grid (n=128, e=8). K/V^T staged once, reused across 4 i-panels.
// Round-3: round-1 occupancy config (bounds(256,4), no z-split, no spill) +
// round-2 structural wins kept:
//  * One-tile software pipeline: iteration i issues tile-i MFMAs and CONSUMES
//    tile i-1 (St/R3 carried in regs, R2 in aged LDS banks). MFMA issue of
//    tile i overlaps the exp/pack/PV of tile i-1.
//  * R3 via ds_bpermute on held MFMA result regs (same quad / same reg index;
//    only lane varies). R3T LDS buffer deleted (LDS 26.9 KB).
//  * Consume constants collapsed to ONE register (pbase); pcol/hi/bank/bpermute
//    addr derived per-r with compile-time r (register-pressure insurance).
//  * R2 write placed AFTER consume (same-wave DS order) - no WAR on the banks.
// PASS==2: p = i-j+255. PASS==1: p = j-i+255 (flipped pos).
template <int PASS>
__global__ __launch_bounds__(256, 4) void k_attn_mfma(
    const short* __restrict__ Qg, int ldq,
    const short* __restrict__ Kg, const short* __restrict__ Vg, int ldkv,
    const short* __restrict__ PP, short* __restrict__ OT) {
  __shared__ short Ks[256][16];
  __shared__ short VTs[16][264];
  __shared__ float R2T[4][2][16][20];  // [wave][bank][pm][i + pad4]

  const int t = threadIdx.x;
  const int n = blockIdx.x;
  const int e = blockIdx.y;
  const int lane = t & 63, wv = t >> 6;
  const int ml = lane & 15, quad = lane >> 4;
  const bool lo = lane < 32;
  const bf16x8 zero8 = {0, 0, 0, 0, 0, 0, 0, 0};
  const f32x4 z4 = {0.f, 0.f, 0.f, 0.f};

#pragma unroll
  for (int it = 0; it < 4; ++it) {  // K rows: 256 rows x 4 chunks of 4 shorts
    int idx = t + it * 256;
    int r = idx >> 2, c4 = idx & 3;
    *(bf16x4*)&Ks[r][c4 * 4] =
        *(const bf16x4*)&Kg[((size_t)r * NBd + n) * ldkv + e * 16 + c4 * 4];
  }
#pragma unroll
  for (int it = 0; it < 4; ++it) {  // V transposed: row-linear lanes
    bf16x4 vv = *(const bf16x4*)&Vg[((size_t)t * NBd + n) * ldkv + e * 16 + it * 4];
    VTs[it * 4 + 0][t] = vv[0];
    VTs[it * 4 + 1][t] = vv[1];
    VTs[it * 4 + 2][t] = vv[2];
    VTs[it * 4 + 3][t] = vv[3];
  }
  __syncthreads();

  // Single-register consume base: pcol(r) = pbase -/+ r (r compile-time).
  const int pbase = (PASS == 2) ? (ml - quad * 4 + 15) : (quad * 4 - ml + 15);
  const int qsh = quad << 6;  // bpermute byte addr high part ((quad<<4)<<2)

  const short* PPe = PP + e * 16;
  short* OTb = OT + (size_t)(n * 8 + e) * 256 * 16;

  for (int ip = 0; ip < 4; ++ip) {
    const int i0p = ip * 64;
    const int wb = (PASS == 2) ? i0p : (192 - i0p);
    bf16x8 bQ = lo ? *(const bf16x8*)&Qg[((size_t)(i0p + 16 * wv + ml) * NBd + n) * ldq +
                                         e * 16 + quad * 8]
                   : zero8;
    f32x4 Ot = {0.f, 0.f, 0.f, 0.f};
    float den = 0.f;

    // init "tile -1" R2 half -> bank 1
    bf16x8 fPQprev;
    {
      int pp = (PASS == 2) ? (wb + 16 * wv + 256 + ml) : (wb - 16 * wv + 48 + ml);
      if (pp > 510) pp = 510;
      const short* pr = &PPe[(size_t)pp * 256];
      bf16x8 fPK0 = lo ? *(const bf16x8*)&pr[128 + quad * 8] : zero8;
      fPQprev     = lo ? *(const bf16x8*)&pr[quad * 8] : zero8;
      f32x4 R2i = __builtin_amdgcn_mfma_f32_16x16x32_bf16(bQ, fPK0, z4, 0, 0, 0);
      *(f32x4*)&R2T[wv][1][ml][quad * 4] = R2i;
    }
    // preload PP row for tile 0
    bf16x8 fPK, fPQf;
    {
      int pf = (PASS == 2) ? (wb + 16 * wv + 240 + ml) : (wb - 16 * wv + 64 + ml);
      if (pf > 510) pf = 510;
      const short* prf = &PPe[(size_t)pf * 256];
      fPK  = lo ? *(const bf16x8*)&prf[128 + quad * 8] : zero8;
      fPQf = lo ? *(const bf16x8*)&prf[quad * 8] : zero8;
    }

    // carried (pipelined) tile state
    f32x4 St_p, R3a_p, R3b_p;
    unsigned pA0 = 0, pA1 = 0;

    // ---- compute tile 0 (no consume) ----
    {
      bf16x8 aK = lo ? *(const bf16x8*)&Ks[ml][quad * 8] : zero8;
      St_p = __builtin_amdgcn_mfma_f32_16x16x32_bf16(aK, bQ, z4, 0, 0, 0);
      f32x4 R2c = __builtin_amdgcn_mfma_f32_16x16x32_bf16(bQ, fPK, z4, 0, 0, 0);
      if (PASS == 2) {
        R3a_p = __builtin_amdgcn_mfma_f32_16x16x32_bf16(aK, fPQf, z4, 0, 0, 0);
        R3b_p = __builtin_amdgcn_mfma_f32_16x16x32_bf16(aK, fPQprev, z4, 0, 0, 0);
      } else {
        R3b_p = __builtin_amdgcn_mfma_f32_16x16x32_bf16(aK, fPQf, z4, 0, 0, 0);
        R3a_p = __builtin_amdgcn_mfma_f32_16x16x32_bf16(aK, fPQprev, z4, 0, 0, 0);
      }
      fPQprev = fPQf;
      {  // prefetch PP row for tile 1
        int pf = (PASS == 2) ? (wb + 16 * wv - 16 + 240 + ml) : (wb - 16 * wv + 16 + 64 + ml);
        if (pf > 510) pf = 510;
        const short* prf = &PPe[(size_t)pf * 256];
        fPK  = lo ? *(const bf16x8*)&prf[128 + quad * 8] : zero8;
        fPQf = lo ? *(const bf16x8*)&prf[quad * 8] : zero8;
      }
      *(f32x4*)&R2T[wv][0][ml][quad * 4] = R2c;
    }

    // consume tile T (reads aged R2 banks, bpermutes held R3 regs, exp, pack, PV)
    auto consume = [&](int T) {
      float pe4[4];
#pragma unroll
      for (int r = 0; r < 4; ++r) {
        const int pcol = (PASS == 2) ? (pbase - r) : (pbase + r);
        const int hi = pcol >> 4;
        const int bk = (T & 1) ^ hi ^ (PASS == 1 ? 1 : 0);
        const int ba = ((pcol & 15) << 2) | qsh;
        float r2 = R2T[wv][bk][pcol & 15][ml];
        float va = __int_as_float(
            __builtin_amdgcn_ds_bpermute(ba, __float_as_int(R3a_p[r])));
        float vb = __int_as_float(
            __builtin_amdgcn_ds_bpermute(ba, __float_as_int(R3b_p[r])));
        float s = St_p[r] + r2 + (hi ? vb : va);
        pe4[r] = __expf(s);
        den += pe4[r];
      }
      unsigned d0, d1;
      asm("v_cvt_pk_bf16_f32 %0, %1, %2" : "=v"(d0) : "v"(pe4[0]), "v"(pe4[1]));
      asm("v_cvt_pk_bf16_f32 %0, %1, %2" : "=v"(d1) : "v"(pe4[2]), "v"(pe4[3]));
      if ((T & 1) == 0) {
        pA0 = d0;
        pA1 = d1;
      } else {
        unsigned b0 = pA0, b2 = d0, b1 = pA1, b3 = d1;
        asm("v_permlane32_swap_b32 %0, %1" : "+v"(b0), "+v"(b2));
        asm("v_permlane16_swap_b32 %0, %1" : "+v"(b0), "+v"(b2));
        asm("v_permlane32_swap_b32 %0, %1" : "+v"(b1), "+v"(b3));
        asm("v_permlane16_swap_b32 %0, %1" : "+v"(b1), "+v"(b3));
        union { unsigned u[4]; bf16x8 v8; } bp;
        bp.u[0] = b0; bp.u[1] = b1; bp.u[2] = b2; bp.u[3] = b3;
        bf16x8 aVT = *(const bf16x8*)&VTs[ml][(T >> 1) * 32 + quad * 8];
        Ot = __builtin_amdgcn_mfma_f32_16x16x32_bf16(aVT, bp.v8, Ot, 0, 0, 0);
      }
    };

#pragma unroll
    for (int i = 1; i < 16; ++i) {
      const int j0 = i * 16;
      // ---- issue tile i MFMAs ----
      bf16x8 aK = lo ? *(const bf16x8*)&Ks[j0 + ml][quad * 8] : zero8;
      f32x4 St_c = __builtin_amdgcn_mfma_f32_16x16x32_bf16(aK, bQ, z4, 0, 0, 0);
      f32x4 R2c  = __builtin_amdgcn_mfma_f32_16x16x32_bf16(bQ, fPK, z4, 0, 0, 0);
      f32x4 R3A, R3B;
      if (PASS == 2) {
        R3A = __builtin_amdgcn_mfma_f32_16x16x32_bf16(aK, fPQf, z4, 0, 0, 0);
        R3B = __builtin_amdgcn_mfma_f32_16x16x32_bf16(aK, fPQprev, z4, 0, 0, 0);
      } else {
        R3B = __builtin_amdgcn_mfma_f32_16x16x32_bf16(aK, fPQf, z4, 0, 0, 0);
        R3A = __builtin_amdgcn_mfma_f32_16x16x32_bf16(aK, fPQprev, z4, 0, 0, 0);
      }
      fPQprev = fPQf;
      if (i < 15) {  // prefetch PP row for tile i+1
        int pf = (PASS == 2) ? (wb + 16 * wv - (j0 + 16) + 240 + ml)
                             : (wb - 16 * wv + (j0 + 16) + 64 + ml);
        if (pf > 510) pf = 510;
        const short* prf = &PPe[(size_t)pf * 256];
        fPK  = lo ? *(const bf16x8*)&prf[128 + quad * 8] : zero8;
        fPQf = lo ? *(const bf16x8*)&prf[quad * 8] : zero8;
      }
      // ---- consume tile i-1 (before the bank-(i&1) overwrite below) ----
      consume(i - 1);
      *(f32x4*)&R2T[wv][i & 1][ml][quad * 4] = R2c;
      St_p = St_c; R3a_p = R3A; R3b_p = R3B;
    }
    // ---- epilogue: consume tile 15 (odd -> fires the last PV) ----
    consume(15);

    den += __shfl_xor(den, 16);
    den += __shfl_xor(den, 32);
    float inv = 1.f / den;
    bf16x4 ob;
    ob[0] = f2bf(Ot[0] * inv); ob[1] = f2bf(Ot[1] * inv);
    ob[2] = f2bf(Ot[2] * inv); ob[3] = f2bf(Ot[3] * inv);
    // OT[n][e][i][cc]: 16 rows x 32B = 512B contiguous per wave store
    *(bf16x4*)&OTb[(size_t)(i0p + 16 * wv + ml) * 16 + quad * 4] = ob;
  }
}

// ---------------- raw = sum_e pre-softmax scores, dense K=128 ----------------
// Banded reuse: R2 second half = prev jq's first-half RESULT (aQ invariant);
// PQ fragments carried across jq (saves loads). Grid (4 i-panels, 128 n, 4 j-quarters).
__global__ __launch_bounds__(256, 4) void k_raw(
    const short* __restrict__ Qf, const short* __restrict__ Kf,
    const short* __restrict__ PP, float* __restrict__ raw) {
  __shared__ float R2s[4][2][16][17];
  __shared__ float R3s[4][16][34];
  const int t = threadIdx.x;
  const int n = blockIdx.y;
  const int lane = t & 63, wv = t >> 6;
  const int ml = lane & 15, quad = lane >> 4;
  const int it0 = blockIdx.x * 64 + wv * 16;
  const int jt0 = blockIdx.z * 4;
  const f32x4 z4 = {0.f, 0.f, 0.f, 0.f};

  bf16x8 aQ[4];
#pragma unroll
  for (int kc = 0; kc < 4; ++kc)
    aQ[kc] = *(const bf16x8*)&Qf[((size_t)(it0 + ml) * NBd + n) * 384 + kc * 32 + quad * 8];

  float* rbase = &raw[(((size_t)(n & 1) * HNd + (n >> 1)) * Wd + it0) * Wd];

  bf16x8 fPQprev[4];
  {
    int pp = it0 - jt0 * 16 + 256 + ml;
    if (pp > 510) pp = 510;
    const short* pr = &PP[(size_t)pp * 256];
    f32x4 R2i = z4;
#pragma unroll
    for (int kc = 0; kc < 4; ++kc) {
      bf16x8 fPK = *(const bf16x8*)&pr[128 + kc * 32 + quad * 8];
      R2i = __builtin_amdgcn_mfma_f32_16x16x32_bf16(aQ[kc], fPK, R2i, 0, 0, 0);
      fPQprev[kc] = *(const bf16x8*)&pr[kc * 32 + quad * 8];
    }
#pragma unroll
    for (int r = 0; r < 4; ++r) R2s[wv][1][quad * 4 + r][ml] = R2i[r];
  }

#pragma unroll
  for (int jq = 0; jq < 4; ++jq) {
    const int j0 = (jt0 + jq) * 16;
    bf16x8 aK[4];
#pragma unroll
    for (int kc = 0; kc < 4; ++kc)
      aK[kc] = *(const bf16x8*)&Kf[((size_t)(j0 + ml) * NBd + n) * 256 + kc * 32 + quad * 8];
    const int p0 = it0 - j0 + 240 + ml;  // in [0,495] always
    const short* pr0 = &PP[(size_t)p0 * 256];
    f32x4 St = z4, R2f = z4, R3a = z4, R3b = z4;
    bf16x8 fPQ0[4];
#pragma unroll
    for (int kc = 0; kc < 4; ++kc)
      St = __builtin_amdgcn_mfma_f32_16x16x32_bf16(aQ[kc], aK[kc], St, 0, 0, 0);
#pragma unroll
    for (int kc = 0; kc < 4; ++kc) {
      bf16x8 fPK0 = *(const bf16x8*)&pr0[128 + kc * 32 + quad * 8];
      R2f = __builtin_amdgcn_mfma_f32_16x16x32_bf16(aQ[kc], fPK0, R2f, 0, 0, 0);
    }
#pragma unroll
    for (int kc = 0; kc < 4; ++kc) {
      fPQ0[kc] = *(const bf16x8*)&pr0[kc * 32 + quad * 8];
      R3a = __builtin_amdgcn_mfma_f32_16x16x32_bf16(aK[kc], fPQ0[kc], R3a, 0, 0, 0);
    }
#pragma unroll
    for (int kc = 0; kc < 4; ++kc)
      R3b = __builtin_amdgcn_mfma_f32_16x16x32_bf16(aK[kc], fPQprev[kc], R3b, 0, 0, 0);
#pragma unroll
    for (int kc = 0; kc < 4; ++kc) fPQprev[kc] = fPQ0[kc];
#pragma unroll
    for (int r = 0; r < 4; ++r) {
      R2s[wv][jq & 1][quad * 4 + r][ml] = R2f[r];
      R3s[wv][quad * 4 + r][ml]      = R3a[r];
      R3s[wv][quad * 4 + r][ml + 16] = R3b[r];
    }
#pragma unroll
    for (int r = 0; r < 4; ++r) {
      const int il = quad * 4 + r;
      const int pcol = il - ml + 15;
      const int hi = pcol >> 4, col = pcol & 15;
      const int bk = (jq & 1) ^ hi;
      rbase[(size_t)il * Wd + j0 + ml] = St[r] + R2s[wv][bk][il][col] + R3s[wv][ml][pcol];
    }
  }
}

extern "C" void kernel_launch(void* const* d_in, const int* in_sizes, int n_in,
                              void* d_out, int out_size, void* d_ws, size_t ws_size,
                              hipStream_t stream) {
  const float* feat_l = (const float*)d_in[0];
  const float* feat_r = (const float*)d_in[1];
  const float* pos    = (const float*)d_in[2];
  // d_in[3] = pos_indexes (int) -- structure known analytically, unused.
  const float* Wqkv = (const float*)d_in[4];
  const float* bqkv = (const float*)d_in[5];
  const float* Wo   = (const float*)d_in[6];
  const float* bo   = (const float*)d_in[7];
  const float* g1   = (const float*)d_in[8];
  const float* b1   = (const float*)d_in[9];
  const float* g2   = (const float*)d_in[10];
  const float* b2   = (const float*)d_in[11];
  float* out = (float*)d_out;

  float* ws = (float*)d_ws;
  float* fl_seq = ws;                 // fp32
  float* fr_seq = ws + SEQF;          // fp32
  float* fr2_f  = ws + 2 * SEQF;      // fp32 (fr_new)
  float* fl_new = ws + 3 * SEQF;      // fp32
  short* wsb    = (short*)(ws + 4 * SEQF);
  short* fl2_b   = wsb;               // SEQF bf16
  short* fr2_b   = wsb + SEQF;
  short* frb2_b  = wsb + 2 * SEQF;
  short* QKVl_b  = wsb + 3 * SEQF;    // 3*SEQF
  short* Qr_b    = wsb + 6 * SEQF;
  short* KVr2_b  = wsb + 7 * SEQF;    // 2*SEQF
  short* O_b     = wsb + 9 * SEQF;    // OT layout [n][e][i][cc]
  short* PP_b    = wsb + 10 * SEQF;   // 511*256
  short* Wb      = PP_b + 131072;     // Wqkv (49152) then Wo (16384)
  short* pos_b   = Wb + 65536;        // 511*128

  // to_seq + LN(g1,b1) fused, both tensors
  k_to_seq_ln<<<dim3(8, 256), 256, 0, stream>>>(feat_l, feat_r, fl_seq, fr_seq,
                                                fl2_b, fr2_b, g1, b1);
  k_cvt<<<256, 256, 0, stream>>>(Wqkv, Wb, Wo, Wb + 49152, pos, pos_b);

  // PP = [PQ(scaled)|PK] projections of the 511 pos rows (bf16 out)
  k_gemm_bf<<<dim3(8, 2), 256, 0, stream>>>(pos_b, Wb, bqkv, nullptr, PP_b,
                                            511, 256, 128, 0.25f,
                                            nullptr, nullptr, 0, 999);
  // QKV of fl2 (Q scaled) + Q of fr2 (scaled), merged
  k_gemm_bf<<<dim3(512, 4), 256, 0, stream>>>(fl2_b, Wb, bqkv, nullptr, QKVl_b,
                                              32768, 384, 128, 0.25f,
                                              fr2_b, Qr_b, 128, 3);

  // mha1: q=fr2-proj, kv=fl2-proj, flipped pos => p = j-i+255
  k_attn_mfma<1><<<dim3(128, 8), 256, 0, stream>>>(
      Qr_b, Cd, QKVl_b + 128, QKVl_b + 256, 384, PP_b, O_b);
  // fr_new = fr_seq + O @ Wo^T + bo  (+ fused LN(g2,b2) -> frb2_b)
  k_gemm_wo_ln<<<512, 256, 0, stream>>>(O_b, Wb + 49152, bo, fr_seq, fr2_f,
                                        frb2_b, g2, b2);
  // KV of frb2
  k_gemm_bf<<<dim3(512, 2), 256, 0, stream>>>(frb2_b, Wb + 16384, bqkv + 128, nullptr,
                                              KVr2_b, 32768, 256, 0, 1.0f,
                                              nullptr, nullptr, 0, 999);
  // mha2: q=fl2-proj (in QKVl), kv=frb2-proj; p = i-j+255
  k_attn_mfma<2><<<dim3(128, 8), 256, 0, stream>>>(
      QKVl_b, 384, KVr2_b, KVr2_b + 128, 256, PP_b, O_b);
  // raw = sum over heads of pre-softmax scores (dense K=128 formulation)
  k_raw<<<dim3(4, 128, 4), 256, 0, stream>>>(QKVl_b, KVr2_b, PP_b, out + 2 * SEQF);
  // fl_new = fl_seq + O @ Wo^T + bo (no LN)
  k_gemm_wo_ln<<<512, 256, 0, stream>>>(O_b, Wb + 49152, bo, fl_seq, fl_new,
                                        nullptr, nullptr, nullptr);

  k_from_seq2<<<dim3(8, 4, 256), dim3(32, 8), 0, stream>>>(fl_new, fr2_f, out, out + SEQF);

  (void)in_sizes; (void)n_in; (void)out_size; (void)ws_size;
}

// Round 4
// 391.476 us; speedup vs baseline: 1.2573x; 1.1242x over previous
//
#include <hip/hip_runtime.h>
#include <cstddef>

// Problem constants (fixed by setup_inputs)
static constexpr int Wd  = 256;   // sequence length (width)
static constexpr int NBd = 128;   // batch = hn*bs
static constexpr int Cd  = 128;   // channels
static constexpr int BSd = 2;     // bs
static constexpr int HNd = 64;    // hn
static constexpr size_t SEQF = (size_t)Wd * NBd * Cd;  // 4,194,304 elements

typedef __attribute__((ext_vector_type(8))) short bf16x8;
typedef __attribute__((ext_vector_type(4))) short bf16x4;
typedef __attribute__((ext_vector_type(4))) float f32x4;
typedef __attribute__((ext_vector_type(2))) float f32x2;

__device__ inline short f2bf(float f) {
  union { float f; unsigned u; } v; v.f = f;
  return (short)((v.u + 0x7FFFu + ((v.u >> 16) & 1u)) >> 16);
}

// ---------------- fused to_seq + LayerNorm ----------------
// feat (bs,c,hn,w) -> seq fp32 (w,n,c) AND ln(seq) bf16. grid (8 wtiles, 256 z).
__global__ __launch_bounds__(256) void k_to_seq_ln(
    const float* __restrict__ fA, const float* __restrict__ fB,
    float* __restrict__ seqA, float* __restrict__ seqB,
    short* __restrict__ lnA, short* __restrict__ lnB,
    const float* __restrict__ g, const float* __restrict__ bb) {
  __shared__ float red[2][8][33];
  __shared__ float mv[2][32];
  const int z = blockIdx.y;
  const float* feat = (z < 128) ? fA : fB;
  float* seq = (z < 128) ? seqA : seqB;
  short* lno = (z < 128) ? lnA : lnB;
  const int hb = z & 127;
  const int h = hb >> 1, b = hb & 1;
  const int n = h * BSd + b;
  const int w0 = blockIdx.x * 32;
  const int t = threadIdx.x;
  const int wl = t & 31, cg = t >> 5, c0 = cg * 16;
  float v[16];
  float s1 = 0.f, s2 = 0.f;
#pragma unroll
  for (int r = 0; r < 16; ++r) {
    v[r] = feat[(((size_t)b * Cd + c0 + r) * HNd + h) * Wd + w0 + wl];
    s1 += v[r]; s2 += v[r] * v[r];
  }
  red[0][cg][wl] = s1; red[1][cg][wl] = s2;
  __syncthreads();
  if (t < 32) {
    float a1 = 0.f, a2 = 0.f;
#pragma unroll
    for (int k = 0; k < 8; ++k) { a1 += red[0][k][t]; a2 += red[1][k][t]; }
    float mean = a1 * (1.0f / Cd);
    float var = a2 * (1.0f / Cd) - mean * mean;
    mv[0][t] = mean; mv[1][t] = rsqrtf(var + 1e-5f);
  }
  __syncthreads();
  const float mean = mv[0][wl], rstd = mv[1][wl];
  float* so = &seq[((size_t)(w0 + wl) * NBd + n) * Cd + c0];
  short* bo_ = &lno[((size_t)(w0 + wl) * NBd + n) * Cd + c0];
#pragma unroll
  for (int r = 0; r < 16; ++r) so[r] = v[r];
#pragma unroll
  for (int r = 0; r < 16; ++r)
    bo_[r] = f2bf((v[r] - mean) * rstd * g[c0 + r] + bb[c0 + r]);
}

// ---------------- from_seq: merged for both tensors ----------------
__global__ __launch_bounds__(256) void k_from_seq2(const float* __restrict__ seqA,
                                                   const float* __restrict__ seqB,
                                                   float* __restrict__ featA,
                                                   float* __restrict__ featB) {
  __shared__ float tile[32][33];
  int wi0 = blockIdx.x * 32, ci0 = blockIdx.y * 32;
  int z = blockIdx.z;
  const float* seq = (z < 128) ? seqA : seqB;
  float* feat = (z < 128) ? featA : featB;
  int hb = z & 127;
  int h = hb >> 1, b = hb & 1;
  int n = h * BSd + b;
  int tx = threadIdx.x, ty = threadIdx.y;
#pragma unroll
  for (int r = 0; r < 4; ++r) {
    int wi = wi0 + ty + r * 8;
    tile[ty + r * 8][tx] = seq[((size_t)wi * NBd + n) * Cd + ci0 + tx];
  }
  __syncthreads();
#pragma unroll
  for (int r = 0; r < 4; ++r) {
    int ci = ci0 + ty + r * 8;
    feat[(((size_t)b * Cd + ci) * HNd + h) * Wd + wi0 + tx] = tile[tx][ty + r * 8];
  }
}

// ---------------- one-shot fp32->bf16 weight/pos convert ----------------
__global__ __launch_bounds__(256) void k_cvt(const float* __restrict__ w1, short* d1,  // 49152
                                             const float* __restrict__ w2, short* d2,  // 16384
                                             const float* __restrict__ w3, short* d3)  // 65408
{
  int i = blockIdx.x * 256 + threadIdx.x;
  if (i < 49152) d1[i] = f2bf(w1[i]);
  if (i < 16384) d2[i] = f2bf(w2[i]);
  if (i < 65408) d3[i] = f2bf(w3[i]);
}

// ---------------- bf16 MFMA GEMM, K=128, no LDS, no barriers ----------------
__global__ __launch_bounds__(256) void k_gemm_bf(
    const short* __restrict__ A, const short* __restrict__ Wt,
    const float* __restrict__ bias, float* __restrict__ outF,
    short* __restrict__ outB, int M, int ldout, int scaleN0, float scale,
    const short* __restrict__ A2, short* __restrict__ outB2, int ldout2, int yCut) {
  const int t = threadIdx.x;
  const int lane = t & 63, wv = t >> 6;
  const int ml = lane & 15, quad = lane >> 4;
  const int m0 = blockIdx.x * 64;
  int yb = blockIdx.y;
  const short* Ap = A;
  short* oB = outB;
  float* oF = outF;
  int ld = ldout;
  int nblk = yb;
  if (yb >= yCut) { Ap = A2; oB = outB2; oF = nullptr; ld = ldout2; nblk = 0; }
  const int n0 = nblk * 128 + wv * 32;
  const bf16x8 zero8 = {0, 0, 0, 0, 0, 0, 0, 0};

  bf16x8 Bfr[2][4];
#pragma unroll
  for (int nf = 0; nf < 2; ++nf)
#pragma unroll
    for (int ks = 0; ks < 4; ++ks)
      Bfr[nf][ks] = *(const bf16x8*)&Wt[(size_t)(n0 + nf * 16 + ml) * 128 + ks * 32 + quad * 8];

  f32x4 acc[4][2];
#pragma unroll
  for (int mf = 0; mf < 4; ++mf)
#pragma unroll
    for (int nf = 0; nf < 2; ++nf) acc[mf][nf] = {0.f, 0.f, 0.f, 0.f};

#pragma unroll
  for (int ks = 0; ks < 4; ++ks) {
    bf16x8 Af[4];
#pragma unroll
    for (int mf = 0; mf < 4; ++mf) {
      int m = m0 + mf * 16 + ml;
      Af[mf] = (m < M) ? *(const bf16x8*)&Ap[(size_t)m * 128 + ks * 32 + quad * 8] : zero8;
    }
#pragma unroll
    for (int mf = 0; mf < 4; ++mf)
#pragma unroll
      for (int nf = 0; nf < 2; ++nf)
        acc[mf][nf] = __builtin_amdgcn_mfma_f32_16x16x32_bf16(Af[mf], Bfr[nf][ks], acc[mf][nf], 0, 0, 0);
  }

#pragma unroll
  for (int nf = 0; nf < 2; ++nf) {
    int n = n0 + nf * 16 + ml;
    float bi = bias[n];
    float sc = (n < scaleN0) ? scale : 1.0f;
#pragma unroll
    for (int mf = 0; mf < 4; ++mf) {
#pragma unroll
      for (int r = 0; r < 4; ++r) {
        int m = m0 + mf * 16 + quad * 4 + r;
        if (m >= M) continue;
        float v = (acc[mf][nf][r] + bi) * sc;
        if (oF) oF[(size_t)m * ld + n] = v;
        if (oB) oB[(size_t)m * ld + n] = f2bf(v);
      }
    }
  }
}

// ---------------- Wo GEMM + residual + optional fused LayerNorm ----------------
// A (= attention output) is in OT layout [n][e][i][cc] (see k_attn_mfma); the
// fragment read below maps c = 32*ks + 8*quad -> (e2 = c>>4, off = c&15), which is
// identical to the old contiguous (m,c) read. res/outF/outLN stay in (w,n,c).
__global__ __launch_bounds__(256) void k_gemm_wo_ln(
    const short* __restrict__ A, const short* __restrict__ Wt,
    const float* __restrict__ bias, const float* __restrict__ res,
    float* __restrict__ outF, short* __restrict__ outLN,
    const float* __restrict__ lng, const float* __restrict__ lnb) {
  const int t = threadIdx.x;
  const int lane = t & 63, wv = t >> 6;
  const int ml = lane & 15, quad = lane >> 4;
  const int m0 = blockIdx.x * 64 + wv * 16;
  const int ii = m0 >> 7;              // w index (fixed across the 16 lanes)
  const int nn = (m0 & 127) + ml;      // n index (per-lane)

  f32x4 acc[8];
#pragma unroll
  for (int nf = 0; nf < 8; ++nf) acc[nf] = {0.f, 0.f, 0.f, 0.f};
#pragma unroll
  for (int ks = 0; ks < 4; ++ks) {
    bf16x8 Af = *(const bf16x8*)&A[(((size_t)nn * 8 + ks * 2 + (quad >> 1)) * 256 + ii) * 16 +
                                   (quad & 1) * 8];
#pragma unroll
    for (int nf = 0; nf < 8; ++nf) {
      bf16x8 Bf = *(const bf16x8*)&Wt[(size_t)(nf * 16 + ml) * 128 + ks * 32 + quad * 8];
      acc[nf] = __builtin_amdgcn_mfma_f32_16x16x32_bf16(Af, Bf, acc[nf], 0, 0, 0);
    }
  }
  float val[8][4];
#pragma unroll
  for (int nf = 0; nf < 8; ++nf) {
    float bi = bias[nf * 16 + ml];
#pragma unroll
    for (int r = 0; r < 4; ++r) {
      int m = m0 + quad * 4 + r;
      val[nf][r] = acc[nf][r] + bi + res[(size_t)m * 128 + nf * 16 + ml];
      outF[(size_t)m * 128 + nf * 16 + ml] = val[nf][r];
    }
  }
  if (outLN) {
#pragma unroll
    for (int r = 0; r < 4; ++r) {
      float s1 = 0.f, s2 = 0.f;
#pragma unroll
      for (int nf = 0; nf < 8; ++nf) { s1 += val[nf][r]; s2 += val[nf][r] * val[nf][r]; }
#pragma unroll
      for (int mk = 1; mk < 16; mk <<= 1) { s1 += __shfl_xor(s1, mk); s2 += __shfl_xor(s2, mk); }
      float mean = s1 * (1.0f / 128.f);
      float var = s2 * (1.0f / 128.f) - mean * mean;
      float rstd = rsqrtf(var + 1e-5f);
      int m = m0 + quad * 4 + r;
#pragma unroll
      for (int nf = 0; nf < 8; ++nf) {
        int nn2 = nf * 16 + ml;
        outLN[(size_t)m * 128 + nn2] = f2bf((val[nf][r] - mean) * rstd * lng[nn2] + lnb[nn2]);
      }
    }
  }
}

// ---------------- MFMA fused attention, head-split + i-panel loop ----------------
// Grid (n=128, e=8, ip-pairs=2). K/V^T staged per block, reused across 2 i-panels.
// Round-4: pipeline finally given enough registers.
//  * __launch_bounds__(256,3): VGPR cap ~168 -- the 1-tile pipeline's live set
//    (~110) spilled at 128 (round 3: +72MB sym. scratch traffic). LDS 27.1KB x3
//    = 81KB/CU ok.
//  * 2-way z-split keeps the grid at 2048 so the 3-blocks/CU schedule has a
//    small tail quantum (768 resident, ~89% schedule eff. vs 67% at 1024).
//  * One-tile software pipeline: iteration i issues tile-i MFMAs and CONSUMES
//    tile i-1 (St/R3 carried in regs, R2 in aged LDS banks).
//  * R3 via ds_bpermute on held MFMA result regs; R3T LDS buffer deleted.
//  * R2 write placed AFTER consume (same-wave DS order) - no WAR on the banks.
// PASS==2: p = i-j+255. PASS==1: p = j-i+255 (flipped pos).
template <int PASS>
__global__ __launch_bounds__(256, 3) void k_attn_mfma(
    const short* __restrict__ Qg, int ldq,
    const short* __restrict__ Kg, const short* __restrict__ Vg, int ldkv,
    const short* __restrict__ PP, short* __restrict__ OT) {
  __shared__ short Ks[256][16];
  __shared__ short VTs[16][264];
  __shared__ float R2T[4][2][16][20];  // [wave][bank][pm][i + pad4]

  const int t = threadIdx.x;
  const int n = blockIdx.x;
  const int e = blockIdx.y;
  const int lane = t & 63, wv = t >> 6;
  const int ml = lane & 15, quad = lane >> 4;
  const bool lo = lane < 32;
  const bf16x8 zero8 = {0, 0, 0, 0, 0, 0, 0, 0};
  const f32x4 z4 = {0.f, 0.f, 0.f, 0.f};

#pragma unroll
  for (int it = 0; it < 4; ++it) {  // K rows: 256 rows x 4 chunks of 4 shorts
    int idx = t + it * 256;
    int r = idx >> 2, c4 = idx & 3;
    *(bf16x4*)&Ks[r][c4 * 4] =
        *(const bf16x4*)&Kg[((size_t)r * NBd + n) * ldkv + e * 16 + c4 * 4];
  }
#pragma unroll
  for (int it = 0; it < 4; ++it) {  // V transposed: row-linear lanes
    bf16x4 vv = *(const bf16x4*)&Vg[((size_t)t * NBd + n) * ldkv + e * 16 + it * 4];
    VTs[it * 4 + 0][t] = vv[0];
    VTs[it * 4 + 1][t] = vv[1];
    VTs[it * 4 + 2][t] = vv[2];
    VTs[it * 4 + 3][t] = vv[3];
  }
  __syncthreads();

  // Single-register consume base: pcol(r) = pbase -/+ r (r compile-time).
  const int pbase = (PASS == 2) ? (ml - quad * 4 + 15) : (quad * 4 - ml + 15);
  const int qsh = quad << 6;  // bpermute byte addr high part ((quad<<4)<<2)

  const short* PPe = PP + e * 16;
  short* OTb = OT + (size_t)(n * 8 + e) * 256 * 16;

  for (int ipl = 0; ipl < 2; ++ipl) {
    const int i0p = ((int)blockIdx.z * 2 + ipl) * 64;
    const int wb = (PASS == 2) ? i0p : (192 - i0p);
    bf16x8 bQ = lo ? *(const bf16x8*)&Qg[((size_t)(i0p + 16 * wv + ml) * NBd + n) * ldq +
                                         e * 16 + quad * 8]
                   : zero8;
    f32x4 Ot = {0.f, 0.f, 0.f, 0.f};
    float den = 0.f;

    // init "tile -1" R2 half -> bank 1
    bf16x8 fPQprev;
    {
      int pp = (PASS == 2) ? (wb + 16 * wv + 256 + ml) : (wb - 16 * wv + 48 + ml);
      if (pp > 510) pp = 510;
      const short* pr = &PPe[(size_t)pp * 256];
      bf16x8 fPK0 = lo ? *(const bf16x8*)&pr[128 + quad * 8] : zero8;
      fPQprev     = lo ? *(const bf16x8*)&pr[quad * 8] : zero8;
      f32x4 R2i = __builtin_amdgcn_mfma_f32_16x16x32_bf16(bQ, fPK0, z4, 0, 0, 0);
      *(f32x4*)&R2T[wv][1][ml][quad * 4] = R2i;
    }
    // preload PP row for tile 0
    bf16x8 fPK, fPQf;
    {
      int pf = (PASS == 2) ? (wb + 16 * wv + 240 + ml) : (wb - 16 * wv + 64 + ml);
      if (pf > 510) pf = 510;
      const short* prf = &PPe[(size_t)pf * 256];
      fPK  = lo ? *(const bf16x8*)&prf[128 + quad * 8] : zero8;
      fPQf = lo ? *(const bf16x8*)&prf[quad * 8] : zero8;
    }

    // carried (pipelined) tile state
    f32x4 St_p, R3a_p, R3b_p;
    unsigned pA0 = 0, pA1 = 0;

    // ---- compute tile 0 (no consume) ----
    {
      bf16x8 aK = lo ? *(const bf16x8*)&Ks[ml][quad * 8] : zero8;
      St_p = __builtin_amdgcn_mfma_f32_16x16x32_bf16(aK, bQ, z4, 0, 0, 0);
      f32x4 R2c = __builtin_amdgcn_mfma_f32_16x16x32_bf16(bQ, fPK, z4, 0, 0, 0);
      if (PASS == 2) {
        R3a_p = __builtin_amdgcn_mfma_f32_16x16x32_bf16(aK, fPQf, z4, 0, 0, 0);
        R3b_p = __builtin_amdgcn_mfma_f32_16x16x32_bf16(aK, fPQprev, z4, 0, 0, 0);
      } else {
        R3b_p = __builtin_amdgcn_mfma_f32_16x16x32_bf16(aK, fPQf, z4, 0, 0, 0);
        R3a_p = __builtin_amdgcn_mfma_f32_16x16x32_bf16(aK, fPQprev, z4, 0, 0, 0);
      }
      fPQprev = fPQf;
      {  // prefetch PP row for tile 1
        int pf = (PASS == 2) ? (wb + 16 * wv - 16 + 240 + ml) : (wb - 16 * wv + 16 + 64 + ml);
        if (pf > 510) pf = 510;
        const short* prf = &PPe[(size_t)pf * 256];
        fPK  = lo ? *(const bf16x8*)&prf[128 + quad * 8] : zero8;
        fPQf = lo ? *(const bf16x8*)&prf[quad * 8] : zero8;
      }
      *(f32x4*)&R2T[wv][0][ml][quad * 4] = R2c;
    }

    // consume tile T (reads aged R2 banks, bpermutes held R3 regs, exp, pack, PV)
    auto consume = [&](int T) {
      float pe4[4];
#pragma unroll
      for (int r = 0; r < 4; ++r) {
        const int pcol = (PASS == 2) ? (pbase - r) : (pbase + r);
        const int hi = pcol >> 4;
        const int bk = (T & 1) ^ hi ^ (PASS == 1 ? 1 : 0);
        const int ba = ((pcol & 15) << 2) | qsh;
        float r2 = R2T[wv][bk][pcol & 15][ml];
        float va = __int_as_float(
            __builtin_amdgcn_ds_bpermute(ba, __float_as_int(R3a_p[r])));
        float vb = __int_as_float(
            __builtin_amdgcn_ds_bpermute(ba, __float_as_int(R3b_p[r])));
        float s = St_p[r] + r2 + (hi ? vb : va);
        pe4[r] = __expf(s);
        den += pe4[r];
      }
      unsigned d0, d1;
      asm("v_cvt_pk_bf16_f32 %0, %1, %2" : "=v"(d0) : "v"(pe4[0]), "v"(pe4[1]));
      asm("v_cvt_pk_bf16_f32 %0, %1, %2" : "=v"(d1) : "v"(pe4[2]), "v"(pe4[3]));
      if ((T & 1) == 0) {
        pA0 = d0;
        pA1 = d1;
      } else {
        unsigned b0 = pA0, b2 = d0, b1 = pA1, b3 = d1;
        asm("v_permlane32_swap_b32 %0, %1" : "+v"(b0), "+v"(b2));
        asm("v_permlane16_swap_b32 %0, %1" : "+v"(b0), "+v"(b2));
        asm("v_permlane32_swap_b32 %0, %1" : "+v"(b1), "+v"(b3));
        asm("v_permlane16_swap_b32 %0, %1" : "+v"(b1), "+v"(b3));
        union { unsigned u[4]; bf16x8 v8; } bp;
        bp.u[0] = b0; bp.u[1] = b1; bp.u[2] = b2; bp.u[3] = b3;
        bf16x8 aVT = *(const bf16x8*)&VTs[ml][(T >> 1) * 32 + quad * 8];
        Ot = __builtin_amdgcn_mfma_f32_16x16x32_bf16(aVT, bp.v8, Ot, 0, 0, 0);
      }
    };

#pragma unroll
    for (int i = 1; i < 16; ++i) {
      const int j0 = i * 16;
      // ---- issue tile i MFMAs ----
      bf16x8 aK = lo ? *(const bf16x8*)&Ks[j0 + ml][quad * 8] : zero8;
      f32x4 St_c = __builtin_amdgcn_mfma_f32_16x16x32_bf16(aK, bQ, z4, 0, 0, 0);
      f32x4 R2c  = __builtin_amdgcn_mfma_f32_16x16x32_bf16(bQ, fPK, z4, 0, 0, 0);
      f32x4 R3A, R3B;
      if (PASS == 2) {
        R3A = __builtin_amdgcn_mfma_f32_16x16x32_bf16(aK, fPQf, z4, 0, 0, 0);
        R3B = __builtin_amdgcn_mfma_f32_16x16x32_bf16(aK, fPQprev, z4, 0, 0, 0);
      } else {
        R3B = __builtin_amdgcn_mfma_f32_16x16x32_bf16(aK, fPQf, z4, 0, 0, 0);
        R3A = __builtin_amdgcn_mfma_f32_16x16x32_bf16(aK, fPQprev, z4, 0, 0, 0);
      }
      fPQprev = fPQf;
      if (i < 15) {  // prefetch PP row for tile i+1
        int pf = (PASS == 2) ? (wb + 16 * wv - (j0 + 16) + 240 + ml)
                             : (wb - 16 * wv + (j0 + 16) + 64 + ml);
        if (pf > 510) pf = 510;
        const short* prf = &PPe[(size_t)pf * 256];
        fPK  = lo ? *(const bf16x8*)&prf[128 + quad * 8] : zero8;
        fPQf = lo ? *(const bf16x8*)&prf[quad * 8] : zero8;
      }
      // ---- consume tile i-1 (before the bank-(i&1) overwrite below) ----
      consume(i - 1);
      *(f32x4*)&R2T[wv][i & 1][ml][quad * 4] = R2c;
      St_p = St_c; R3a_p = R3A; R3b_p = R3B;
    }
    // ---- epilogue: consume tile 15 (odd -> fires the last PV) ----
    consume(15);

    den += __shfl_xor(den, 16);
    den += __shfl_xor(den, 32);
    float inv = 1.f / den;
    bf16x4 ob;
    ob[0] = f2bf(Ot[0] * inv); ob[1] = f2bf(Ot[1] * inv);
    ob[2] = f2bf(Ot[2] * inv); ob[3] = f2bf(Ot[3] * inv);
    // OT[n][e][i][cc]: 16 rows x 32B = 512B contiguous per wave store
    *(bf16x4*)&OTb[(size_t)(i0p + 16 * wv + ml) * 16 + quad * 4] = ob;
  }
}

// ---------------- raw = sum_e pre-softmax scores, dense K=128 ----------------
// Banded reuse: R2 second half = prev jq's first-half RESULT (aQ invariant);
// PQ fragments carried across jq (saves loads). Grid (4 i-panels, 128 n, 4 j-quarters).
__global__ __launch_bounds__(256, 4) void k_raw(
    const short* __restrict__ Qf, const short* __restrict__ Kf,
    const short* __restrict__ PP, float* __restrict__ raw) {
  __shared__ float R2s[4][2][16][17];
  __shared__ float R3s[4][16][34];
  const int t = threadIdx.x;
  const int n = blockIdx.y;
  const int lane = t & 63, wv = t >> 6;
  const int ml = lane & 15, quad = lane >> 4;
  const int it0 = blockIdx.x * 64 + wv * 16;
  const int jt0 = blockIdx.z * 4;
  const f32x4 z4 = {0.f, 0.f, 0.f, 0.f};

  bf16x8 aQ[4];
#pragma unroll
  for (int kc = 0; kc < 4; ++kc)
    aQ[kc] = *(const bf16x8*)&Qf[((size_t)(it0 + ml) * NBd + n) * 384 + kc * 32 + quad * 8];

  float* rbase = &raw[(((size_t)(n & 1) * HNd + (n >> 1)) * Wd + it0) * Wd];

  bf16x8 fPQprev[4];
  {
    int pp = it0 - jt0 * 16 + 256 + ml;
    if (pp > 510) pp = 510;
    const short* pr = &PP[(size_t)pp * 256];
    f32x4 R2i = z4;
#pragma unroll
    for (int kc = 0; kc < 4; ++kc) {
      bf16x8 fPK = *(const bf16x8*)&pr[128 + kc * 32 + quad * 8];
      R2i = __builtin_amdgcn_mfma_f32_16x16x32_bf16(aQ[kc], fPK, R2i, 0, 0, 0);
      fPQprev[kc] = *(const bf16x8*)&pr[kc * 32 + quad * 8];
    }
#pragma unroll
    for (int r = 0; r < 4; ++r) R2s[wv][1][quad * 4 + r][ml] = R2i[r];
  }

#pragma unroll
  for (int jq = 0; jq < 4; ++jq) {
    const int j0 = (jt0 + jq) * 16;
    bf16x8 aK[4];
#pragma unroll
    for (int kc = 0; kc < 4; ++kc)
      aK[kc] = *(const bf16x8*)&Kf[((size_t)(j0 + ml) * NBd + n) * 256 + kc * 32 + quad * 8];
    const int p0 = it0 - j0 + 240 + ml;  // in [0,495] always
    const short* pr0 = &PP[(size_t)p0 * 256];
    f32x4 St = z4, R2f = z4, R3a = z4, R3b = z4;
    bf16x8 fPQ0[4];
#pragma unroll
    for (int kc = 0; kc < 4; ++kc)
      St = __builtin_amdgcn_mfma_f32_16x16x32_bf16(aQ[kc], aK[kc], St, 0, 0, 0);
#pragma unroll
    for (int kc = 0; kc < 4; ++kc) {
      bf16x8 fPK0 = *(const bf16x8*)&pr0[128 + kc * 32 + quad * 8];
      R2f = __builtin_amdgcn_mfma_f32_16x16x32_bf16(aQ[kc], fPK0, R2f, 0, 0, 0);
    }
#pragma unroll
    for (int kc = 0; kc < 4; ++kc) {
      fPQ0[kc] = *(const bf16x8*)&pr0[kc * 32 + quad * 8];
      R3a = __builtin_amdgcn_mfma_f32_16x16x32_bf16(aK[kc], fPQ0[kc], R3a, 0, 0, 0);
    }
#pragma unroll
    for (int kc = 0; kc < 4; ++kc)
      R3b = __builtin_amdgcn_mfma_f32_16x16x32_bf16(aK[kc], fPQprev[kc], R3b, 0, 0, 0);
#pragma unroll
    for (int kc = 0; kc < 4; ++kc) fPQprev[kc] = fPQ0[kc];
#pragma unroll
    for (int r = 0; r < 4; ++r) {
      R2s[wv][jq & 1][quad * 4 + r][ml] = R2f[r];
      R3s[wv][quad * 4 + r][ml]      = R3a[r];
      R3s[wv][quad * 4 + r][ml + 16] = R3b[r];
    }
#pragma unroll
    for (int r = 0; r < 4; ++r) {
      const int il = quad * 4 + r;
      const int pcol = il - ml + 15;
      const int hi = pcol >> 4, col = pcol & 15;
      const int bk = (jq & 1) ^ hi;
      rbase[(size_t)il * Wd + j0 + ml] = St[r] + R2s[wv][bk][il][col] + R3s[wv][ml][pcol];
    }
  }
}

extern "C" void kernel_launch(void* const* d_in, const int* in_sizes, int n_in,
                              void* d_out, int out_size, void* d_ws, size_t ws_size,
                              hipStream_t stream) {
  const float* feat_l = (const float*)d_in[0];
  const float* feat_r = (const float*)d_in[1];
  const float* pos    = (const float*)d_in[2];
  // d_in[3] = pos_indexes (int) -- structure known analytically, unused.
  const float* Wqkv = (const float*)d_in[4];
  const float* bqkv = (const float*)d_in[5];
  const float* Wo   = (const float*)d_in[6];
  const float* bo   = (const float*)d_in[7];
  const float* g1   = (const float*)d_in[8];
  const float* b1   = (const float*)d_in[9];
  const float* g2   = (const float*)d_in[10];
  const float* b2   = (const float*)d_in[11];
  float* out = (float*)d_out;

  float* ws = (float*)d_ws;
  float* fl_seq = ws;                 // fp32
  float* fr_seq = ws + SEQF;          // fp32
  float* fr2_f  = ws + 2 * SEQF;      // fp32 (fr_new)
  float* fl_new = ws + 3 * SEQF;      // fp32
  short* wsb    = (short*)(ws + 4 * SEQF);
  short* fl2_b   = wsb;               // SEQF bf16
  short* fr2_b   = wsb + SEQF;
  short* frb2_b  = wsb + 2 * SEQF;
  short* QKVl_b  = wsb + 3 * SEQF;    // 3*SEQF
  short* Qr_b    = wsb + 6 * SEQF;
  short* KVr2_b  = wsb + 7 * SEQF;    // 2*SEQF
  short* O_b     = wsb + 9 * SEQF;    // OT layout [n][e][i][cc]
  short* PP_b    = wsb + 10 * SEQF;   // 511*256
  short* Wb      = PP_b + 131072;     // Wqkv (49152) then Wo (16384)
  short* pos_b   = Wb + 65536;        // 511*128

  // to_seq + LN(g1,b1) fused, both tensors
  k_to_seq_ln<<<dim3(8, 256), 256, 0, stream>>>(feat_l, feat_r, fl_seq, fr_seq,
                                                fl2_b, fr2_b, g1, b1);
  k_cvt<<<256, 256, 0, stream>>>(Wqkv, Wb, Wo, Wb + 49152, pos, pos_b);

  // PP = [PQ(scaled)|PK] projections of the 511 pos rows (bf16 out)
  k_gemm_bf<<<dim3(8, 2), 256, 0, stream>>>(pos_b, Wb, bqkv, nullptr, PP_b,
                                            511, 256, 128, 0.25f,
                                            nullptr, nullptr, 0, 999);
  // QKV of fl2 (Q scaled) + Q of fr2 (scaled), merged
  k_gemm_bf<<<dim3(512, 4), 256, 0, stream>>>(fl2_b, Wb, bqkv, nullptr, QKVl_b,
                                              32768, 384, 128, 0.25f,
                                              fr2_b, Qr_b, 128, 3);

  // mha1: q=fr2-proj, kv=fl2-proj, flipped pos => p = j-i+255
  k_attn_mfma<1><<<dim3(128, 8, 2), 256, 0, stream>>>(
      Qr_b, Cd, QKVl_b + 128, QKVl_b + 256, 384, PP_b, O_b);
  // fr_new = fr_seq + O @ Wo^T + bo  (+ fused LN(g2,b2) -> frb2_b)
  k_gemm_wo_ln<<<512, 256, 0, stream>>>(O_b, Wb + 49152, bo, fr_seq, fr2_f,
                                        frb2_b, g2, b2);
  // KV of frb2
  k_gemm_bf<<<dim3(512, 2), 256, 0, stream>>>(frb2_b, Wb + 16384, bqkv + 128, nullptr,
                                              KVr2_b, 32768, 256, 0, 1.0f,
                                              nullptr, nullptr, 0, 999);
  // mha2: q=fl2-proj (in QKVl), kv=frb2-proj; p = i-j+255
  k_attn_mfma<2><<<dim3(128, 8, 2), 256, 0, stream>>>(
      QKVl_b, 384, KVr2_b, KVr2_b + 128, 256, PP_b, O_b);
  // raw = sum over heads of pre-softmax scores (dense K=128 formulation)
  k_raw<<<dim3(4, 128, 4), 256, 0, stream>>>(QKVl_b, KVr2_b, PP_b, out + 2 * SEQF);
  // fl_new = fl_seq + O @ Wo^T + bo (no LN)
  k_gemm_wo_ln<<<512, 256, 0, stream>>>(O_b, Wb + 49152, bo, fl_seq, fl_new,
                                        nullptr, nullptr, nullptr);

  k_from_seq2<<<dim3(8, 4, 256), dim3(32, 8), 0, stream>>>(fl_new, fr2_f, out, out + SEQF);

  (void)in_sizes; (void)n_in; (void)out_size; (void)ws_size;
}

// Round 5
// 390.888 us; speedup vs baseline: 1.2592x; 1.0015x over previous
//
#include <hip/hip_runtime.h>
#include <cstddef>

// Problem constants (fixed by setup_inputs)
static constexpr int Wd  = 256;   // sequence length (width)
static constexpr int NBd = 128;   // batch = hn*bs
static constexpr int Cd  = 128;   // channels
static constexpr int BSd = 2;     // bs
static constexpr int HNd = 64;    // hn
static constexpr size_t SEQF = (size_t)Wd * NBd * Cd;  // 4,194,304 elements

typedef __attribute__((ext_vector_type(8))) short bf16x8;
typedef __attribute__((ext_vector_type(4))) short bf16x4;
typedef __attribute__((ext_vector_type(4))) float f32x4;
typedef __attribute__((ext_vector_type(2))) float f32x2;

__device__ inline short f2bf(float f) {
  union { float f; unsigned u; } v; v.f = f;
  return (short)((v.u + 0x7FFFu + ((v.u >> 16) & 1u)) >> 16);
}

// ---------------- fused to_seq + LayerNorm ----------------
// feat (bs,c,hn,w) -> seq fp32 (w,n,c) AND ln(seq) bf16. grid (8 wtiles, 256 z).
__global__ __launch_bounds__(256) void k_to_seq_ln(
    const float* __restrict__ fA, const float* __restrict__ fB,
    float* __restrict__ seqA, float* __restrict__ seqB,
    short* __restrict__ lnA, short* __restrict__ lnB,
    const float* __restrict__ g, const float* __restrict__ bb) {
  __shared__ float red[2][8][33];
  __shared__ float mv[2][32];
  const int z = blockIdx.y;
  const float* feat = (z < 128) ? fA : fB;
  float* seq = (z < 128) ? seqA : seqB;
  short* lno = (z < 128) ? lnA : lnB;
  const int hb = z & 127;
  const int h = hb >> 1, b = hb & 1;
  const int n = h * BSd + b;
  const int w0 = blockIdx.x * 32;
  const int t = threadIdx.x;
  const int wl = t & 31, cg = t >> 5, c0 = cg * 16;
  float v[16];
  float s1 = 0.f, s2 = 0.f;
#pragma unroll
  for (int r = 0; r < 16; ++r) {
    v[r] = feat[(((size_t)b * Cd + c0 + r) * HNd + h) * Wd + w0 + wl];
    s1 += v[r]; s2 += v[r] * v[r];
  }
  red[0][cg][wl] = s1; red[1][cg][wl] = s2;
  __syncthreads();
  if (t < 32) {
    float a1 = 0.f, a2 = 0.f;
#pragma unroll
    for (int k = 0; k < 8; ++k) { a1 += red[0][k][t]; a2 += red[1][k][t]; }
    float mean = a1 * (1.0f / Cd);
    float var = a2 * (1.0f / Cd) - mean * mean;
    mv[0][t] = mean; mv[1][t] = rsqrtf(var + 1e-5f);
  }
  __syncthreads();
  const float mean = mv[0][wl], rstd = mv[1][wl];
  float* so = &seq[((size_t)(w0 + wl) * NBd + n) * Cd + c0];
  short* bo_ = &lno[((size_t)(w0 + wl) * NBd + n) * Cd + c0];
#pragma unroll
  for (int r = 0; r < 16; ++r) so[r] = v[r];
#pragma unroll
  for (int r = 0; r < 16; ++r)
    bo_[r] = f2bf((v[r] - mean) * rstd * g[c0 + r] + bb[c0 + r]);
}

// ---------------- from_seq: merged for both tensors ----------------
__global__ __launch_bounds__(256) void k_from_seq2(const float* __restrict__ seqA,
                                                   const float* __restrict__ seqB,
                                                   float* __restrict__ featA,
                                                   float* __restrict__ featB) {
  __shared__ float tile[32][33];
  int wi0 = blockIdx.x * 32, ci0 = blockIdx.y * 32;
  int z = blockIdx.z;
  const float* seq = (z < 128) ? seqA : seqB;
  float* feat = (z < 128) ? featA : featB;
  int hb = z & 127;
  int h = hb >> 1, b = hb & 1;
  int n = h * BSd + b;
  int tx = threadIdx.x, ty = threadIdx.y;
#pragma unroll
  for (int r = 0; r < 4; ++r) {
    int wi = wi0 + ty + r * 8;
    tile[ty + r * 8][tx] = seq[((size_t)wi * NBd + n) * Cd + ci0 + tx];
  }
  __syncthreads();
#pragma unroll
  for (int r = 0; r < 4; ++r) {
    int ci = ci0 + ty + r * 8;
    feat[(((size_t)b * Cd + ci) * HNd + h) * Wd + wi0 + tx] = tile[tx][ty + r * 8];
  }
}

// ---------------- one-shot fp32->bf16 weight/pos convert ----------------
__global__ __launch_bounds__(256) void k_cvt(const float* __restrict__ w1, short* d1,  // 49152
                                             const float* __restrict__ w2, short* d2,  // 16384
                                             const float* __restrict__ w3, short* d3)  // 65408
{
  int i = blockIdx.x * 256 + threadIdx.x;
  if (i < 49152) d1[i] = f2bf(w1[i]);
  if (i < 16384) d2[i] = f2bf(w2[i]);
  if (i < 65408) d3[i] = f2bf(w3[i]);
}

// ---------------- bf16 MFMA GEMM, K=128, no LDS, no barriers ----------------
__global__ __launch_bounds__(256) void k_gemm_bf(
    const short* __restrict__ A, const short* __restrict__ Wt,
    const float* __restrict__ bias, float* __restrict__ outF,
    short* __restrict__ outB, int M, int ldout, int scaleN0, float scale,
    const short* __restrict__ A2, short* __restrict__ outB2, int ldout2, int yCut) {
  const int t = threadIdx.x;
  const int lane = t & 63, wv = t >> 6;
  const int ml = lane & 15, quad = lane >> 4;
  const int m0 = blockIdx.x * 64;
  int yb = blockIdx.y;
  const short* Ap = A;
  short* oB = outB;
  float* oF = outF;
  int ld = ldout;
  int nblk = yb;
  if (yb >= yCut) { Ap = A2; oB = outB2; oF = nullptr; ld = ldout2; nblk = 0; }
  const int n0 = nblk * 128 + wv * 32;
  const bf16x8 zero8 = {0, 0, 0, 0, 0, 0, 0, 0};

  bf16x8 Bfr[2][4];
#pragma unroll
  for (int nf = 0; nf < 2; ++nf)
#pragma unroll
    for (int ks = 0; ks < 4; ++ks)
      Bfr[nf][ks] = *(const bf16x8*)&Wt[(size_t)(n0 + nf * 16 + ml) * 128 + ks * 32 + quad * 8];

  f32x4 acc[4][2];
#pragma unroll
  for (int mf = 0; mf < 4; ++mf)
#pragma unroll
    for (int nf = 0; nf < 2; ++nf) acc[mf][nf] = {0.f, 0.f, 0.f, 0.f};

#pragma unroll
  for (int ks = 0; ks < 4; ++ks) {
    bf16x8 Af[4];
#pragma unroll
    for (int mf = 0; mf < 4; ++mf) {
      int m = m0 + mf * 16 + ml;
      Af[mf] = (m < M) ? *(const bf16x8*)&Ap[(size_t)m * 128 + ks * 32 + quad * 8] : zero8;
    }
#pragma unroll
    for (int mf = 0; mf < 4; ++mf)
#pragma unroll
      for (int nf = 0; nf < 2; ++nf)
        acc[mf][nf] = __builtin_amdgcn_mfma_f32_16x16x32_bf16(Af[mf], Bfr[nf][ks], acc[mf][nf], 0, 0, 0);
  }

#pragma unroll
  for (int nf = 0; nf < 2; ++nf) {
    int n = n0 + nf * 16 + ml;
    float bi = bias[n];
    float sc = (n < scaleN0) ? scale : 1.0f;
#pragma unroll
    for (int mf = 0; mf < 4; ++mf) {
#pragma unroll
      for (int r = 0; r < 4; ++r) {
        int m = m0 + mf * 16 + quad * 4 + r;
        if (m >= M) continue;
        float v = (acc[mf][nf][r] + bi) * sc;
        if (oF) oF[(size_t)m * ld + n] = v;
        if (oB) oB[(size_t)m * ld + n] = f2bf(v);
      }
    }
  }
}

// ---------------- Wo GEMM + residual + optional fused LayerNorm ----------------
// A (= attention output) is in OT layout [n][e][i][cc] (see k_attn_mfma); the
// fragment read below maps c = 32*ks + 8*quad -> (e2 = c>>4, off = c&15), which is
// identical to the old contiguous (m,c) read. res/outF/outLN stay in (w,n,c).
__global__ __launch_bounds__(256) void k_gemm_wo_ln(
    const short* __restrict__ A, const short* __restrict__ Wt,
    const float* __restrict__ bias, const float* __restrict__ res,
    float* __restrict__ outF, short* __restrict__ outLN,
    const float* __restrict__ lng, const float* __restrict__ lnb) {
  const int t = threadIdx.x;
  const int lane = t & 63, wv = t >> 6;
  const int ml = lane & 15, quad = lane >> 4;
  const int m0 = blockIdx.x * 64 + wv * 16;
  const int ii = m0 >> 7;              // w index (fixed across the 16 lanes)
  const int nn = (m0 & 127) + ml;      // n index (per-lane)

  f32x4 acc[8];
#pragma unroll
  for (int nf = 0; nf < 8; ++nf) acc[nf] = {0.f, 0.f, 0.f, 0.f};
#pragma unroll
  for (int ks = 0; ks < 4; ++ks) {
    bf16x8 Af = *(const bf16x8*)&A[(((size_t)nn * 8 + ks * 2 + (quad >> 1)) * 256 + ii) * 16 +
                                   (quad & 1) * 8];
#pragma unroll
    for (int nf = 0; nf < 8; ++nf) {
      bf16x8 Bf = *(const bf16x8*)&Wt[(size_t)(nf * 16 + ml) * 128 + ks * 32 + quad * 8];
      acc[nf] = __builtin_amdgcn_mfma_f32_16x16x32_bf16(Af, Bf, acc[nf], 0, 0, 0);
    }
  }
  float val[8][4];
#pragma unroll
  for (int nf = 0; nf < 8; ++nf) {
    float bi = bias[nf * 16 + ml];
#pragma unroll
    for (int r = 0; r < 4; ++r) {
      int m = m0 + quad * 4 + r;
      val[nf][r] = acc[nf][r] + bi + res[(size_t)m * 128 + nf * 16 + ml];
      outF[(size_t)m * 128 + nf * 16 + ml] = val[nf][r];
    }
  }
  if (outLN) {
#pragma unroll
    for (int r = 0; r < 4; ++r) {
      float s1 = 0.f, s2 = 0.f;
#pragma unroll
      for (int nf = 0; nf < 8; ++nf) { s1 += val[nf][r]; s2 += val[nf][r] * val[nf][r]; }
#pragma unroll
      for (int mk = 1; mk < 16; mk <<= 1) { s1 += __shfl_xor(s1, mk); s2 += __shfl_xor(s2, mk); }
      float mean = s1 * (1.0f / 128.f);
      float var = s2 * (1.0f / 128.f) - mean * mean;
      float rstd = rsqrtf(var + 1e-5f);
      int m = m0 + quad * 4 + r;
#pragma unroll
      for (int nf = 0; nf < 8; ++nf) {
        int nn2 = nf * 16 + ml;
        outLN[(size_t)m * 128 + nn2] = f2bf((val[nf][r] - mean) * rstd * lng[nn2] + lnb[nn2]);
      }
    }
  }
}

// ---------------- MFMA fused attention, head-split + i-panel loop ----------------
// Grid (n=128, e=8, ip-pairs=2). K/V^T staged per block, reused across 2 i-panels.
// Round-5: issue-early / use-late split of the consume phase.
//  * Phase A (top of iter i): ALL LDS ops for tile i-1 -- 4 R2 reads, 8
//    ds_bpermute of the held R3 MFMA results, and the PV aVT read -- issue
//    BEFORE the tile-i MFMA cluster + PP global prefetch. The ~120-cycle LDS
//    latency hides under the MFMA/global issue window (round 4 showed 2.7x
//    over the VALU-issue floor from exactly this stall).
//  * aK fragment prefetched one tile ahead (register-carried) so the MFMA
//    cluster never waits on LDS.
//  * Phase B (bottom): exp/pack/PV + R2 write (bank write still AFTER the
//    phase-A reads -- same bank semantics as round 4).
//  * bounds(256,3): VGPR cap ~168 (round-3 lesson: the pipeline spills at 128).
// PASS==2: p = i-j+255. PASS==1: p = j-i+255 (flipped pos).
template <int PASS>
__global__ __launch_bounds__(256, 3) void k_attn_mfma(
    const short* __restrict__ Qg, int ldq,
    const short* __restrict__ Kg, const short* __restrict__ Vg, int ldkv,
    const short* __restrict__ PP, short* __restrict__ OT) {
  __shared__ short Ks[256][16];
  __shared__ short VTs[16][264];
  __shared__ float R2T[4][2][16][20];  // [wave][bank][pm][i + pad4]

  const int t = threadIdx.x;
  const int n = blockIdx.x;
  const int e = blockIdx.y;
  const int lane = t & 63, wv = t >> 6;
  const int ml = lane & 15, quad = lane >> 4;
  const bool lo = lane < 32;
  const bf16x8 zero8 = {0, 0, 0, 0, 0, 0, 0, 0};
  const f32x4 z4 = {0.f, 0.f, 0.f, 0.f};

#pragma unroll
  for (int it = 0; it < 4; ++it) {  // K rows: 256 rows x 4 chunks of 4 shorts
    int idx = t + it * 256;
    int r = idx >> 2, c4 = idx & 3;
    *(bf16x4*)&Ks[r][c4 * 4] =
        *(const bf16x4*)&Kg[((size_t)r * NBd + n) * ldkv + e * 16 + c4 * 4];
  }
#pragma unroll
  for (int it = 0; it < 4; ++it) {  // V transposed: row-linear lanes
    bf16x4 vv = *(const bf16x4*)&Vg[((size_t)t * NBd + n) * ldkv + e * 16 + it * 4];
    VTs[it * 4 + 0][t] = vv[0];
    VTs[it * 4 + 1][t] = vv[1];
    VTs[it * 4 + 2][t] = vv[2];
    VTs[it * 4 + 3][t] = vv[3];
  }
  __syncthreads();

  // Single-register consume base: pcol(r) = pbase -/+ r (r compile-time).
  const int pbase = (PASS == 2) ? (ml - quad * 4 + 15) : (quad * 4 - ml + 15);
  const int qsh = quad << 6;  // bpermute byte addr high part ((quad<<4)<<2)

  const short* PPe = PP + e * 16;
  short* OTb = OT + (size_t)(n * 8 + e) * 256 * 16;

  for (int ipl = 0; ipl < 2; ++ipl) {
    const int i0p = ((int)blockIdx.z * 2 + ipl) * 64;
    const int wb = (PASS == 2) ? i0p : (192 - i0p);
    bf16x8 bQ = lo ? *(const bf16x8*)&Qg[((size_t)(i0p + 16 * wv + ml) * NBd + n) * ldq +
                                         e * 16 + quad * 8]
                   : zero8;
    f32x4 Ot = {0.f, 0.f, 0.f, 0.f};
    float den = 0.f;

    // init "tile -1" R2 half -> bank 1
    bf16x8 fPQprev;
    {
      int pp = (PASS == 2) ? (wb + 16 * wv + 256 + ml) : (wb - 16 * wv + 48 + ml);
      if (pp > 510) pp = 510;
      const short* pr = &PPe[(size_t)pp * 256];
      bf16x8 fPK0 = lo ? *(const bf16x8*)&pr[128 + quad * 8] : zero8;
      fPQprev     = lo ? *(const bf16x8*)&pr[quad * 8] : zero8;
      f32x4 R2i = __builtin_amdgcn_mfma_f32_16x16x32_bf16(bQ, fPK0, z4, 0, 0, 0);
      *(f32x4*)&R2T[wv][1][ml][quad * 4] = R2i;
    }
    // preload PP row for tile 0
    bf16x8 fPK, fPQf;
    {
      int pf = (PASS == 2) ? (wb + 16 * wv + 240 + ml) : (wb - 16 * wv + 64 + ml);
      if (pf > 510) pf = 510;
      const short* prf = &PPe[(size_t)pf * 256];
      fPK  = lo ? *(const bf16x8*)&prf[128 + quad * 8] : zero8;
      fPQf = lo ? *(const bf16x8*)&prf[quad * 8] : zero8;
    }

    // carried (pipelined) tile state
    f32x4 St_p, R3a_p, R3b_p;
    unsigned pA0 = 0, pA1 = 0;
    bf16x8 aKn;  // prefetched K fragment for the next tile

    // ---- compute tile 0 (no consume) ----
    {
      bf16x8 aK = lo ? *(const bf16x8*)&Ks[ml][quad * 8] : zero8;
      St_p = __builtin_amdgcn_mfma_f32_16x16x32_bf16(aK, bQ, z4, 0, 0, 0);
      f32x4 R2c = __builtin_amdgcn_mfma_f32_16x16x32_bf16(bQ, fPK, z4, 0, 0, 0);
      if (PASS == 2) {
        R3a_p = __builtin_amdgcn_mfma_f32_16x16x32_bf16(aK, fPQf, z4, 0, 0, 0);
        R3b_p = __builtin_amdgcn_mfma_f32_16x16x32_bf16(aK, fPQprev, z4, 0, 0, 0);
      } else {
        R3b_p = __builtin_amdgcn_mfma_f32_16x16x32_bf16(aK, fPQf, z4, 0, 0, 0);
        R3a_p = __builtin_amdgcn_mfma_f32_16x16x32_bf16(aK, fPQprev, z4, 0, 0, 0);
      }
      fPQprev = fPQf;
      {  // prefetch PP row for tile 1
        int pf = (PASS == 2) ? (wb + 16 * wv - 16 + 240 + ml) : (wb - 16 * wv + 16 + 64 + ml);
        if (pf > 510) pf = 510;
        const short* prf = &PPe[(size_t)pf * 256];
        fPK  = lo ? *(const bf16x8*)&prf[128 + quad * 8] : zero8;
        fPQf = lo ? *(const bf16x8*)&prf[quad * 8] : zero8;
      }
      aKn = lo ? *(const bf16x8*)&Ks[16 + ml][quad * 8] : zero8;  // prefetch tile 1
      *(f32x4*)&R2T[wv][0][ml][quad * 4] = R2c;
    }

#pragma unroll
    for (int i = 1; i < 16; ++i) {
      const int T = i - 1;
      const int j0 = i * 16;

      // ---- phase A: issue ALL LDS ops for tile T (results used in phase B) ----
      float r2v[4], va[4], vb[4];
#pragma unroll
      for (int r = 0; r < 4; ++r) {
        const int pcol = (PASS == 2) ? (pbase - r) : (pbase + r);
        const int hi = pcol >> 4;
        const int bk = (T & 1) ^ hi ^ (PASS == 1 ? 1 : 0);
        const int ba = ((pcol & 15) << 2) | qsh;
        r2v[r] = R2T[wv][bk][pcol & 15][ml];
        va[r] = __int_as_float(
            __builtin_amdgcn_ds_bpermute(ba, __float_as_int(R3a_p[r])));
        vb[r] = __int_as_float(
            __builtin_amdgcn_ds_bpermute(ba, __float_as_int(R3b_p[r])));
      }
      bf16x8 aVT = zero8;
      if (T & 1) aVT = *(const bf16x8*)&VTs[ml][(T >> 1) * 32 + quad * 8];

      // ---- issue tile i MFMAs (all operands in registers) ----
      bf16x8 aK = aKn;
      f32x4 St_c = __builtin_amdgcn_mfma_f32_16x16x32_bf16(aK, bQ, z4, 0, 0, 0);
      f32x4 R2c  = __builtin_amdgcn_mfma_f32_16x16x32_bf16(bQ, fPK, z4, 0, 0, 0);
      f32x4 R3A, R3B;
      if (PASS == 2) {
        R3A = __builtin_amdgcn_mfma_f32_16x16x32_bf16(aK, fPQf, z4, 0, 0, 0);
        R3B = __builtin_amdgcn_mfma_f32_16x16x32_bf16(aK, fPQprev, z4, 0, 0, 0);
      } else {
        R3B = __builtin_amdgcn_mfma_f32_16x16x32_bf16(aK, fPQf, z4, 0, 0, 0);
        R3A = __builtin_amdgcn_mfma_f32_16x16x32_bf16(aK, fPQprev, z4, 0, 0, 0);
      }
      fPQprev = fPQf;
      if (i < 15) {  // prefetch PP row + K fragment for tile i+1
        int pf = (PASS == 2) ? (wb + 16 * wv - (j0 + 16) + 240 + ml)
                             : (wb - 16 * wv + (j0 + 16) + 64 + ml);
        if (pf > 510) pf = 510;
        const short* prf = &PPe[(size_t)pf * 256];
        fPK  = lo ? *(const bf16x8*)&prf[128 + quad * 8] : zero8;
        fPQf = lo ? *(const bf16x8*)&prf[quad * 8] : zero8;
        aKn = lo ? *(const bf16x8*)&Ks[j0 + 16 + ml][quad * 8] : zero8;
      }

      // ---- phase B: consume tile T with the preloaded values ----
      float pe4[4];
#pragma unroll
      for (int r = 0; r < 4; ++r) {
        const int pcol = (PASS == 2) ? (pbase - r) : (pbase + r);
        const int hi = pcol >> 4;
        float s = St_p[r] + r2v[r] + (hi ? vb[r] : va[r]);
        pe4[r] = __expf(s);
        den += pe4[r];
      }
      unsigned d0, d1;
      asm("v_cvt_pk_bf16_f32 %0, %1, %2" : "=v"(d0) : "v"(pe4[0]), "v"(pe4[1]));
      asm("v_cvt_pk_bf16_f32 %0, %1, %2" : "=v"(d1) : "v"(pe4[2]), "v"(pe4[3]));
      if ((T & 1) == 0) {
        pA0 = d0;
        pA1 = d1;
      } else {
        unsigned b0 = pA0, b2 = d0, b1 = pA1, b3 = d1;
        asm("v_permlane32_swap_b32 %0, %1" : "+v"(b0), "+v"(b2));
        asm("v_permlane16_swap_b32 %0, %1" : "+v"(b0), "+v"(b2));
        asm("v_permlane32_swap_b32 %0, %1" : "+v"(b1), "+v"(b3));
        asm("v_permlane16_swap_b32 %0, %1" : "+v"(b1), "+v"(b3));
        union { unsigned u[4]; bf16x8 v8; } bp;
        bp.u[0] = b0; bp.u[1] = b1; bp.u[2] = b2; bp.u[3] = b3;
        Ot = __builtin_amdgcn_mfma_f32_16x16x32_bf16(aVT, bp.v8, Ot, 0, 0, 0);
      }
      *(f32x4*)&R2T[wv][i & 1][ml][quad * 4] = R2c;
      St_p = St_c; R3a_p = R3A; R3b_p = R3B;
    }

    // ---- epilogue: consume tile 15 (odd -> fires the last PV) ----
    {
      const int T = 15;
      float r2v[4], va[4], vb[4];
#pragma unroll
      for (int r = 0; r < 4; ++r) {
        const int pcol = (PASS == 2) ? (pbase - r) : (pbase + r);
        const int hi = pcol >> 4;
        const int bk = (T & 1) ^ hi ^ (PASS == 1 ? 1 : 0);
        const int ba = ((pcol & 15) << 2) | qsh;
        r2v[r] = R2T[wv][bk][pcol & 15][ml];
        va[r] = __int_as_float(
            __builtin_amdgcn_ds_bpermute(ba, __float_as_int(R3a_p[r])));
        vb[r] = __int_as_float(
            __builtin_amdgcn_ds_bpermute(ba, __float_as_int(R3b_p[r])));
      }
      bf16x8 aVT = *(const bf16x8*)&VTs[ml][(T >> 1) * 32 + quad * 8];
      float pe4[4];
#pragma unroll
      for (int r = 0; r < 4; ++r) {
        const int pcol = (PASS == 2) ? (pbase - r) : (pbase + r);
        const int hi = pcol >> 4;
        float s = St_p[r] + r2v[r] + (hi ? vb[r] : va[r]);
        pe4[r] = __expf(s);
        den += pe4[r];
      }
      unsigned d0, d1;
      asm("v_cvt_pk_bf16_f32 %0, %1, %2" : "=v"(d0) : "v"(pe4[0]), "v"(pe4[1]));
      asm("v_cvt_pk_bf16_f32 %0, %1, %2" : "=v"(d1) : "v"(pe4[2]), "v"(pe4[3]));
      unsigned b0 = pA0, b2 = d0, b1 = pA1, b3 = d1;
      asm("v_permlane32_swap_b32 %0, %1" : "+v"(b0), "+v"(b2));
      asm("v_permlane16_swap_b32 %0, %1" : "+v"(b0), "+v"(b2));
      asm("v_permlane32_swap_b32 %0, %1" : "+v"(b1), "+v"(b3));
      asm("v_permlane16_swap_b32 %0, %1" : "+v"(b1), "+v"(b3));
      union { unsigned u[4]; bf16x8 v8; } bp;
      bp.u[0] = b0; bp.u[1] = b1; bp.u[2] = b2; bp.u[3] = b3;
      Ot = __builtin_amdgcn_mfma_f32_16x16x32_bf16(aVT, bp.v8, Ot, 0, 0, 0);
    }

    den += __shfl_xor(den, 16);
    den += __shfl_xor(den, 32);
    float inv = 1.f / den;
    bf16x4 ob;
    ob[0] = f2bf(Ot[0] * inv); ob[1] = f2bf(Ot[1] * inv);
    ob[2] = f2bf(Ot[2] * inv); ob[3] = f2bf(Ot[3] * inv);
    // OT[n][e][i][cc]: 16 rows x 32B = 512B contiguous per wave store
    *(bf16x4*)&OTb[(size_t)(i0p + 16 * wv + ml) * 16 + quad * 4] = ob;
  }
}

// ---------------- raw = sum_e pre-softmax scores, dense K=128 ----------------
// Banded reuse: R2 second half = prev jq's first-half RESULT (aQ invariant);
// PQ fragments carried across jq (saves loads). Grid (4 i-panels, 128 n, 4 j-quarters).
__global__ __launch_bounds__(256, 4) void k_raw(
    const short* __restrict__ Qf, const short* __restrict__ Kf,
    const short* __restrict__ PP, float* __restrict__ raw) {
  __shared__ float R2s[4][2][16][17];
  __shared__ float R3s[4][16][34];
  const int t = threadIdx.x;
  const int n = blockIdx.y;
  const int lane = t & 63, wv = t >> 6;
  const int ml = lane & 15, quad = lane >> 4;
  const int it0 = blockIdx.x * 64 + wv * 16;
  const int jt0 = blockIdx.z * 4;
  const f32x4 z4 = {0.f, 0.f, 0.f, 0.f};

  bf16x8 aQ[4];
#pragma unroll
  for (int kc = 0; kc < 4; ++kc)
    aQ[kc] = *(const bf16x8*)&Qf[((size_t)(it0 + ml) * NBd + n) * 384 + kc * 32 + quad * 8];

  float* rbase = &raw[(((size_t)(n & 1) * HNd + (n >> 1)) * Wd + it0) * Wd];

  bf16x8 fPQprev[4];
  {
    int pp = it0 - jt0 * 16 + 256 + ml;
    if (pp > 510) pp = 510;
    const short* pr = &PP[(size_t)pp * 256];
    f32x4 R2i = z4;
#pragma unroll
    for (int kc = 0; kc < 4; ++kc) {
      bf16x8 fPK = *(const bf16x8*)&pr[128 + kc * 32 + quad * 8];
      R2i = __builtin_amdgcn_mfma_f32_16x16x32_bf16(aQ[kc], fPK, R2i, 0, 0, 0);
      fPQprev[kc] = *(const bf16x8*)&pr[kc * 32 + quad * 8];
    }
#pragma unroll
    for (int r = 0; r < 4; ++r) R2s[wv][1][quad * 4 + r][ml] = R2i[r];
  }

#pragma unroll
  for (int jq = 0; jq < 4; ++jq) {
    const int j0 = (jt0 + jq) * 16;
    bf16x8 aK[4];
#pragma unroll
    for (int kc = 0; kc < 4; ++kc)
      aK[kc] = *(const bf16x8*)&Kf[((size_t)(j0 + ml) * NBd + n) * 256 + kc * 32 + quad * 8];
    const int p0 = it0 - j0 + 240 + ml;  // in [0,495] always
    const short* pr0 = &PP[(size_t)p0 * 256];
    f32x4 St = z4, R2f = z4, R3a = z4, R3b = z4;
    bf16x8 fPQ0[4];
#pragma unroll
    for (int kc = 0; kc < 4; ++kc)
      St = __builtin_amdgcn_mfma_f32_16x16x32_bf16(aQ[kc], aK[kc], St, 0, 0, 0);
#pragma unroll
    for (int kc = 0; kc < 4; ++kc) {
      bf16x8 fPK0 = *(const bf16x8*)&pr0[128 + kc * 32 + quad * 8];
      R2f = __builtin_amdgcn_mfma_f32_16x16x32_bf16(aQ[kc], fPK0, R2f, 0, 0, 0);
    }
#pragma unroll
    for (int kc = 0; kc < 4; ++kc) {
      fPQ0[kc] = *(const bf16x8*)&pr0[kc * 32 + quad * 8];
      R3a = __builtin_amdgcn_mfma_f32_16x16x32_bf16(aK[kc], fPQ0[kc], R3a, 0, 0, 0);
    }
#pragma unroll
    for (int kc = 0; kc < 4; ++kc)
      R3b = __builtin_amdgcn_mfma_f32_16x16x32_bf16(aK[kc], fPQprev[kc], R3b, 0, 0, 0);
#pragma unroll
    for (int kc = 0; kc < 4; ++kc) fPQprev[kc] = fPQ0[kc];
#pragma unroll
    for (int r = 0; r < 4; ++r) {
      R2s[wv][jq & 1][quad * 4 + r][ml] = R2f[r];
      R3s[wv][quad * 4 + r][ml]      = R3a[r];
      R3s[wv][quad * 4 + r][ml + 16] = R3b[r];
    }
#pragma unroll
    for (int r = 0; r < 4; ++r) {
      const int il = quad * 4 + r;
      const int pcol = il - ml + 15;
      const int hi = pcol >> 4, col = pcol & 15;
      const int bk = (jq & 1) ^ hi;
      rbase[(size_t)il * Wd + j0 + ml] = St[r] + R2s[wv][bk][il][col] + R3s[wv][ml][pcol];
    }
  }
}

extern "C" void kernel_launch(void* const* d_in, const int* in_sizes, int n_in,
                              void* d_out, int out_size, void* d_ws, size_t ws_size,
                              hipStream_t stream) {
  const float* feat_l = (const float*)d_in[0];
  const float* feat_r = (const float*)d_in[1];
  const float* pos    = (const float*)d_in[2];
  // d_in[3] = pos_indexes (int) -- structure known analytically, unused.
  const float* Wqkv = (const float*)d_in[4];
  const float* bqkv = (const float*)d_in[5];
  const float* Wo   = (const float*)d_in[6];
  const float* bo   = (const float*)d_in[7];
  const float* g1   = (const float*)d_in[8];
  const float* b1   = (const float*)d_in[9];
  const float* g2   = (const float*)d_in[10];
  const float* b2   = (const float*)d_in[11];
  float* out = (float*)d_out;

  float* ws = (float*)d_ws;
  float* fl_seq = ws;                 // fp32
  float* fr_seq = ws + SEQF;          // fp32
  float* fr2_f  = ws + 2 * SEQF;      // fp32 (fr_new)
  float* fl_new = ws + 3 * SEQF;      // fp32
  short* wsb    = (short*)(ws + 4 * SEQF);
  short* fl2_b   = wsb;               // SEQF bf16
  short* fr2_b   = wsb + SEQF;
  short* frb2_b  = wsb + 2 * SEQF;
  short* QKVl_b  = wsb + 3 * SEQF;    // 3*SEQF
  short* Qr_b    = wsb + 6 * SEQF;
  short* KVr2_b  = wsb + 7 * SEQF;    // 2*SEQF
  short* O_b     = wsb + 9 * SEQF;    // OT layout [n][e][i][cc]
  short* PP_b    = wsb + 10 * SEQF;   // 511*256
  short* Wb      = PP_b + 131072;     // Wqkv (49152) then Wo (16384)
  short* pos_b   = Wb + 65536;        // 511*128

  // to_seq + LN(g1,b1) fused, both tensors
  k_to_seq_ln<<<dim3(8, 256), 256, 0, stream>>>(feat_l, feat_r, fl_seq, fr_seq,
                                                fl2_b, fr2_b, g1, b1);
  k_cvt<<<256, 256, 0, stream>>>(Wqkv, Wb, Wo, Wb + 49152, pos, pos_b);

  // PP = [PQ(scaled)|PK] projections of the 511 pos rows (bf16 out)
  k_gemm_bf<<<dim3(8, 2), 256, 0, stream>>>(pos_b, Wb, bqkv, nullptr, PP_b,
                                            511, 256, 128, 0.25f,
                                            nullptr, nullptr, 0, 999);
  // QKV of fl2 (Q scaled) + Q of fr2 (scaled), merged
  k_gemm_bf<<<dim3(512, 4), 256, 0, stream>>>(fl2_b, Wb, bqkv, nullptr, QKVl_b,
                                              32768, 384, 128, 0.25f,
                                              fr2_b, Qr_b, 128, 3);

  // mha1: q=fr2-proj, kv=fl2-proj, flipped pos => p = j-i+255
  k_attn_mfma<1><<<dim3(128, 8, 2), 256, 0, stream>>>(
      Qr_b, Cd, QKVl_b + 128, QKVl_b + 256, 384, PP_b, O_b);
  // fr_new = fr_seq + O @ Wo^T + bo  (+ fused LN(g2,b2) -> frb2_b)
  k_gemm_wo_ln<<<512, 256, 0, stream>>>(O_b, Wb + 49152, bo, fr_seq, fr2_f,
                                        frb2_b, g2, b2);
  // KV of frb2
  k_gemm_bf<<<dim3(512, 2), 256, 0, stream>>>(frb2_b, Wb + 16384, bqkv + 128, nullptr,
                                              KVr2_b, 32768, 256, 0, 1.0f,
                                              nullptr, nullptr, 0, 999);
  // mha2: q=fl2-proj (in QKVl), kv=frb2-proj; p = i-j+255
  k_attn_mfma<2><<<dim3(128, 8, 2), 256, 0, stream>>>(
      QKVl_b, 384, KVr2_b, KVr2_b + 128, 256, PP_b, O_b);
  // raw = sum over heads of pre-softmax scores (dense K=128 formulation)
  k_raw<<<dim3(4, 128, 4), 256, 0, stream>>>(QKVl_b, KVr2_b, PP_b, out + 2 * SEQF);
  // fl_new = fl_seq + O @ Wo^T + bo (no LN)
  k_gemm_wo_ln<<<512, 256, 0, stream>>>(O_b, Wb + 49152, bo, fl_seq, fl_new,
                                        nullptr, nullptr, nullptr);

  k_from_seq2<<<dim3(8, 4, 256), dim3(32, 8), 0, stream>>>(fl_new, fr2_f, out, out + SEQF);

  (void)in_sizes; (void)n_in; (void)out_size; (void)ws_size;
}

// Round 6
// 390.346 us; speedup vs baseline: 1.2610x; 1.0014x over previous
//
#include <hip/hip_runtime.h>
#include <cstddef>

// Problem constants (fixed by setup_inputs)
static constexpr int Wd  = 256;   // sequence length (width)
static constexpr int NBd = 128;   // batch = hn*bs
static constexpr int Cd  = 128;   // channels
static constexpr int BSd = 2;     // bs
static constexpr int HNd = 64;    // hn
static constexpr size_t SEQF = (size_t)Wd * NBd * Cd;  // 4,194,304 elements

typedef __attribute__((ext_vector_type(8))) short bf16x8;
typedef __attribute__((ext_vector_type(4))) short bf16x4;
typedef __attribute__((ext_vector_type(4))) float f32x4;
typedef __attribute__((ext_vector_type(2))) float f32x2;

__device__ inline short f2bf(float f) {
  union { float f; unsigned u; } v; v.f = f;
  return (short)((v.u + 0x7FFFu + ((v.u >> 16) & 1u)) >> 16);
}

// ---------------- fused to_seq + LayerNorm ----------------
// feat (bs,c,hn,w) -> seq fp32 (w,n,c) AND ln(seq) bf16. grid (8 wtiles, 256 z).
__global__ __launch_bounds__(256) void k_to_seq_ln(
    const float* __restrict__ fA, const float* __restrict__ fB,
    float* __restrict__ seqA, float* __restrict__ seqB,
    short* __restrict__ lnA, short* __restrict__ lnB,
    const float* __restrict__ g, const float* __restrict__ bb) {
  __shared__ float red[2][8][33];
  __shared__ float mv[2][32];
  const int z = blockIdx.y;
  const float* feat = (z < 128) ? fA : fB;
  float* seq = (z < 128) ? seqA : seqB;
  short* lno = (z < 128) ? lnA : lnB;
  const int hb = z & 127;
  const int h = hb >> 1, b = hb & 1;
  const int n = h * BSd + b;
  const int w0 = blockIdx.x * 32;
  const int t = threadIdx.x;
  const int wl = t & 31, cg = t >> 5, c0 = cg * 16;
  float v[16];
  float s1 = 0.f, s2 = 0.f;
#pragma unroll
  for (int r = 0; r < 16; ++r) {
    v[r] = feat[(((size_t)b * Cd + c0 + r) * HNd + h) * Wd + w0 + wl];
    s1 += v[r]; s2 += v[r] * v[r];
  }
  red[0][cg][wl] = s1; red[1][cg][wl] = s2;
  __syncthreads();
  if (t < 32) {
    float a1 = 0.f, a2 = 0.f;
#pragma unroll
    for (int k = 0; k < 8; ++k) { a1 += red[0][k][t]; a2 += red[1][k][t]; }
    float mean = a1 * (1.0f / Cd);
    float var = a2 * (1.0f / Cd) - mean * mean;
    mv[0][t] = mean; mv[1][t] = rsqrtf(var + 1e-5f);
  }
  __syncthreads();
  const float mean = mv[0][wl], rstd = mv[1][wl];
  float* so = &seq[((size_t)(w0 + wl) * NBd + n) * Cd + c0];
  short* bo_ = &lno[((size_t)(w0 + wl) * NBd + n) * Cd + c0];
#pragma unroll
  for (int r = 0; r < 16; ++r) so[r] = v[r];
#pragma unroll
  for (int r = 0; r < 16; ++r)
    bo_[r] = f2bf((v[r] - mean) * rstd * g[c0 + r] + bb[c0 + r]);
}

// ---------------- from_seq: merged for both tensors ----------------
__global__ __launch_bounds__(256) void k_from_seq2(const float* __restrict__ seqA,
                                                   const float* __restrict__ seqB,
                                                   float* __restrict__ featA,
                                                   float* __restrict__ featB) {
  __shared__ float tile[32][33];
  int wi0 = blockIdx.x * 32, ci0 = blockIdx.y * 32;
  int z = blockIdx.z;
  const float* seq = (z < 128) ? seqA : seqB;
  float* feat = (z < 128) ? featA : featB;
  int hb = z & 127;
  int h = hb >> 1, b = hb & 1;
  int n = h * BSd + b;
  int tx = threadIdx.x, ty = threadIdx.y;
#pragma unroll
  for (int r = 0; r < 4; ++r) {
    int wi = wi0 + ty + r * 8;
    tile[ty + r * 8][tx] = seq[((size_t)wi * NBd + n) * Cd + ci0 + tx];
  }
  __syncthreads();
#pragma unroll
  for (int r = 0; r < 4; ++r) {
    int ci = ci0 + ty + r * 8;
    feat[(((size_t)b * Cd + ci) * HNd + h) * Wd + wi0 + tx] = tile[tx][ty + r * 8];
  }
}

// ---------------- one-shot fp32->bf16 weight/pos convert ----------------
__global__ __launch_bounds__(256) void k_cvt(const float* __restrict__ w1, short* d1,  // 49152
                                             const float* __restrict__ w2, short* d2,  // 16384
                                             const float* __restrict__ w3, short* d3)  // 65408
{
  int i = blockIdx.x * 256 + threadIdx.x;
  if (i < 49152) d1[i] = f2bf(w1[i]);
  if (i < 16384) d2[i] = f2bf(w2[i]);
  if (i < 65408) d3[i] = f2bf(w3[i]);
}

// ---------------- bf16 MFMA GEMM, K=128, no LDS, no barriers ----------------
__global__ __launch_bounds__(256) void k_gemm_bf(
    const short* __restrict__ A, const short* __restrict__ Wt,
    const float* __restrict__ bias, float* __restrict__ outF,
    short* __restrict__ outB, int M, int ldout, int scaleN0, float scale,
    const short* __restrict__ A2, short* __restrict__ outB2, int ldout2, int yCut) {
  const int t = threadIdx.x;
  const int lane = t & 63, wv = t >> 6;
  const int ml = lane & 15, quad = lane >> 4;
  const int m0 = blockIdx.x * 64;
  int yb = blockIdx.y;
  const short* Ap = A;
  short* oB = outB;
  float* oF = outF;
  int ld = ldout;
  int nblk = yb;
  if (yb >= yCut) { Ap = A2; oB = outB2; oF = nullptr; ld = ldout2; nblk = 0; }
  const int n0 = nblk * 128 + wv * 32;
  const bf16x8 zero8 = {0, 0, 0, 0, 0, 0, 0, 0};

  bf16x8 Bfr[2][4];
#pragma unroll
  for (int nf = 0; nf < 2; ++nf)
#pragma unroll
    for (int ks = 0; ks < 4; ++ks)
      Bfr[nf][ks] = *(const bf16x8*)&Wt[(size_t)(n0 + nf * 16 + ml) * 128 + ks * 32 + quad * 8];

  f32x4 acc[4][2];
#pragma unroll
  for (int mf = 0; mf < 4; ++mf)
#pragma unroll
    for (int nf = 0; nf < 2; ++nf) acc[mf][nf] = {0.f, 0.f, 0.f, 0.f};

#pragma unroll
  for (int ks = 0; ks < 4; ++ks) {
    bf16x8 Af[4];
#pragma unroll
    for (int mf = 0; mf < 4; ++mf) {
      int m = m0 + mf * 16 + ml;
      Af[mf] = (m < M) ? *(const bf16x8*)&Ap[(size_t)m * 128 + ks * 32 + quad * 8] : zero8;
    }
#pragma unroll
    for (int mf = 0; mf < 4; ++mf)
#pragma unroll
      for (int nf = 0; nf < 2; ++nf)
        acc[mf][nf] = __builtin_amdgcn_mfma_f32_16x16x32_bf16(Af[mf], Bfr[nf][ks], acc[mf][nf], 0, 0, 0);
  }

#pragma unroll
  for (int nf = 0; nf < 2; ++nf) {
    int n = n0 + nf * 16 + ml;
    float bi = bias[n];
    float sc = (n < scaleN0) ? scale : 1.0f;
#pragma unroll
    for (int mf = 0; mf < 4; ++mf) {
#pragma unroll
      for (int r = 0; r < 4; ++r) {
        int m = m0 + mf * 16 + quad * 4 + r;
        if (m >= M) continue;
        float v = (acc[mf][nf][r] + bi) * sc;
        if (oF) oF[(size_t)m * ld + n] = v;
        if (oB) oB[(size_t)m * ld + n] = f2bf(v);
      }
    }
  }
}

// ---------------- Wo GEMM + residual + optional fused LayerNorm ----------------
// A (= attention output) is in OT layout [n][e][i][cc] (see k_attn_mfma); the
// fragment read below maps c = 32*ks + 8*quad -> (e2 = c>>4, off = c&15), which is
// identical to the old contiguous (m,c) read. res/outF/outLN stay in (w,n,c).
__global__ __launch_bounds__(256) void k_gemm_wo_ln(
    const short* __restrict__ A, const short* __restrict__ Wt,
    const float* __restrict__ bias, const float* __restrict__ res,
    float* __restrict__ outF, short* __restrict__ outLN,
    const float* __restrict__ lng, const float* __restrict__ lnb) {
  const int t = threadIdx.x;
  const int lane = t & 63, wv = t >> 6;
  const int ml = lane & 15, quad = lane >> 4;
  const int m0 = blockIdx.x * 64 + wv * 16;
  const int ii = m0 >> 7;              // w index (fixed across the 16 lanes)
  const int nn = (m0 & 127) + ml;      // n index (per-lane)

  f32x4 acc[8];
#pragma unroll
  for (int nf = 0; nf < 8; ++nf) acc[nf] = {0.f, 0.f, 0.f, 0.f};
#pragma unroll
  for (int ks = 0; ks < 4; ++ks) {
    bf16x8 Af = *(const bf16x8*)&A[(((size_t)nn * 8 + ks * 2 + (quad >> 1)) * 256 + ii) * 16 +
                                   (quad & 1) * 8];
#pragma unroll
    for (int nf = 0; nf < 8; ++nf) {
      bf16x8 Bf = *(const bf16x8*)&Wt[(size_t)(nf * 16 + ml) * 128 + ks * 32 + quad * 8];
      acc[nf] = __builtin_amdgcn_mfma_f32_16x16x32_bf16(Af, Bf, acc[nf], 0, 0, 0);
    }
  }
  float val[8][4];
#pragma unroll
  for (int nf = 0; nf < 8; ++nf) {
    float bi = bias[nf * 16 + ml];
#pragma unroll
    for (int r = 0; r < 4; ++r) {
      int m = m0 + quad * 4 + r;
      val[nf][r] = acc[nf][r] + bi + res[(size_t)m * 128 + nf * 16 + ml];
      outF[(size_t)m * 128 + nf * 16 + ml] = val[nf][r];
    }
  }
  if (outLN) {
#pragma unroll
    for (int r = 0; r < 4; ++r) {
      float s1 = 0.f, s2 = 0.f;
#pragma unroll
      for (int nf = 0; nf < 8; ++nf) { s1 += val[nf][r]; s2 += val[nf][r] * val[nf][r]; }
#pragma unroll
      for (int mk = 1; mk < 16; mk <<= 1) { s1 += __shfl_xor(s1, mk); s2 += __shfl_xor(s2, mk); }
      float mean = s1 * (1.0f / 128.f);
      float var = s2 * (1.0f / 128.f) - mean * mean;
      float rstd = rsqrtf(var + 1e-5f);
      int m = m0 + quad * 4 + r;
#pragma unroll
      for (int nf = 0; nf < 8; ++nf) {
        int nn2 = nf * 16 + ml;
        outLN[(size_t)m * 128 + nn2] = f2bf((val[nf][r] - mean) * rstd * lng[nn2] + lnb[nn2]);
      }
    }
  }
}

// ---------------- MFMA fused attention, head-split + i-panel loop ----------------
// Grid (n=128, e=8, ip-pairs=2). K/V^T staged per block, reused across 2 i-panels.
// Round-5 structure (kept): issue-early / use-late split of the consume phase.
//  * Phase A (top of iter i): ALL LDS ops for tile i-1 issue BEFORE the tile-i
//    MFMA cluster + PP global prefetch (hides ~120-cycle LDS latency).
//  * aK fragment prefetched one tile ahead; R3 via ds_bpermute; R2 2-bank LDS.
//  * bounds(256,3): VGPR cap ~168 (spills at 128).
// PASS==2: p = i-j+255. PASS==1: p = j-i+255 (flipped pos).
template <int PASS>
__global__ __launch_bounds__(256, 3) void k_attn_mfma(
    const short* __restrict__ Qg, int ldq,
    const short* __restrict__ Kg, const short* __restrict__ Vg, int ldkv,
    const short* __restrict__ PP, short* __restrict__ OT) {
  __shared__ short Ks[256][16];
  __shared__ short VTs[16][264];
  __shared__ float R2T[4][2][16][20];  // [wave][bank][pm][i + pad4]

  const int t = threadIdx.x;
  const int n = blockIdx.x;
  const int e = blockIdx.y;
  const int lane = t & 63, wv = t >> 6;
  const int ml = lane & 15, quad = lane >> 4;
  const bool lo = lane < 32;
  const bf16x8 zero8 = {0, 0, 0, 0, 0, 0, 0, 0};
  const f32x4 z4 = {0.f, 0.f, 0.f, 0.f};

#pragma unroll
  for (int it = 0; it < 4; ++it) {  // K rows: 256 rows x 4 chunks of 4 shorts
    int idx = t + it * 256;
    int r = idx >> 2, c4 = idx & 3;
    *(bf16x4*)&Ks[r][c4 * 4] =
        *(const bf16x4*)&Kg[((size_t)r * NBd + n) * ldkv + e * 16 + c4 * 4];
  }
#pragma unroll
  for (int it = 0; it < 4; ++it) {  // V transposed: row-linear lanes
    bf16x4 vv = *(const bf16x4*)&Vg[((size_t)t * NBd + n) * ldkv + e * 16 + it * 4];
    VTs[it * 4 + 0][t] = vv[0];
    VTs[it * 4 + 1][t] = vv[1];
    VTs[it * 4 + 2][t] = vv[2];
    VTs[it * 4 + 3][t] = vv[3];
  }
  __syncthreads();

  // Single-register consume base: pcol(r) = pbase -/+ r (r compile-time).
  const int pbase = (PASS == 2) ? (ml - quad * 4 + 15) : (quad * 4 - ml + 15);
  const int qsh = quad << 6;  // bpermute byte addr high part ((quad<<4)<<2)

  const short* PPe = PP + e * 16;
  short* OTb = OT + (size_t)(n * 8 + e) * 256 * 16;

  for (int ipl = 0; ipl < 2; ++ipl) {
    const int i0p = ((int)blockIdx.z * 2 + ipl) * 64;
    const int wb = (PASS == 2) ? i0p : (192 - i0p);
    bf16x8 bQ = lo ? *(const bf16x8*)&Qg[((size_t)(i0p + 16 * wv + ml) * NBd + n) * ldq +
                                         e * 16 + quad * 8]
                   : zero8;
    f32x4 Ot = {0.f, 0.f, 0.f, 0.f};
    float den = 0.f;

    // init "tile -1" R2 half -> bank 1
    bf16x8 fPQprev;
    {
      int pp = (PASS == 2) ? (wb + 16 * wv + 256 + ml) : (wb - 16 * wv + 48 + ml);
      if (pp > 510) pp = 510;
      const short* pr = &PPe[(size_t)pp * 256];
      bf16x8 fPK0 = lo ? *(const bf16x8*)&pr[128 + quad * 8] : zero8;
      fPQprev     = lo ? *(const bf16x8*)&pr[quad * 8] : zero8;
      f32x4 R2i = __builtin_amdgcn_mfma_f32_16x16x32_bf16(bQ, fPK0, z4, 0, 0, 0);
      *(f32x4*)&R2T[wv][1][ml][quad * 4] = R2i;
    }
    // preload PP row for tile 0
    bf16x8 fPK, fPQf;
    {
      int pf = (PASS == 2) ? (wb + 16 * wv + 240 + ml) : (wb - 16 * wv + 64 + ml);
      if (pf > 510) pf = 510;
      const short* prf = &PPe[(size_t)pf * 256];
      fPK  = lo ? *(const bf16x8*)&prf[128 + quad * 8] : zero8;
      fPQf = lo ? *(const bf16x8*)&prf[quad * 8] : zero8;
    }

    // carried (pipelined) tile state
    f32x4 St_p, R3a_p, R3b_p;
    unsigned pA0 = 0, pA1 = 0;
    bf16x8 aKn;  // prefetched K fragment for the next tile

    // ---- compute tile 0 (no consume) ----
    {
      bf16x8 aK = lo ? *(const bf16x8*)&Ks[ml][quad * 8] : zero8;
      St_p = __builtin_amdgcn_mfma_f32_16x16x32_bf16(aK, bQ, z4, 0, 0, 0);
      f32x4 R2c = __builtin_amdgcn_mfma_f32_16x16x32_bf16(bQ, fPK, z4, 0, 0, 0);
      if (PASS == 2) {
        R3a_p = __builtin_amdgcn_mfma_f32_16x16x32_bf16(aK, fPQf, z4, 0, 0, 0);
        R3b_p = __builtin_amdgcn_mfma_f32_16x16x32_bf16(aK, fPQprev, z4, 0, 0, 0);
      } else {
        R3b_p = __builtin_amdgcn_mfma_f32_16x16x32_bf16(aK, fPQf, z4, 0, 0, 0);
        R3a_p = __builtin_amdgcn_mfma_f32_16x16x32_bf16(aK, fPQprev, z4, 0, 0, 0);
      }
      fPQprev = fPQf;
      {  // prefetch PP row for tile 1
        int pf = (PASS == 2) ? (wb + 16 * wv - 16 + 240 + ml) : (wb - 16 * wv + 16 + 64 + ml);
        if (pf > 510) pf = 510;
        const short* prf = &PPe[(size_t)pf * 256];
        fPK  = lo ? *(const bf16x8*)&prf[128 + quad * 8] : zero8;
        fPQf = lo ? *(const bf16x8*)&prf[quad * 8] : zero8;
      }
      aKn = lo ? *(const bf16x8*)&Ks[16 + ml][quad * 8] : zero8;  // prefetch tile 1
      *(f32x4*)&R2T[wv][0][ml][quad * 4] = R2c;
    }

#pragma unroll
    for (int i = 1; i < 16; ++i) {
      const int T = i - 1;
      const int j0 = i * 16;

      // ---- phase A: issue ALL LDS ops for tile T (results used in phase B) ----
      float r2v[4], va[4], vb[4];
#pragma unroll
      for (int r = 0; r < 4; ++r) {
        const int pcol = (PASS == 2) ? (pbase - r) : (pbase + r);
        const int hi = pcol >> 4;
        const int bk = (T & 1) ^ hi ^ (PASS == 1 ? 1 : 0);
        const int ba = ((pcol & 15) << 2) | qsh;
        r2v[r] = R2T[wv][bk][pcol & 15][ml];
        va[r] = __int_as_float(
            __builtin_amdgcn_ds_bpermute(ba, __float_as_int(R3a_p[r])));
        vb[r] = __int_as_float(
            __builtin_amdgcn_ds_bpermute(ba, __float_as_int(R3b_p[r])));
      }
      bf16x8 aVT = zero8;
      if (T & 1) aVT = *(const bf16x8*)&VTs[ml][(T >> 1) * 32 + quad * 8];

      // ---- issue tile i MFMAs (all operands in registers) ----
      bf16x8 aK = aKn;
      f32x4 St_c = __builtin_amdgcn_mfma_f32_16x16x32_bf16(aK, bQ, z4, 0, 0, 0);
      f32x4 R2c  = __builtin_amdgcn_mfma_f32_16x16x32_bf16(bQ, fPK, z4, 0, 0, 0);
      f32x4 R3A, R3B;
      if (PASS == 2) {
        R3A = __builtin_amdgcn_mfma_f32_16x16x32_bf16(aK, fPQf, z4, 0, 0, 0);
        R3B = __builtin_amdgcn_mfma_f32_16x16x32_bf16(aK, fPQprev, z4, 0, 0, 0);
      } else {
        R3B = __builtin_amdgcn_mfma_f32_16x16x32_bf16(aK, fPQf, z4, 0, 0, 0);
        R3A = __builtin_amdgcn_mfma_f32_16x16x32_bf16(aK, fPQprev, z4, 0, 0, 0);
      }
      fPQprev = fPQf;
      if (i < 15) {  // prefetch PP row + K fragment for tile i+1
        int pf = (PASS == 2) ? (wb + 16 * wv - (j0 + 16) + 240 + ml)
                             : (wb - 16 * wv + (j0 + 16) + 64 + ml);
        if (pf > 510) pf = 510;
        const short* prf = &PPe[(size_t)pf * 256];
        fPK  = lo ? *(const bf16x8*)&prf[128 + quad * 8] : zero8;
        fPQf = lo ? *(const bf16x8*)&prf[quad * 8] : zero8;
        aKn = lo ? *(const bf16x8*)&Ks[j0 + 16 + ml][quad * 8] : zero8;
      }

      // ---- phase B: consume tile T with the preloaded values ----
      float pe4[4];
#pragma unroll
      for (int r = 0; r < 4; ++r) {
        const int pcol = (PASS == 2) ? (pbase - r) : (pbase + r);
        const int hi = pcol >> 4;
        float s = St_p[r] + r2v[r] + (hi ? vb[r] : va[r]);
        pe4[r] = __expf(s);
        den += pe4[r];
      }
      unsigned d0, d1;
      asm("v_cvt_pk_bf16_f32 %0, %1, %2" : "=v"(d0) : "v"(pe4[0]), "v"(pe4[1]));
      asm("v_cvt_pk_bf16_f32 %0, %1, %2" : "=v"(d1) : "v"(pe4[2]), "v"(pe4[3]));
      if ((T & 1) == 0) {
        pA0 = d0;
        pA1 = d1;
      } else {
        unsigned b0 = pA0, b2 = d0, b1 = pA1, b3 = d1;
        asm("v_permlane32_swap_b32 %0, %1" : "+v"(b0), "+v"(b2));
        asm("v_permlane16_swap_b32 %0, %1" : "+v"(b0), "+v"(b2));
        asm("v_permlane32_swap_b32 %0, %1" : "+v"(b1), "+v"(b3));
        asm("v_permlane16_swap_b32 %0, %1" : "+v"(b1), "+v"(b3));
        union { unsigned u[4]; bf16x8 v8; } bp;
        bp.u[0] = b0; bp.u[1] = b1; bp.u[2] = b2; bp.u[3] = b3;
        Ot = __builtin_amdgcn_mfma_f32_16x16x32_bf16(aVT, bp.v8, Ot, 0, 0, 0);
      }
      *(f32x4*)&R2T[wv][i & 1][ml][quad * 4] = R2c;
      St_p = St_c; R3a_p = R3A; R3b_p = R3B;
    }

    // ---- epilogue: consume tile 15 (odd -> fires the last PV) ----
    {
      const int T = 15;
      float r2v[4], va[4], vb[4];
#pragma unroll
      for (int r = 0; r < 4; ++r) {
        const int pcol = (PASS == 2) ? (pbase - r) : (pbase + r);
        const int hi = pcol >> 4;
        const int bk = (T & 1) ^ hi ^ (PASS == 1 ? 1 : 0);
        const int ba = ((pcol & 15) << 2) | qsh;
        r2v[r] = R2T[wv][bk][pcol & 15][ml];
        va[r] = __int_as_float(
            __builtin_amdgcn_ds_bpermute(ba, __float_as_int(R3a_p[r])));
        vb[r] = __int_as_float(
            __builtin_amdgcn_ds_bpermute(ba, __float_as_int(R3b_p[r])));
      }
      bf16x8 aVT = *(const bf16x8*)&VTs[ml][(T >> 1) * 32 + quad * 8];
      float pe4[4];
#pragma unroll
      for (int r = 0; r < 4; ++r) {
        const int pcol = (PASS == 2) ? (pbase - r) : (pbase + r);
        const int hi = pcol >> 4;
        float s = St_p[r] + r2v[r] + (hi ? vb[r] : va[r]);
        pe4[r] = __expf(s);
        den += pe4[r];
      }
      unsigned d0, d1;
      asm("v_cvt_pk_bf16_f32 %0, %1, %2" : "=v"(d0) : "v"(pe4[0]), "v"(pe4[1]));
      asm("v_cvt_pk_bf16_f32 %0, %1, %2" : "=v"(d1) : "v"(pe4[2]), "v"(pe4[3]));
      unsigned b0 = pA0, b2 = d0, b1 = pA1, b3 = d1;
      asm("v_permlane32_swap_b32 %0, %1" : "+v"(b0), "+v"(b2));
      asm("v_permlane16_swap_b32 %0, %1" : "+v"(b0), "+v"(b2));
      asm("v_permlane32_swap_b32 %0, %1" : "+v"(b1), "+v"(b3));
      asm("v_permlane16_swap_b32 %0, %1" : "+v"(b1), "+v"(b3));
      union { unsigned u[4]; bf16x8 v8; } bp;
      bp.u[0] = b0; bp.u[1] = b1; bp.u[2] = b2; bp.u[3] = b3;
      Ot = __builtin_amdgcn_mfma_f32_16x16x32_bf16(aVT, bp.v8, Ot, 0, 0, 0);
    }

    den += __shfl_xor(den, 16);
    den += __shfl_xor(den, 32);
    float inv = 1.f / den;
    bf16x4 ob;
    ob[0] = f2bf(Ot[0] * inv); ob[1] = f2bf(Ot[1] * inv);
    ob[2] = f2bf(Ot[2] * inv); ob[3] = f2bf(Ot[3] * inv);
    // OT[n][e][i][cc]: 16 rows x 32B = 512B contiguous per wave store
    *(bf16x4*)&OTb[(size_t)(i0p + 16 * wv + ml) * 16 + quad * 4] = ob;
  }
}

// ---------------- raw = sum_e pre-softmax scores, dense K=128 ----------------
// Round-6 rewrite: attn-style 1-tile-delayed pipeline (round 4/5 counters showed
// this kernel at 60us with ALL pipes <12% -- pure latency serialization).
//  * Iteration i issues tile-i MFMAs (aK + 8 PP fragments prefetched one tile
//    ahead; those 16-segment L2 gathers were the stall) and consumes tile i-1.
//  * LDS score tiles stored TRANSPOSED + 2-banked: R2T[bank][pm][i+pad4] and
//    R3T[bank][p'][j+pad4] -- 12 scalar b32 writes -> 3x ds_write_b128; read
//    banks <=2-way (free). Consume reads (phase A) precede the bank overwrite
//    (same-wave DS order), exactly the attn discipline.
//  * bounds(256,3): live set ~120 regs; cap-128 would spill (round-3 lesson).
// Grid (4 i-panels, 128 n, 4 j-quarters) unchanged.
__global__ __launch_bounds__(256, 3) void k_raw(
    const short* __restrict__ Qf, const short* __restrict__ Kf,
    const short* __restrict__ PP, float* __restrict__ raw) {
  __shared__ float R2T[4][2][16][20];  // [wave][bank][pm][i + pad4]
  __shared__ float R3T[4][2][32][20];  // [wave][bank][p'][j + pad4]
  const int t = threadIdx.x;
  const int n = blockIdx.y;
  const int lane = t & 63, wv = t >> 6;
  const int ml = lane & 15, quad = lane >> 4;
  const int it0 = blockIdx.x * 64 + wv * 16;
  const int jt0 = blockIdx.z * 4;
  const f32x4 z4 = {0.f, 0.f, 0.f, 0.f};

  bf16x8 aQ[4];
#pragma unroll
  for (int kc = 0; kc < 4; ++kc)
    aQ[kc] = *(const bf16x8*)&Qf[((size_t)(it0 + ml) * NBd + n) * 384 + kc * 32 + quad * 8];

  float* rbase = &raw[(((size_t)(n & 1) * HNd + (n >> 1)) * Wd + it0) * Wd];

  // "tile -1" R2 init -> bank 1, and fPQprev from the same rows
  bf16x8 fPQprev[4];
  {
    int pp = it0 - jt0 * 16 + 256 + ml;
    if (pp > 510) pp = 510;
    const short* pr = &PP[(size_t)pp * 256];
    f32x4 R2i = z4;
#pragma unroll
    for (int kc = 0; kc < 4; ++kc) {
      bf16x8 fPK = *(const bf16x8*)&pr[128 + kc * 32 + quad * 8];
      R2i = __builtin_amdgcn_mfma_f32_16x16x32_bf16(aQ[kc], fPK, R2i, 0, 0, 0);
      fPQprev[kc] = *(const bf16x8*)&pr[kc * 32 + quad * 8];
    }
    *(f32x4*)&R2T[wv][1][ml][quad * 4] = R2i;
  }

  // tile-0 operand loads
  bf16x8 aKn[4], fPKn[4], fPQn[4];
  {
    const int j0 = jt0 * 16;
#pragma unroll
    for (int kc = 0; kc < 4; ++kc)
      aKn[kc] = *(const bf16x8*)&Kf[((size_t)(j0 + ml) * NBd + n) * 256 + kc * 32 + quad * 8];
    const int p0 = it0 - j0 + 240 + ml;  // in [0,495]
    const short* pr0 = &PP[(size_t)p0 * 256];
#pragma unroll
    for (int kc = 0; kc < 4; ++kc) {
      fPKn[kc] = *(const bf16x8*)&pr0[128 + kc * 32 + quad * 8];
      fPQn[kc] = *(const bf16x8*)&pr0[kc * 32 + quad * 8];
    }
  }

  f32x4 St_p;
  // ---- compute tile 0 (no consume) ----
  {
    f32x4 St = z4, R2f = z4, R3a = z4, R3b = z4;
#pragma unroll
    for (int kc = 0; kc < 4; ++kc)
      St = __builtin_amdgcn_mfma_f32_16x16x32_bf16(aQ[kc], aKn[kc], St, 0, 0, 0);
#pragma unroll
    for (int kc = 0; kc < 4; ++kc)
      R2f = __builtin_amdgcn_mfma_f32_16x16x32_bf16(aQ[kc], fPKn[kc], R2f, 0, 0, 0);
#pragma unroll
    for (int kc = 0; kc < 4; ++kc)
      R3a = __builtin_amdgcn_mfma_f32_16x16x32_bf16(aKn[kc], fPQn[kc], R3a, 0, 0, 0);
#pragma unroll
    for (int kc = 0; kc < 4; ++kc)
      R3b = __builtin_amdgcn_mfma_f32_16x16x32_bf16(aKn[kc], fPQprev[kc], R3b, 0, 0, 0);
#pragma unroll
    for (int kc = 0; kc < 4; ++kc) fPQprev[kc] = fPQn[kc];
    *(f32x4*)&R2T[wv][0][ml][quad * 4] = R2f;
    *(f32x4*)&R3T[wv][0][ml][quad * 4] = R3a;
    *(f32x4*)&R3T[wv][0][ml + 16][quad * 4] = R3b;
    St_p = St;
    // prefetch tile 1 operands
    const int j0n = (jt0 + 1) * 16;
#pragma unroll
    for (int kc = 0; kc < 4; ++kc)
      aKn[kc] = *(const bf16x8*)&Kf[((size_t)(j0n + ml) * NBd + n) * 256 + kc * 32 + quad * 8];
    const int p0n = it0 - j0n + 240 + ml;
    const short* prn = &PP[(size_t)p0n * 256];
#pragma unroll
    for (int kc = 0; kc < 4; ++kc) {
      fPKn[kc] = *(const bf16x8*)&prn[128 + kc * 32 + quad * 8];
      fPQn[kc] = *(const bf16x8*)&prn[kc * 32 + quad * 8];
    }
  }

#pragma unroll
  for (int i = 1; i < 4; ++i) {
    const int T = i - 1;
    // ---- phase A: LDS reads for tile T ----
    float r2v[4], r3v[4];
#pragma unroll
    for (int r = 0; r < 4; ++r) {
      const int il = quad * 4 + r;
      const int pcol = il - ml + 15;
      const int hi = pcol >> 4, col = pcol & 15;
      const int bk = (T & 1) ^ hi;
      r2v[r] = R2T[wv][bk][col][il];
      r3v[r] = R3T[wv][T & 1][pcol][ml];
    }
    // ---- tile i MFMAs (operands prefetched last iteration) ----
    f32x4 St = z4, R2f = z4, R3a = z4, R3b = z4;
#pragma unroll
    for (int kc = 0; kc < 4; ++kc)
      St = __builtin_amdgcn_mfma_f32_16x16x32_bf16(aQ[kc], aKn[kc], St, 0, 0, 0);
#pragma unroll
    for (int kc = 0; kc < 4; ++kc)
      R2f = __builtin_amdgcn_mfma_f32_16x16x32_bf16(aQ[kc], fPKn[kc], R2f, 0, 0, 0);
#pragma unroll
    for (int kc = 0; kc < 4; ++kc)
      R3a = __builtin_amdgcn_mfma_f32_16x16x32_bf16(aKn[kc], fPQn[kc], R3a, 0, 0, 0);
#pragma unroll
    for (int kc = 0; kc < 4; ++kc)
      R3b = __builtin_amdgcn_mfma_f32_16x16x32_bf16(aKn[kc], fPQprev[kc], R3b, 0, 0, 0);
#pragma unroll
    for (int kc = 0; kc < 4; ++kc) fPQprev[kc] = fPQn[kc];
    // ---- prefetch tile i+1 operands ----
    if (i < 3) {
      const int j0n = (jt0 + i + 1) * 16;
#pragma unroll
      for (int kc = 0; kc < 4; ++kc)
        aKn[kc] = *(const bf16x8*)&Kf[((size_t)(j0n + ml) * NBd + n) * 256 + kc * 32 + quad * 8];
      const int p0n = it0 - j0n + 240 + ml;
      const short* prn = &PP[(size_t)p0n * 256];
#pragma unroll
      for (int kc = 0; kc < 4; ++kc) {
        fPKn[kc] = *(const bf16x8*)&prn[128 + kc * 32 + quad * 8];
        fPQn[kc] = *(const bf16x8*)&prn[kc * 32 + quad * 8];
      }
    }
    // ---- phase B: emit tile T, then overwrite the aged banks ----
    const int j0T = (jt0 + T) * 16;
#pragma unroll
    for (int r = 0; r < 4; ++r) {
      const int il = quad * 4 + r;
      rbase[(size_t)il * Wd + j0T + ml] = St_p[r] + r2v[r] + r3v[r];
    }
    *(f32x4*)&R2T[wv][i & 1][ml][quad * 4] = R2f;
    *(f32x4*)&R3T[wv][i & 1][ml][quad * 4] = R3a;
    *(f32x4*)&R3T[wv][i & 1][ml + 16][quad * 4] = R3b;
    St_p = St;
  }

  // ---- epilogue: consume tile 3 ----
  {
    const int T = 3;
    const int j0T = (jt0 + T) * 16;
#pragma unroll
    for (int r = 0; r < 4; ++r) {
      const int il = quad * 4 + r;
      const int pcol = il - ml + 15;
      const int hi = pcol >> 4, col = pcol & 15;
      const int bk = (T & 1) ^ hi;
      float r2v = R2T[wv][bk][col][il];
      float r3v = R3T[wv][T & 1][pcol][ml];
      rbase[(size_t)il * Wd + j0T + ml] = St_p[r] + r2v + r3v;
    }
  }
}

extern "C" void kernel_launch(void* const* d_in, const int* in_sizes, int n_in,
                              void* d_out, int out_size, void* d_ws, size_t ws_size,
                              hipStream_t stream) {
  const float* feat_l = (const float*)d_in[0];
  const float* feat_r = (const float*)d_in[1];
  const float* pos    = (const float*)d_in[2];
  // d_in[3] = pos_indexes (int) -- structure known analytically, unused.
  const float* Wqkv = (const float*)d_in[4];
  const float* bqkv = (const float*)d_in[5];
  const float* Wo   = (const float*)d_in[6];
  const float* bo   = (const float*)d_in[7];
  const float* g1   = (const float*)d_in[8];
  const float* b1   = (const float*)d_in[9];
  const float* g2   = (const float*)d_in[10];
  const float* b2   = (const float*)d_in[11];
  float* out = (float*)d_out;

  float* ws = (float*)d_ws;
  float* fl_seq = ws;                 // fp32
  float* fr_seq = ws + SEQF;          // fp32
  float* fr2_f  = ws + 2 * SEQF;      // fp32 (fr_new)
  float* fl_new = ws + 3 * SEQF;      // fp32
  short* wsb    = (short*)(ws + 4 * SEQF);
  short* fl2_b   = wsb;               // SEQF bf16
  short* fr2_b   = wsb + SEQF;
  short* frb2_b  = wsb + 2 * SEQF;
  short* QKVl_b  = wsb + 3 * SEQF;    // 3*SEQF
  short* Qr_b    = wsb + 6 * SEQF;
  short* KVr2_b  = wsb + 7 * SEQF;    // 2*SEQF
  short* O_b     = wsb + 9 * SEQF;    // OT layout [n][e][i][cc]
  short* PP_b    = wsb + 10 * SEQF;   // 511*256
  short* Wb      = PP_b + 131072;     // Wqkv (49152) then Wo (16384)
  short* pos_b   = Wb + 65536;        // 511*128

  // to_seq + LN(g1,b1) fused, both tensors
  k_to_seq_ln<<<dim3(8, 256), 256, 0, stream>>>(feat_l, feat_r, fl_seq, fr_seq,
                                                fl2_b, fr2_b, g1, b1);
  k_cvt<<<256, 256, 0, stream>>>(Wqkv, Wb, Wo, Wb + 49152, pos, pos_b);

  // PP = [PQ(scaled)|PK] projections of the 511 pos rows (bf16 out)
  k_gemm_bf<<<dim3(8, 2), 256, 0, stream>>>(pos_b, Wb, bqkv, nullptr, PP_b,
                                            511, 256, 128, 0.25f,
                                            nullptr, nullptr, 0, 999);
  // QKV of fl2 (Q scaled) + Q of fr2 (scaled), merged
  k_gemm_bf<<<dim3(512, 4), 256, 0, stream>>>(fl2_b, Wb, bqkv, nullptr, QKVl_b,
                                              32768, 384, 128, 0.25f,
                                              fr2_b, Qr_b, 128, 3);

  // mha1: q=fr2-proj, kv=fl2-proj, flipped pos => p = j-i+255
  k_attn_mfma<1><<<dim3(128, 8, 2), 256, 0, stream>>>(
      Qr_b, Cd, QKVl_b + 128, QKVl_b + 256, 384, PP_b, O_b);
  // fr_new = fr_seq + O @ Wo^T + bo  (+ fused LN(g2,b2) -> frb2_b)
  k_gemm_wo_ln<<<512, 256, 0, stream>>>(O_b, Wb + 49152, bo, fr_seq, fr2_f,
                                        frb2_b, g2, b2);
  // KV of frb2
  k_gemm_bf<<<dim3(512, 2), 256, 0, stream>>>(frb2_b, Wb + 16384, bqkv + 128, nullptr,
                                              KVr2_b, 32768, 256, 0, 1.0f,
                                              nullptr, nullptr, 0, 999);
  // mha2: q=fl2-proj (in QKVl), kv=frb2-proj; p = i-j+255
  k_attn_mfma<2><<<dim3(128, 8, 2), 256, 0, stream>>>(
      QKVl_b, 384, KVr2_b, KVr2_b + 128, 256, PP_b, O_b);
  // raw = sum over heads of pre-softmax scores (dense K=128 formulation)
  k_raw<<<dim3(4, 128, 4), 256, 0, stream>>>(QKVl_b, KVr2_b, PP_b, out + 2 * SEQF);
  // fl_new = fl_seq + O @ Wo^T + bo (no LN)
  k_gemm_wo_ln<<<512, 256, 0, stream>>>(O_b, Wb + 49152, bo, fl_seq, fl_new,
                                        nullptr, nullptr, nullptr);

  k_from_seq2<<<dim3(8, 4, 256), dim3(32, 8), 0, stream>>>(fl_new, fr2_f, out, out + SEQF);

  (void)in_sizes; (void)n_in; (void)out_size; (void)ws_size;
}

// Round 7
// 349.613 us; speedup vs baseline: 1.4079x; 1.1165x over previous
//
#include <hip/hip_runtime.h>
#include <cstddef>

// Problem constants (fixed by setup_inputs)
static constexpr int Wd  = 256;   // sequence length (width)
static constexpr int NBd = 128;   // batch = hn*bs
static constexpr int Cd  = 128;   // channels
static constexpr int BSd = 2;     // bs
static constexpr int HNd = 64;    // hn
static constexpr size_t SEQF = (size_t)Wd * NBd * Cd;  // 4,194,304 elements

typedef __attribute__((ext_vector_type(8))) short bf16x8;
typedef __attribute__((ext_vector_type(4))) short bf16x4;
typedef __attribute__((ext_vector_type(4))) float f32x4;
typedef __attribute__((ext_vector_type(2))) float f32x2;

__device__ inline short f2bf(float f) {
  union { float f; unsigned u; } v; v.f = f;
  return (short)((v.u + 0x7FFFu + ((v.u >> 16) & 1u)) >> 16);
}

// ---------------- fused to_seq + LayerNorm ----------------
__global__ __launch_bounds__(256) void k_to_seq_ln(
    const float* __restrict__ fA, const float* __restrict__ fB,
    float* __restrict__ seqA, float* __restrict__ seqB,
    short* __restrict__ lnA, short* __restrict__ lnB,
    const float* __restrict__ g, const float* __restrict__ bb) {
  __shared__ float red[2][8][33];
  __shared__ float mv[2][32];
  const int z = blockIdx.y;
  const float* feat = (z < 128) ? fA : fB;
  float* seq = (z < 128) ? seqA : seqB;
  short* lno = (z < 128) ? lnA : lnB;
  const int hb = z & 127;
  const int h = hb >> 1, b = hb & 1;
  const int n = h * BSd + b;
  const int w0 = blockIdx.x * 32;
  const int t = threadIdx.x;
  const int wl = t & 31, cg = t >> 5, c0 = cg * 16;
  float v[16];
  float s1 = 0.f, s2 = 0.f;
#pragma unroll
  for (int r = 0; r < 16; ++r) {
    v[r] = feat[(((size_t)b * Cd + c0 + r) * HNd + h) * Wd + w0 + wl];
    s1 += v[r]; s2 += v[r] * v[r];
  }
  red[0][cg][wl] = s1; red[1][cg][wl] = s2;
  __syncthreads();
  if (t < 32) {
    float a1 = 0.f, a2 = 0.f;
#pragma unroll
    for (int k = 0; k < 8; ++k) { a1 += red[0][k][t]; a2 += red[1][k][t]; }
    float mean = a1 * (1.0f / Cd);
    float var = a2 * (1.0f / Cd) - mean * mean;
    mv[0][t] = mean; mv[1][t] = rsqrtf(var + 1e-5f);
  }
  __syncthreads();
  const float mean = mv[0][wl], rstd = mv[1][wl];
  float* so = &seq[((size_t)(w0 + wl) * NBd + n) * Cd + c0];
  short* bo_ = &lno[((size_t)(w0 + wl) * NBd + n) * Cd + c0];
#pragma unroll
  for (int r = 0; r < 16; ++r) so[r] = v[r];
#pragma unroll
  for (int r = 0; r < 16; ++r)
    bo_[r] = f2bf((v[r] - mean) * rstd * g[c0 + r] + bb[c0 + r]);
}

// ---------------- from_seq: merged for both tensors ----------------
__global__ __launch_bounds__(256) void k_from_seq2(const float* __restrict__ seqA,
                                                   const float* __restrict__ seqB,
                                                   float* __restrict__ featA,
                                                   float* __restrict__ featB) {
  __shared__ float tile[32][33];
  int wi0 = blockIdx.x * 32, ci0 = blockIdx.y * 32;
  int z = blockIdx.z;
  const float* seq = (z < 128) ? seqA : seqB;
  float* feat = (z < 128) ? featA : featB;
  int hb = z & 127;
  int h = hb >> 1, b = hb & 1;
  int n = h * BSd + b;
  int tx = threadIdx.x, ty = threadIdx.y;
#pragma unroll
  for (int r = 0; r < 4; ++r) {
    int wi = wi0 + ty + r * 8;
    tile[ty + r * 8][tx] = seq[((size_t)wi * NBd + n) * Cd + ci0 + tx];
  }
  __syncthreads();
#pragma unroll
  for (int r = 0; r < 4; ++r) {
    int ci = ci0 + ty + r * 8;
    feat[(((size_t)b * Cd + ci) * HNd + h) * Wd + wi0 + tx] = tile[tx][ty + r * 8];
  }
}

// ---------------- one-shot fp32->bf16 weight/pos convert ----------------
__global__ __launch_bounds__(256) void k_cvt(const float* __restrict__ w1, short* d1,  // 49152
                                             const float* __restrict__ w2, short* d2,  // 16384
                                             const float* __restrict__ w3, short* d3)  // 65408
{
  int i = blockIdx.x * 256 + threadIdx.x;
  if (i < 49152) d1[i] = f2bf(w1[i]);
  if (i < 16384) d2[i] = f2bf(w2[i]);
  if (i < 65408) d3[i] = f2bf(w3[i]);
}

// ---------------- PP repack: [511][256] -> [chunk=c/8][511][8] ----------------
// Makes fragment loads (16 consecutive rows x 16B) CONTIGUOUS 256B segments.
__global__ __launch_bounds__(256) void k_ppt(const short* __restrict__ src,
                                             short* __restrict__ dst) {
  int row = blockIdx.x;   // 0..510
  int c = threadIdx.x;    // 0..255
  dst[((size_t)(c >> 3) * 511 + row) * 8 + (c & 7)] = src[(size_t)row * 256 + c];
}

// ---------------- bf16 MFMA GEMM, K=128, no LDS, no barriers ----------------
__global__ __launch_bounds__(256) void k_gemm_bf(
    const short* __restrict__ A, const short* __restrict__ Wt,
    const float* __restrict__ bias, float* __restrict__ outF,
    short* __restrict__ outB, int M, int ldout, int scaleN0, float scale,
    const short* __restrict__ A2, short* __restrict__ outB2, int ldout2, int yCut) {
  const int t = threadIdx.x;
  const int lane = t & 63, wv = t >> 6;
  const int ml = lane & 15, quad = lane >> 4;
  const int m0 = blockIdx.x * 64;
  int yb = blockIdx.y;
  const short* Ap = A;
  short* oB = outB;
  float* oF = outF;
  int ld = ldout;
  int nblk = yb;
  if (yb >= yCut) { Ap = A2; oB = outB2; oF = nullptr; ld = ldout2; nblk = 0; }
  const int n0 = nblk * 128 + wv * 32;
  const bf16x8 zero8 = {0, 0, 0, 0, 0, 0, 0, 0};

  bf16x8 Bfr[2][4];
#pragma unroll
  for (int nf = 0; nf < 2; ++nf)
#pragma unroll
    for (int ks = 0; ks < 4; ++ks)
      Bfr[nf][ks] = *(const bf16x8*)&Wt[(size_t)(n0 + nf * 16 + ml) * 128 + ks * 32 + quad * 8];

  f32x4 acc[4][2];
#pragma unroll
  for (int mf = 0; mf < 4; ++mf)
#pragma unroll
    for (int nf = 0; nf < 2; ++nf) acc[mf][nf] = {0.f, 0.f, 0.f, 0.f};

#pragma unroll
  for (int ks = 0; ks < 4; ++ks) {
    bf16x8 Af[4];
#pragma unroll
    for (int mf = 0; mf < 4; ++mf) {
      int m = m0 + mf * 16 + ml;
      Af[mf] = (m < M) ? *(const bf16x8*)&Ap[(size_t)m * 128 + ks * 32 + quad * 8] : zero8;
    }
#pragma unroll
    for (int mf = 0; mf < 4; ++mf)
#pragma unroll
      for (int nf = 0; nf < 2; ++nf)
        acc[mf][nf] = __builtin_amdgcn_mfma_f32_16x16x32_bf16(Af[mf], Bfr[nf][ks], acc[mf][nf], 0, 0, 0);
  }

#pragma unroll
  for (int nf = 0; nf < 2; ++nf) {
    int n = n0 + nf * 16 + ml;
    float bi = bias[n];
    float sc = (n < scaleN0) ? scale : 1.0f;
#pragma unroll
    for (int mf = 0; mf < 4; ++mf) {
#pragma unroll
      for (int r = 0; r < 4; ++r) {
        int m = m0 + mf * 16 + quad * 4 + r;
        if (m >= M) continue;
        float v = (acc[mf][nf][r] + bi) * sc;
        if (oF) oF[(size_t)m * ld + n] = v;
        if (oB) oB[(size_t)m * ld + n] = f2bf(v);
      }
    }
  }
}

// ---------------- Wo GEMM + residual + optional fused LayerNorm ----------------
__global__ __launch_bounds__(256) void k_gemm_wo_ln(
    const short* __restrict__ A, const short* __restrict__ Wt,
    const float* __restrict__ bias, const float* __restrict__ res,
    float* __restrict__ outF, short* __restrict__ outLN,
    const float* __restrict__ lng, const float* __restrict__ lnb) {
  const int t = threadIdx.x;
  const int lane = t & 63, wv = t >> 6;
  const int ml = lane & 15, quad = lane >> 4;
  const int m0 = blockIdx.x * 64 + wv * 16;
  const int ii = m0 >> 7;              // w index (fixed across the 16 lanes)
  const int nn = (m0 & 127) + ml;      // n index (per-lane)

  f32x4 acc[8];
#pragma unroll
  for (int nf = 0; nf < 8; ++nf) acc[nf] = {0.f, 0.f, 0.f, 0.f};
#pragma unroll
  for (int ks = 0; ks < 4; ++ks) {
    bf16x8 Af = *(const bf16x8*)&A[(((size_t)nn * 8 + ks * 2 + (quad >> 1)) * 256 + ii) * 16 +
                                   (quad & 1) * 8];
#pragma unroll
    for (int nf = 0; nf < 8; ++nf) {
      bf16x8 Bf = *(const bf16x8*)&Wt[(size_t)(nf * 16 + ml) * 128 + ks * 32 + quad * 8];
      acc[nf] = __builtin_amdgcn_mfma_f32_16x16x32_bf16(Af, Bf, acc[nf], 0, 0, 0);
    }
  }
  float val[8][4];
#pragma unroll
  for (int nf = 0; nf < 8; ++nf) {
    float bi = bias[nf * 16 + ml];
#pragma unroll
    for (int r = 0; r < 4; ++r) {
      int m = m0 + quad * 4 + r;
      val[nf][r] = acc[nf][r] + bi + res[(size_t)m * 128 + nf * 16 + ml];
      outF[(size_t)m * 128 + nf * 16 + ml] = val[nf][r];
    }
  }
  if (outLN) {
#pragma unroll
    for (int r = 0; r < 4; ++r) {
      float s1 = 0.f, s2 = 0.f;
#pragma unroll
      for (int nf = 0; nf < 8; ++nf) { s1 += val[nf][r]; s2 += val[nf][r] * val[nf][r]; }
#pragma unroll
      for (int mk = 1; mk < 16; mk <<= 1) { s1 += __shfl_xor(s1, mk); s2 += __shfl_xor(s2, mk); }
      float mean = s1 * (1.0f / 128.f);
      float var = s2 * (1.0f / 128.f) - mean * mean;
      float rstd = rsqrtf(var + 1e-5f);
      int m = m0 + quad * 4 + r;
#pragma unroll
      for (int nf = 0; nf < 8; ++nf) {
        int nn2 = nf * 16 + ml;
        outLN[(size_t)m * 128 + nn2] = f2bf((val[nf][r] - mean) * rstd * lng[nn2] + lnb[nn2]);
      }
    }
  }
}

// ---------------- MFMA fused attention, head-split + i-panel loop ----------------
// Round-7: PP loads switched to the PPT [chunk][row][8] layout -- lane ml reads
// 16 CONSECUTIVE rows x 16B = one 256B contiguous segment per quad (was 16
// scattered 64B lines per instruction). Rounds 4-6 showed both this kernel and
// k_raw pinned at ~60us, insensitive to occupancy/pipelining -> bound by per-CU
// cache-line request throughput of the divergent loads, which this removes.
// Everything else identical to round 5/6 (phase A/B split, bpermute R3,
// 2-bank R2, bounds(256,3)).
template <int PASS>
__global__ __launch_bounds__(256, 3) void k_attn_mfma(
    const short* __restrict__ Qg, int ldq,
    const short* __restrict__ Kg, const short* __restrict__ Vg, int ldkv,
    const short* __restrict__ PPT, short* __restrict__ OT) {
  __shared__ short Ks[256][16];
  __shared__ short VTs[16][264];
  __shared__ float R2T[4][2][16][20];  // [wave][bank][pm][i + pad4]

  const int t = threadIdx.x;
  const int n = blockIdx.x;
  const int e = blockIdx.y;
  const int lane = t & 63, wv = t >> 6;
  const int ml = lane & 15, quad = lane >> 4;
  const bool lo = lane < 32;
  const bf16x8 zero8 = {0, 0, 0, 0, 0, 0, 0, 0};
  const f32x4 z4 = {0.f, 0.f, 0.f, 0.f};

#pragma unroll
  for (int it = 0; it < 4; ++it) {  // K rows: 256 rows x 4 chunks of 4 shorts
    int idx = t + it * 256;
    int r = idx >> 2, c4 = idx & 3;
    *(bf16x4*)&Ks[r][c4 * 4] =
        *(const bf16x4*)&Kg[((size_t)r * NBd + n) * ldkv + e * 16 + c4 * 4];
  }
#pragma unroll
  for (int it = 0; it < 4; ++it) {  // V transposed: row-linear lanes
    bf16x4 vv = *(const bf16x4*)&Vg[((size_t)t * NBd + n) * ldkv + e * 16 + it * 4];
    VTs[it * 4 + 0][t] = vv[0];
    VTs[it * 4 + 1][t] = vv[1];
    VTs[it * 4 + 2][t] = vv[2];
    VTs[it * 4 + 3][t] = vv[3];
  }
  __syncthreads();

  // Single-register consume base: pcol(r) = pbase -/+ r (r compile-time).
  const int pbase = (PASS == 2) ? (ml - quad * 4 + 15) : (quad * 4 - ml + 15);
  const int qsh = quad << 6;  // bpermute byte addr high part ((quad<<4)<<2)

  // PPT bases for this lane (PQ chunk = e*2+quad, PK chunk = 16+e*2+quad).
  // Only lo lanes (quad 0,1) dereference these.
  const short* PQe = PPT + (size_t)(e * 2 + quad) * 511 * 8;
  const short* PKe = PQe + (size_t)16 * 511 * 8;

  short* OTb = OT + (size_t)(n * 8 + e) * 256 * 16;

  for (int ipl = 0; ipl < 2; ++ipl) {
    const int i0p = ((int)blockIdx.z * 2 + ipl) * 64;
    const int wb = (PASS == 2) ? i0p : (192 - i0p);
    bf16x8 bQ = lo ? *(const bf16x8*)&Qg[((size_t)(i0p + 16 * wv + ml) * NBd + n) * ldq +
                                         e * 16 + quad * 8]
                   : zero8;
    f32x4 Ot = {0.f, 0.f, 0.f, 0.f};
    float den = 0.f;

    // init "tile -1" R2 half -> bank 1
    bf16x8 fPQprev;
    {
      int pp = (PASS == 2) ? (wb + 16 * wv + 256 + ml) : (wb - 16 * wv + 48 + ml);
      if (pp > 510) pp = 510;
      bf16x8 fPK0 = lo ? *(const bf16x8*)&PKe[(size_t)pp * 8] : zero8;
      fPQprev     = lo ? *(const bf16x8*)&PQe[(size_t)pp * 8] : zero8;
      f32x4 R2i = __builtin_amdgcn_mfma_f32_16x16x32_bf16(bQ, fPK0, z4, 0, 0, 0);
      *(f32x4*)&R2T[wv][1][ml][quad * 4] = R2i;
    }
    // preload PP row for tile 0
    bf16x8 fPK, fPQf;
    {
      int pf = (PASS == 2) ? (wb + 16 * wv + 240 + ml) : (wb - 16 * wv + 64 + ml);
      if (pf > 510) pf = 510;
      fPK  = lo ? *(const bf16x8*)&PKe[(size_t)pf * 8] : zero8;
      fPQf = lo ? *(const bf16x8*)&PQe[(size_t)pf * 8] : zero8;
    }

    // carried (pipelined) tile state
    f32x4 St_p, R3a_p, R3b_p;
    unsigned pA0 = 0, pA1 = 0;
    bf16x8 aKn;  // prefetched K fragment for the next tile

    // ---- compute tile 0 (no consume) ----
    {
      bf16x8 aK = lo ? *(const bf16x8*)&Ks[ml][quad * 8] : zero8;
      St_p = __builtin_amdgcn_mfma_f32_16x16x32_bf16(aK, bQ, z4, 0, 0, 0);
      f32x4 R2c = __builtin_amdgcn_mfma_f32_16x16x32_bf16(bQ, fPK, z4, 0, 0, 0);
      if (PASS == 2) {
        R3a_p = __builtin_amdgcn_mfma_f32_16x16x32_bf16(aK, fPQf, z4, 0, 0, 0);
        R3b_p = __builtin_amdgcn_mfma_f32_16x16x32_bf16(aK, fPQprev, z4, 0, 0, 0);
      } else {
        R3b_p = __builtin_amdgcn_mfma_f32_16x16x32_bf16(aK, fPQf, z4, 0, 0, 0);
        R3a_p = __builtin_amdgcn_mfma_f32_16x16x32_bf16(aK, fPQprev, z4, 0, 0, 0);
      }
      fPQprev = fPQf;
      {  // prefetch PP row for tile 1
        int pf = (PASS == 2) ? (wb + 16 * wv - 16 + 240 + ml) : (wb - 16 * wv + 16 + 64 + ml);
        if (pf > 510) pf = 510;
        fPK  = lo ? *(const bf16x8*)&PKe[(size_t)pf * 8] : zero8;
        fPQf = lo ? *(const bf16x8*)&PQe[(size_t)pf * 8] : zero8;
      }
      aKn = lo ? *(const bf16x8*)&Ks[16 + ml][quad * 8] : zero8;  // prefetch tile 1
      *(f32x4*)&R2T[wv][0][ml][quad * 4] = R2c;
    }

#pragma unroll
    for (int i = 1; i < 16; ++i) {
      const int T = i - 1;
      const int j0 = i * 16;

      // ---- phase A: issue ALL LDS ops for tile T (results used in phase B) ----
      float r2v[4], va[4], vb[4];
#pragma unroll
      for (int r = 0; r < 4; ++r) {
        const int pcol = (PASS == 2) ? (pbase - r) : (pbase + r);
        const int hi = pcol >> 4;
        const int bk = (T & 1) ^ hi ^ (PASS == 1 ? 1 : 0);
        const int ba = ((pcol & 15) << 2) | qsh;
        r2v[r] = R2T[wv][bk][pcol & 15][ml];
        va[r] = __int_as_float(
            __builtin_amdgcn_ds_bpermute(ba, __float_as_int(R3a_p[r])));
        vb[r] = __int_as_float(
            __builtin_amdgcn_ds_bpermute(ba, __float_as_int(R3b_p[r])));
      }
      bf16x8 aVT = zero8;
      if (T & 1) aVT = *(const bf16x8*)&VTs[ml][(T >> 1) * 32 + quad * 8];

      // ---- issue tile i MFMAs (all operands in registers) ----
      bf16x8 aK = aKn;
      f32x4 St_c = __builtin_amdgcn_mfma_f32_16x16x32_bf16(aK, bQ, z4, 0, 0, 0);
      f32x4 R2c  = __builtin_amdgcn_mfma_f32_16x16x32_bf16(bQ, fPK, z4, 0, 0, 0);
      f32x4 R3A, R3B;
      if (PASS == 2) {
        R3A = __builtin_amdgcn_mfma_f32_16x16x32_bf16(aK, fPQf, z4, 0, 0, 0);
        R3B = __builtin_amdgcn_mfma_f32_16x16x32_bf16(aK, fPQprev, z4, 0, 0, 0);
      } else {
        R3B = __builtin_amdgcn_mfma_f32_16x16x32_bf16(aK, fPQf, z4, 0, 0, 0);
        R3A = __builtin_amdgcn_mfma_f32_16x16x32_bf16(aK, fPQprev, z4, 0, 0, 0);
      }
      fPQprev = fPQf;
      if (i < 15) {  // prefetch PP row + K fragment for tile i+1
        int pf = (PASS == 2) ? (wb + 16 * wv - (j0 + 16) + 240 + ml)
                             : (wb - 16 * wv + (j0 + 16) + 64 + ml);
        if (pf > 510) pf = 510;
        fPK  = lo ? *(const bf16x8*)&PKe[(size_t)pf * 8] : zero8;
        fPQf = lo ? *(const bf16x8*)&PQe[(size_t)pf * 8] : zero8;
        aKn = lo ? *(const bf16x8*)&Ks[j0 + 16 + ml][quad * 8] : zero8;
      }

      // ---- phase B: consume tile T with the preloaded values ----
      float pe4[4];
#pragma unroll
      for (int r = 0; r < 4; ++r) {
        const int pcol = (PASS == 2) ? (pbase - r) : (pbase + r);
        const int hi = pcol >> 4;
        float s = St_p[r] + r2v[r] + (hi ? vb[r] : va[r]);
        pe4[r] = __expf(s);
        den += pe4[r];
      }
      unsigned d0, d1;
      asm("v_cvt_pk_bf16_f32 %0, %1, %2" : "=v"(d0) : "v"(pe4[0]), "v"(pe4[1]));
      asm("v_cvt_pk_bf16_f32 %0, %1, %2" : "=v"(d1) : "v"(pe4[2]), "v"(pe4[3]));
      if ((T & 1) == 0) {
        pA0 = d0;
        pA1 = d1;
      } else {
        unsigned b0 = pA0, b2 = d0, b1 = pA1, b3 = d1;
        asm("v_permlane32_swap_b32 %0, %1" : "+v"(b0), "+v"(b2));
        asm("v_permlane16_swap_b32 %0, %1" : "+v"(b0), "+v"(b2));
        asm("v_permlane32_swap_b32 %0, %1" : "+v"(b1), "+v"(b3));
        asm("v_permlane16_swap_b32 %0, %1" : "+v"(b1), "+v"(b3));
        union { unsigned u[4]; bf16x8 v8; } bp;
        bp.u[0] = b0; bp.u[1] = b1; bp.u[2] = b2; bp.u[3] = b3;
        Ot = __builtin_amdgcn_mfma_f32_16x16x32_bf16(aVT, bp.v8, Ot, 0, 0, 0);
      }
      *(f32x4*)&R2T[wv][i & 1][ml][quad * 4] = R2c;
      St_p = St_c; R3a_p = R3A; R3b_p = R3B;
    }

    // ---- epilogue: consume tile 15 (odd -> fires the last PV) ----
    {
      const int T = 15;
      float r2v[4], va[4], vb[4];
#pragma unroll
      for (int r = 0; r < 4; ++r) {
        const int pcol = (PASS == 2) ? (pbase - r) : (pbase + r);
        const int hi = pcol >> 4;
        const int bk = (T & 1) ^ hi ^ (PASS == 1 ? 1 : 0);
        const int ba = ((pcol & 15) << 2) | qsh;
        r2v[r] = R2T[wv][bk][pcol & 15][ml];
        va[r] = __int_as_float(
            __builtin_amdgcn_ds_bpermute(ba, __float_as_int(R3a_p[r])));
        vb[r] = __int_as_float(
            __builtin_amdgcn_ds_bpermute(ba, __float_as_int(R3b_p[r])));
      }
      bf16x8 aVT = *(const bf16x8*)&VTs[ml][(T >> 1) * 32 + quad * 8];
      float pe4[4];
#pragma unroll
      for (int r = 0; r < 4; ++r) {
        const int pcol = (PASS == 2) ? (pbase - r) : (pbase + r);
        const int hi = pcol >> 4;
        float s = St_p[r] + r2v[r] + (hi ? vb[r] : va[r]);
        pe4[r] = __expf(s);
        den += pe4[r];
      }
      unsigned d0, d1;
      asm("v_cvt_pk_bf16_f32 %0, %1, %2" : "=v"(d0) : "v"(pe4[0]), "v"(pe4[1]));
      asm("v_cvt_pk_bf16_f32 %0, %1, %2" : "=v"(d1) : "v"(pe4[2]), "v"(pe4[3]));
      unsigned b0 = pA0, b2 = d0, b1 = pA1, b3 = d1;
      asm("v_permlane32_swap_b32 %0, %1" : "+v"(b0), "+v"(b2));
      asm("v_permlane16_swap_b32 %0, %1" : "+v"(b0), "+v"(b2));
      asm("v_permlane32_swap_b32 %0, %1" : "+v"(b1), "+v"(b3));
      asm("v_permlane16_swap_b32 %0, %1" : "+v"(b1), "+v"(b3));
      union { unsigned u[4]; bf16x8 v8; } bp;
      bp.u[0] = b0; bp.u[1] = b1; bp.u[2] = b2; bp.u[3] = b3;
      Ot = __builtin_amdgcn_mfma_f32_16x16x32_bf16(aVT, bp.v8, Ot, 0, 0, 0);
    }

    den += __shfl_xor(den, 16);
    den += __shfl_xor(den, 32);
    float inv = 1.f / den;
    bf16x4 ob;
    ob[0] = f2bf(Ot[0] * inv); ob[1] = f2bf(Ot[1] * inv);
    ob[2] = f2bf(Ot[2] * inv); ob[3] = f2bf(Ot[3] * inv);
    // OT[n][e][i][cc]: 16 rows x 32B = 512B contiguous per wave store
    *(bf16x4*)&OTb[(size_t)(i0p + 16 * wv + ml) * 16 + quad * 4] = ob;
  }
}

// ---------------- raw = sum_e pre-softmax scores, dense K=128 ----------------
// Round-7: address-divergence fix (round-6 pipeline reverted -- it was a null).
//  * Q-tile and K-tile staged into LDS with COALESCED loads (4 rows x 256B
//    contiguous per instruction); fragment reads come from LDS (264B padded
//    stride -> <=2-way banks, free). Replaces per-lane row-gathers at 64KB
//    stride (16 cache lines / instruction).
//  * PP read via PPT [chunk][row][8]: 16 consecutive rows x 16B = 256B
//    contiguous segment per quad.
// Compute structure = round-5 (banded R2/R3 reuse), bounds(256,3) for 51KB LDS.
__global__ __launch_bounds__(256, 3) void k_raw(
    const short* __restrict__ Qf, const short* __restrict__ Kf,
    const short* __restrict__ PPT, float* __restrict__ raw) {
  __shared__ float R2s[4][2][16][17];
  __shared__ float R3s[4][16][34];
  __shared__ short QSs[64][132];
  __shared__ short KSs[64][132];
  const int t = threadIdx.x;
  const int n = blockIdx.y;
  const int lane = t & 63, wv = t >> 6;
  const int ml = lane & 15, quad = lane >> 4;
  const int itb = blockIdx.x * 64;
  const int jtb = blockIdx.z * 64;
  const int it0 = itb + wv * 16;
  const int jt0 = blockIdx.z * 4;
  const f32x4 z4 = {0.f, 0.f, 0.f, 0.f};

  // coalesced staging: Q rows itb..itb+63, K rows jtb..jtb+63 (full 128 ch)
#pragma unroll
  for (int it = 0; it < 4; ++it) {
    int idx = t + it * 256;
    int r = idx >> 4, c8 = idx & 15;
    *(bf16x8*)&QSs[r][c8 * 8] =
        *(const bf16x8*)&Qf[((size_t)(itb + r) * NBd + n) * 384 + c8 * 8];
    *(bf16x8*)&KSs[r][c8 * 8] =
        *(const bf16x8*)&Kf[((size_t)(jtb + r) * NBd + n) * 256 + c8 * 8];
  }
  __syncthreads();

  bf16x8 aQ[4];
#pragma unroll
  for (int kc = 0; kc < 4; ++kc)
    aQ[kc] = *(const bf16x8*)&QSs[wv * 16 + ml][kc * 32 + quad * 8];

  float* rbase = &raw[(((size_t)(n & 1) * HNd + (n >> 1)) * Wd + it0) * Wd];

  // PPT bases: PQ chunk = kc*4+quad, PK chunk = 16+kc*4+quad
  const short* PQb = PPT + (size_t)quad * 511 * 8;
  const short* PKb = PQb + (size_t)16 * 511 * 8;

  bf16x8 fPQprev[4];
  {
    int pp = it0 - jt0 * 16 + 256 + ml;
    if (pp > 510) pp = 510;
    f32x4 R2i = z4;
#pragma unroll
    for (int kc = 0; kc < 4; ++kc) {
      bf16x8 fPK = *(const bf16x8*)&PKb[((size_t)kc * 4 * 511 + pp) * 8];
      R2i = __builtin_amdgcn_mfma_f32_16x16x32_bf16(aQ[kc], fPK, R2i, 0, 0, 0);
      fPQprev[kc] = *(const bf16x8*)&PQb[((size_t)kc * 4 * 511 + pp) * 8];
    }
#pragma unroll
    for (int r = 0; r < 4; ++r) R2s[wv][1][quad * 4 + r][ml] = R2i[r];
  }

#pragma unroll
  for (int jq = 0; jq < 4; ++jq) {
    const int j0 = (jt0 + jq) * 16;
    bf16x8 aK[4];
#pragma unroll
    for (int kc = 0; kc < 4; ++kc)
      aK[kc] = *(const bf16x8*)&KSs[jq * 16 + ml][kc * 32 + quad * 8];
    const int p0 = it0 - j0 + 240 + ml;  // in [0,495] always
    f32x4 St = z4, R2f = z4, R3a = z4, R3b = z4;
    bf16x8 fPQ0[4];
#pragma unroll
    for (int kc = 0; kc < 4; ++kc)
      St = __builtin_amdgcn_mfma_f32_16x16x32_bf16(aQ[kc], aK[kc], St, 0, 0, 0);
#pragma unroll
    for (int kc = 0; kc < 4; ++kc) {
      bf16x8 fPK0 = *(const bf16x8*)&PKb[((size_t)kc * 4 * 511 + p0) * 8];
      R2f = __builtin_amdgcn_mfma_f32_16x16x32_bf16(aQ[kc], fPK0, R2f, 0, 0, 0);
    }
#pragma unroll
    for (int kc = 0; kc < 4; ++kc) {
      fPQ0[kc] = *(const bf16x8*)&PQb[((size_t)kc * 4 * 511 + p0) * 8];
      R3a = __builtin_amdgcn_mfma_f32_16x16x32_bf16(aK[kc], fPQ0[kc], R3a, 0, 0, 0);
    }
#pragma unroll
    for (int kc = 0; kc < 4; ++kc)
      R3b = __builtin_amdgcn_mfma_f32_16x16x32_bf16(aK[kc], fPQprev[kc], R3b, 0, 0, 0);
#pragma unroll
    for (int kc = 0; kc < 4; ++kc) fPQprev[kc] = fPQ0[kc];
#pragma unroll
    for (int r = 0; r < 4; ++r) {
      R2s[wv][jq & 1][quad * 4 + r][ml] = R2f[r];
      R3s[wv][quad * 4 + r][ml]      = R3a[r];
      R3s[wv][quad * 4 + r][ml + 16] = R3b[r];
    }
#pragma unroll
    for (int r = 0; r < 4; ++r) {
      const int il = quad * 4 + r;
      const int pcol = il - ml + 15;
      const int hi = pcol >> 4, col = pcol & 15;
      const int bk = (jq & 1) ^ hi;
      rbase[(size_t)il * Wd + j0 + ml] = St[r] + R2s[wv][bk][il][col] + R3s[wv][ml][pcol];
    }
  }
}

extern "C" void kernel_launch(void* const* d_in, const int* in_sizes, int n_in,
                              void* d_out, int out_size, void* d_ws, size_t ws_size,
                              hipStream_t stream) {
  const float* feat_l = (const float*)d_in[0];
  const float* feat_r = (const float*)d_in[1];
  const float* pos    = (const float*)d_in[2];
  // d_in[3] = pos_indexes (int) -- structure known analytically, unused.
  const float* Wqkv = (const float*)d_in[4];
  const float* bqkv = (const float*)d_in[5];
  const float* Wo   = (const float*)d_in[6];
  const float* bo   = (const float*)d_in[7];
  const float* g1   = (const float*)d_in[8];
  const float* b1   = (const float*)d_in[9];
  const float* g2   = (const float*)d_in[10];
  const float* b2   = (const float*)d_in[11];
  float* out = (float*)d_out;

  float* ws = (float*)d_ws;
  float* fl_seq = ws;                 // fp32
  float* fr_seq = ws + SEQF;          // fp32
  float* fr2_f  = ws + 2 * SEQF;      // fp32 (fr_new)
  float* fl_new = ws + 3 * SEQF;      // fp32
  short* wsb    = (short*)(ws + 4 * SEQF);
  short* fl2_b   = wsb;               // SEQF bf16
  short* fr2_b   = wsb + SEQF;
  short* frb2_b  = wsb + 2 * SEQF;
  short* QKVl_b  = wsb + 3 * SEQF;    // 3*SEQF
  short* Qr_b    = wsb + 6 * SEQF;
  short* KVr2_b  = wsb + 7 * SEQF;    // 2*SEQF
  short* O_b     = wsb + 9 * SEQF;    // OT layout [n][e][i][cc]
  short* PP_b    = wsb + 10 * SEQF;   // 511*256
  short* Wb      = PP_b + 131072;     // Wqkv (49152) then Wo (16384)
  short* pos_b   = Wb + 65536;        // 511*128
  short* PPT_b   = pos_b + 65536;     // 32*511*8 = 130816 (chunk-major PP)

  // to_seq + LN(g1,b1) fused, both tensors
  k_to_seq_ln<<<dim3(8, 256), 256, 0, stream>>>(feat_l, feat_r, fl_seq, fr_seq,
                                                fl2_b, fr2_b, g1, b1);
  k_cvt<<<256, 256, 0, stream>>>(Wqkv, Wb, Wo, Wb + 49152, pos, pos_b);

  // PP = [PQ(scaled)|PK] projections of the 511 pos rows (bf16 out)
  k_gemm_bf<<<dim3(8, 2), 256, 0, stream>>>(pos_b, Wb, bqkv, nullptr, PP_b,
                                            511, 256, 128, 0.25f,
                                            nullptr, nullptr, 0, 999);
  // repack PP into chunk-major PPT (coalesced fragment loads)
  k_ppt<<<511, 256, 0, stream>>>(PP_b, PPT_b);

  // QKV of fl2 (Q scaled) + Q of fr2 (scaled), merged
  k_gemm_bf<<<dim3(512, 4), 256, 0, stream>>>(fl2_b, Wb, bqkv, nullptr, QKVl_b,
                                              32768, 384, 128, 0.25f,
                                              fr2_b, Qr_b, 128, 3);

  // mha1: q=fr2-proj, kv=fl2-proj, flipped pos => p = j-i+255
  k_attn_mfma<1><<<dim3(128, 8, 2), 256, 0, stream>>>(
      Qr_b, Cd, QKVl_b + 128, QKVl_b + 256, 384, PPT_b, O_b);
  // fr_new = fr_seq + O @ Wo^T + bo  (+ fused LN(g2,b2) -> frb2_b)
  k_gemm_wo_ln<<<512, 256, 0, stream>>>(O_b, Wb + 49152, bo, fr_seq, fr2_f,
                                        frb2_b, g2, b2);
  // KV of frb2
  k_gemm_bf<<<dim3(512, 2), 256, 0, stream>>>(frb2_b, Wb + 16384, bqkv + 128, nullptr,
                                              KVr2_b, 32768, 256, 0, 1.0f,
                                              nullptr, nullptr, 0, 999);
  // mha2: q=fl2-proj (in QKVl), kv=frb2-proj; p = i-j+255
  k_attn_mfma<2><<<dim3(128, 8, 2), 256, 0, stream>>>(
      QKVl_b, 384, KVr2_b, KVr2_b + 128, 256, PPT_b, O_b);
  // raw = sum over heads of pre-softmax scores (dense K=128 formulation)
  k_raw<<<dim3(4, 128, 4), 256, 0, stream>>>(QKVl_b, KVr2_b, PPT_b, out + 2 * SEQF);
  // fl_new = fl_seq + O @ Wo^T + bo (no LN)
  k_gemm_wo_ln<<<512, 256, 0, stream>>>(O_b, Wb + 49152, bo, fl_seq, fl_new,
                                        nullptr, nullptr, nullptr);

  k_from_seq2<<<dim3(8, 4, 256), dim3(32, 8), 0, stream>>>(fl_new, fr2_f, out, out + SEQF);

  (void)in_sizes; (void)n_in; (void)out_size; (void)ws_size;
}

// Round 10
// 332.179 us; speedup vs baseline: 1.4818x; 1.0525x over previous
//
#include <hip/hip_runtime.h>
#include <cstddef>

// Problem constants (fixed by setup_inputs)
static constexpr int Wd  = 256;   // sequence length (width)
static constexpr int NBd = 128;   // batch = hn*bs
static constexpr int Cd  = 128;   // channels
static constexpr int BSd = 2;     // bs
static constexpr int HNd = 64;    // hn
static constexpr size_t SEQF = (size_t)Wd * NBd * Cd;  // 4,194,304 elements

typedef __attribute__((ext_vector_type(8))) short bf16x8;
typedef __attribute__((ext_vector_type(4))) short bf16x4;
typedef __attribute__((ext_vector_type(4))) float f32x4;
typedef __attribute__((ext_vector_type(2))) float f32x2;

__device__ inline short f2bf(float f) {
  union { float f; unsigned u; } v; v.f = f;
  return (short)((v.u + 0x7FFFu + ((v.u >> 16) & 1u)) >> 16);
}

// ---------------- fused to_seq + LayerNorm ----------------
__global__ __launch_bounds__(256) void k_to_seq_ln(
    const float* __restrict__ fA, const float* __restrict__ fB,
    float* __restrict__ seqA, float* __restrict__ seqB,
    short* __restrict__ lnA, short* __restrict__ lnB,
    const float* __restrict__ g, const float* __restrict__ bb) {
  __shared__ float red[2][8][33];
  __shared__ float mv[2][32];
  const int z = blockIdx.y;
  const float* feat = (z < 128) ? fA : fB;
  float* seq = (z < 128) ? seqA : seqB;
  short* lno = (z < 128) ? lnA : lnB;
  const int hb = z & 127;
  const int h = hb >> 1, b = hb & 1;
  const int n = h * BSd + b;
  const int w0 = blockIdx.x * 32;
  const int t = threadIdx.x;
  const int wl = t & 31, cg = t >> 5, c0 = cg * 16;
  float v[16];
  float s1 = 0.f, s2 = 0.f;
#pragma unroll
  for (int r = 0; r < 16; ++r) {
    v[r] = feat[(((size_t)b * Cd + c0 + r) * HNd + h) * Wd + w0 + wl];
    s1 += v[r]; s2 += v[r] * v[r];
  }
  red[0][cg][wl] = s1; red[1][cg][wl] = s2;
  __syncthreads();
  if (t < 32) {
    float a1 = 0.f, a2 = 0.f;
#pragma unroll
    for (int k = 0; k < 8; ++k) { a1 += red[0][k][t]; a2 += red[1][k][t]; }
    float mean = a1 * (1.0f / Cd);
    float var = a2 * (1.0f / Cd) - mean * mean;
    mv[0][t] = mean; mv[1][t] = rsqrtf(var + 1e-5f);
  }
  __syncthreads();
  const float mean = mv[0][wl], rstd = mv[1][wl];
  float* so = &seq[((size_t)(w0 + wl) * NBd + n) * Cd + c0];
  short* bo_ = &lno[((size_t)(w0 + wl) * NBd + n) * Cd + c0];
#pragma unroll
  for (int r = 0; r < 16; ++r) so[r] = v[r];
#pragma unroll
  for (int r = 0; r < 16; ++r)
    bo_[r] = f2bf((v[r] - mean) * rstd * g[c0 + r] + bb[c0 + r]);
}

// ---------------- from_seq: merged for both tensors ----------------
__global__ __launch_bounds__(256) void k_from_seq2(const float* __restrict__ seqA,
                                                   const float* __restrict__ seqB,
                                                   float* __restrict__ featA,
                                                   float* __restrict__ featB) {
  __shared__ float tile[32][33];
  int wi0 = blockIdx.x * 32, ci0 = blockIdx.y * 32;
  int z = blockIdx.z;
  const float* seq = (z < 128) ? seqA : seqB;
  float* feat = (z < 128) ? featA : featB;
  int hb = z & 127;
  int h = hb >> 1, b = hb & 1;
  int n = h * BSd + b;
  int tx = threadIdx.x, ty = threadIdx.y;
#pragma unroll
  for (int r = 0; r < 4; ++r) {
    int wi = wi0 + ty + r * 8;
    tile[ty + r * 8][tx] = seq[((size_t)wi * NBd + n) * Cd + ci0 + tx];
  }
  __syncthreads();
#pragma unroll
  for (int r = 0; r < 4; ++r) {
    int ci = ci0 + ty + r * 8;
    feat[(((size_t)b * Cd + ci) * HNd + h) * Wd + wi0 + tx] = tile[tx][ty + r * 8];
  }
}

// ---------------- one-shot fp32->bf16 weight/pos convert ----------------
__global__ __launch_bounds__(256) void k_cvt(const float* __restrict__ w1, short* d1,  // 49152
                                             const float* __restrict__ w2, short* d2,  // 16384
                                             const float* __restrict__ w3, short* d3)  // 65408
{
  int i = blockIdx.x * 256 + threadIdx.x;
  if (i < 49152) d1[i] = f2bf(w1[i]);
  if (i < 16384) d2[i] = f2bf(w2[i]);
  if (i < 65408) d3[i] = f2bf(w3[i]);
}

// ---------------- PP repack: [511][256] -> [chunk=c/8][511][8] ----------------
// Makes fragment loads (16 consecutive rows x 16B) CONTIGUOUS 256B segments.
__global__ __launch_bounds__(256) void k_ppt(const short* __restrict__ src,
                                             short* __restrict__ dst) {
  int row = blockIdx.x;   // 0..510
  int c = threadIdx.x;    // 0..255
  dst[((size_t)(c >> 3) * 511 + row) * 8 + (c & 7)] = src[(size_t)row * 256 + c];
}

// ---------------- bf16 MFMA GEMM, K=128, LDS-staged A ----------------
// Round-10: A-fragment loads had the k_raw divergence signature (lane ml picks
// rows at 256B stride -> 16 cache-line requests/instr, 16 instrs/thread).
// Same fix as k_raw round 7 (measured 2x there): coalesced LDS stage of the
// 64x128 A-tile, fragments read from LDS ([132] pad = k_raw's proven pattern).
// B loads (8/thread, L2-hot weights) stay direct. Stage row clamped to M-1
// (PP call has M=511; output writes still m<M guarded).
__global__ __launch_bounds__(256) void k_gemm_bf(
    const short* __restrict__ A, const short* __restrict__ Wt,
    const float* __restrict__ bias, float* __restrict__ outF,
    short* __restrict__ outB, int M, int ldout, int scaleN0, float scale,
    const short* __restrict__ A2, short* __restrict__ outB2, int ldout2, int yCut) {
  __shared__ short As[64][132];
  const int t = threadIdx.x;
  const int lane = t & 63, wv = t >> 6;
  const int ml = lane & 15, quad = lane >> 4;
  const int m0 = blockIdx.x * 64;
  int yb = blockIdx.y;
  const short* Ap = A;
  short* oB = outB;
  float* oF = outF;
  int ld = ldout;
  int nblk = yb;
  if (yb >= yCut) { Ap = A2; oB = outB2; oF = nullptr; ld = ldout2; nblk = 0; }
  const int n0 = nblk * 128 + wv * 32;

  bf16x8 Bfr[2][4];
#pragma unroll
  for (int nf = 0; nf < 2; ++nf)
#pragma unroll
    for (int ks = 0; ks < 4; ++ks)
      Bfr[nf][ks] = *(const bf16x8*)&Wt[(size_t)(n0 + nf * 16 + ml) * 128 + ks * 32 + quad * 8];

  // coalesced stage: rows m0..m0+63 (4 rows x 256B contiguous per wave instr)
#pragma unroll
  for (int it = 0; it < 4; ++it) {
    int idx = t + it * 256;
    int r = idx >> 4, c8 = idx & 15;
    int m = m0 + r;
    if (m > M - 1) m = M - 1;
    *(bf16x8*)&As[r][c8 * 8] = *(const bf16x8*)&Ap[(size_t)m * 128 + c8 * 8];
  }
  __syncthreads();

  f32x4 acc[4][2];
#pragma unroll
  for (int mf = 0; mf < 4; ++mf)
#pragma unroll
    for (int nf = 0; nf < 2; ++nf) acc[mf][nf] = {0.f, 0.f, 0.f, 0.f};

#pragma unroll
  for (int ks = 0; ks < 4; ++ks) {
    bf16x8 Af[4];
#pragma unroll
    for (int mf = 0; mf < 4; ++mf)
      Af[mf] = *(const bf16x8*)&As[mf * 16 + ml][ks * 32 + quad * 8];
#pragma unroll
    for (int mf = 0; mf < 4; ++mf)
#pragma unroll
      for (int nf = 0; nf < 2; ++nf)
        acc[mf][nf] = __builtin_amdgcn_mfma_f32_16x16x32_bf16(Af[mf], Bfr[nf][ks], acc[mf][nf], 0, 0, 0);
  }

#pragma unroll
  for (int nf = 0; nf < 2; ++nf) {
    int n = n0 + nf * 16 + ml;
    float bi = bias[n];
    float sc = (n < scaleN0) ? scale : 1.0f;
#pragma unroll
    for (int mf = 0; mf < 4; ++mf) {
#pragma unroll
      for (int r = 0; r < 4; ++r) {
        int m = m0 + mf * 16 + quad * 4 + r;
        if (m >= M) continue;
        float v = (acc[mf][nf][r] + bi) * sc;
        if (oF) oF[(size_t)m * ld + n] = v;
        if (oB) oB[(size_t)m * ld + n] = f2bf(v);
      }
    }
  }
}

// ---------------- Wo GEMM + residual + optional fused LayerNorm ----------------
__global__ __launch_bounds__(256) void k_gemm_wo_ln(
    const short* __restrict__ A, const short* __restrict__ Wt,
    const float* __restrict__ bias, const float* __restrict__ res,
    float* __restrict__ outF, short* __restrict__ outLN,
    const float* __restrict__ lng, const float* __restrict__ lnb) {
  const int t = threadIdx.x;
  const int lane = t & 63, wv = t >> 6;
  const int ml = lane & 15, quad = lane >> 4;
  const int m0 = blockIdx.x * 64 + wv * 16;
  const int ii = m0 >> 7;              // w index (fixed across the 16 lanes)
  const int nn = (m0 & 127) + ml;      // n index (per-lane)

  f32x4 acc[8];
#pragma unroll
  for (int nf = 0; nf < 8; ++nf) acc[nf] = {0.f, 0.f, 0.f, 0.f};
#pragma unroll
  for (int ks = 0; ks < 4; ++ks) {
    bf16x8 Af = *(const bf16x8*)&A[(((size_t)nn * 8 + ks * 2 + (quad >> 1)) * 256 + ii) * 16 +
                                   (quad & 1) * 8];
#pragma unroll
    for (int nf = 0; nf < 8; ++nf) {
      bf16x8 Bf = *(const bf16x8*)&Wt[(size_t)(nf * 16 + ml) * 128 + ks * 32 + quad * 8];
      acc[nf] = __builtin_amdgcn_mfma_f32_16x16x32_bf16(Af, Bf, acc[nf], 0, 0, 0);
    }
  }
  float val[8][4];
#pragma unroll
  for (int nf = 0; nf < 8; ++nf) {
    float bi = bias[nf * 16 + ml];
#pragma unroll
    for (int r = 0; r < 4; ++r) {
      int m = m0 + quad * 4 + r;
      val[nf][r] = acc[nf][r] + bi + res[(size_t)m * 128 + nf * 16 + ml];
      outF[(size_t)m * 128 + nf * 16 + ml] = val[nf][r];
    }
  }
  if (outLN) {
#pragma unroll
    for (int r = 0; r < 4; ++r) {
      float s1 = 0.f, s2 = 0.f;
#pragma unroll
      for (int nf = 0; nf < 8; ++nf) { s1 += val[nf][r]; s2 += val[nf][r] * val[nf][r]; }
#pragma unroll
      for (int mk = 1; mk < 16; mk <<= 1) { s1 += __shfl_xor(s1, mk); s2 += __shfl_xor(s2, mk); }
      float mean = s1 * (1.0f / 128.f);
      float var = s2 * (1.0f / 128.f) - mean * mean;
      float rstd = rsqrtf(var + 1e-5f);
      int m = m0 + quad * 4 + r;
#pragma unroll
      for (int nf = 0; nf < 8; ++nf) {
        int nn2 = nf * 16 + ml;
        outLN[(size_t)m * 128 + nn2] = f2bf((val[nf][r] - mean) * rstd * lng[nn2] + lnb[nn2]);
      }
    }
  }
}

// ---------------- MFMA fused attention, head-split + i-panel loop ----------------
// Round-7 version, verbatim (proven: 55.9us, passed). PP loads via PPT
// [chunk][row][8]; phase A/B issue-early split; bpermute R3; 2-bank R2;
// bounds(256,3).
// PASS==2: p = i-j+255. PASS==1: p = j-i+255 (flipped pos).
template <int PASS>
__global__ __launch_bounds__(256, 3) void k_attn_mfma(
    const short* __restrict__ Qg, int ldq,
    const short* __restrict__ Kg, const short* __restrict__ Vg, int ldkv,
    const short* __restrict__ PPT, short* __restrict__ OT) {
  __shared__ short Ks[256][16];
  __shared__ short VTs[16][264];
  __shared__ float R2T[4][2][16][20];  // [wave][bank][pm][i + pad4]

  const int t = threadIdx.x;
  const int n = blockIdx.x;
  const int e = blockIdx.y;
  const int lane = t & 63, wv = t >> 6;
  const int ml = lane & 15, quad = lane >> 4;
  const bool lo = lane < 32;
  const bf16x8 zero8 = {0, 0, 0, 0, 0, 0, 0, 0};
  const f32x4 z4 = {0.f, 0.f, 0.f, 0.f};

#pragma unroll
  for (int it = 0; it < 4; ++it) {  // K rows: 256 rows x 4 chunks of 4 shorts
    int idx = t + it * 256;
    int r = idx >> 2, c4 = idx & 3;
    *(bf16x4*)&Ks[r][c4 * 4] =
        *(const bf16x4*)&Kg[((size_t)r * NBd + n) * ldkv + e * 16 + c4 * 4];
  }
#pragma unroll
  for (int it = 0; it < 4; ++it) {  // V transposed: row-linear lanes
    bf16x4 vv = *(const bf16x4*)&Vg[((size_t)t * NBd + n) * ldkv + e * 16 + it * 4];
    VTs[it * 4 + 0][t] = vv[0];
    VTs[it * 4 + 1][t] = vv[1];
    VTs[it * 4 + 2][t] = vv[2];
    VTs[it * 4 + 3][t] = vv[3];
  }
  __syncthreads();

  // Single-register consume base: pcol(r) = pbase -/+ r (r compile-time).
  const int pbase = (PASS == 2) ? (ml - quad * 4 + 15) : (quad * 4 - ml + 15);
  const int qsh = quad << 6;  // bpermute byte addr high part ((quad<<4)<<2)

  // PPT bases for this lane (PQ chunk = e*2+quad, PK chunk = 16+e*2+quad).
  // Only lo lanes (quad 0,1) dereference these.
  const short* PQe = PPT + (size_t)(e * 2 + quad) * 511 * 8;
  const short* PKe = PQe + (size_t)16 * 511 * 8;

  short* OTb = OT + (size_t)(n * 8 + e) * 256 * 16;

  for (int ipl = 0; ipl < 2; ++ipl) {
    const int i0p = ((int)blockIdx.z * 2 + ipl) * 64;
    const int wb = (PASS == 2) ? i0p : (192 - i0p);
    bf16x8 bQ = lo ? *(const bf16x8*)&Qg[((size_t)(i0p + 16 * wv + ml) * NBd + n) * ldq +
                                         e * 16 + quad * 8]
                   : zero8;
    f32x4 Ot = {0.f, 0.f, 0.f, 0.f};
    float den = 0.f;

    // init "tile -1" R2 half -> bank 1
    bf16x8 fPQprev;
    {
      int pp = (PASS == 2) ? (wb + 16 * wv + 256 + ml) : (wb - 16 * wv + 48 + ml);
      if (pp > 510) pp = 510;
      bf16x8 fPK0 = lo ? *(const bf16x8*)&PKe[(size_t)pp * 8] : zero8;
      fPQprev     = lo ? *(const bf16x8*)&PQe[(size_t)pp * 8] : zero8;
      f32x4 R2i = __builtin_amdgcn_mfma_f32_16x16x32_bf16(bQ, fPK0, z4, 0, 0, 0);
      *(f32x4*)&R2T[wv][1][ml][quad * 4] = R2i;
    }
    // preload PP row for tile 0
    bf16x8 fPK, fPQf;
    {
      int pf = (PASS == 2) ? (wb + 16 * wv + 240 + ml) : (wb - 16 * wv + 64 + ml);
      if (pf > 510) pf = 510;
      fPK  = lo ? *(const bf16x8*)&PKe[(size_t)pf * 8] : zero8;
      fPQf = lo ? *(const bf16x8*)&PQe[(size_t)pf * 8] : zero8;
    }

    // carried (pipelined) tile state
    f32x4 St_p, R3a_p, R3b_p;
    unsigned pA0 = 0, pA1 = 0;
    bf16x8 aKn;  // prefetched K fragment for the next tile

    // ---- compute tile 0 (no consume) ----
    {
      bf16x8 aK = lo ? *(const bf16x8*)&Ks[ml][quad * 8] : zero8;
      St_p = __builtin_amdgcn_mfma_f32_16x16x32_bf16(aK, bQ, z4, 0, 0, 0);
      f32x4 R2c = __builtin_amdgcn_mfma_f32_16x16x32_bf16(bQ, fPK, z4, 0, 0, 0);
      if (PASS == 2) {
        R3a_p = __builtin_amdgcn_mfma_f32_16x16x32_bf16(aK, fPQf, z4, 0, 0, 0);
        R3b_p = __builtin_amdgcn_mfma_f32_16x16x32_bf16(aK, fPQprev, z4, 0, 0, 0);
      } else {
        R3b_p = __builtin_amdgcn_mfma_f32_16x16x32_bf16(aK, fPQf, z4, 0, 0, 0);
        R3a_p = __builtin_amdgcn_mfma_f32_16x16x32_bf16(aK, fPQprev, z4, 0, 0, 0);
      }
      fPQprev = fPQf;
      {  // prefetch PP row for tile 1
        int pf = (PASS == 2) ? (wb + 16 * wv - 16 + 240 + ml) : (wb - 16 * wv + 16 + 64 + ml);
        if (pf > 510) pf = 510;
        fPK  = lo ? *(const bf16x8*)&PKe[(size_t)pf * 8] : zero8;
        fPQf = lo ? *(const bf16x8*)&PQe[(size_t)pf * 8] : zero8;
      }
      aKn = lo ? *(const bf16x8*)&Ks[16 + ml][quad * 8] : zero8;  // prefetch tile 1
      *(f32x4*)&R2T[wv][0][ml][quad * 4] = R2c;
    }

#pragma unroll
    for (int i = 1; i < 16; ++i) {
      const int T = i - 1;
      const int j0 = i * 16;

      // ---- phase A: issue ALL LDS ops for tile T (results used in phase B) ----
      float r2v[4], va[4], vb[4];
#pragma unroll
      for (int r = 0; r < 4; ++r) {
        const int pcol = (PASS == 2) ? (pbase - r) : (pbase + r);
        const int hi = pcol >> 4;
        const int bk = (T & 1) ^ hi ^ (PASS == 1 ? 1 : 0);
        const int ba = ((pcol & 15) << 2) | qsh;
        r2v[r] = R2T[wv][bk][pcol & 15][ml];
        va[r] = __int_as_float(
            __builtin_amdgcn_ds_bpermute(ba, __float_as_int(R3a_p[r])));
        vb[r] = __int_as_float(
            __builtin_amdgcn_ds_bpermute(ba, __float_as_int(R3b_p[r])));
      }
      bf16x8 aVT = zero8;
      if (T & 1) aVT = *(const bf16x8*)&VTs[ml][(T >> 1) * 32 + quad * 8];

      // ---- issue tile i MFMAs (all operands in registers) ----
      bf16x8 aK = aKn;
      f32x4 St_c = __builtin_amdgcn_mfma_f32_16x16x32_bf16(aK, bQ, z4, 0, 0, 0);
      f32x4 R2c  = __builtin_amdgcn_mfma_f32_16x16x32_bf16(bQ, fPK, z4, 0, 0, 0);
      f32x4 R3A, R3B;
      if (PASS == 2) {
        R3A = __builtin_amdgcn_mfma_f32_16x16x32_bf16(aK, fPQf, z4, 0, 0, 0);
        R3B = __builtin_amdgcn_mfma_f32_16x16x32_bf16(aK, fPQprev, z4, 0, 0, 0);
      } else {
        R3B = __builtin_amdgcn_mfma_f32_16x16x32_bf16(aK, fPQf, z4, 0, 0, 0);
        R3A = __builtin_amdgcn_mfma_f32_16x16x32_bf16(aK, fPQprev, z4, 0, 0, 0);
      }
      fPQprev = fPQf;
      if (i < 15) {  // prefetch PP row + K fragment for tile i+1
        int pf = (PASS == 2) ? (wb + 16 * wv - (j0 + 16) + 240 + ml)
                             : (wb - 16 * wv + (j0 + 16) + 64 + ml);
        if (pf > 510) pf = 510;
        fPK  = lo ? *(const bf16x8*)&PKe[(size_t)pf * 8] : zero8;
        fPQf = lo ? *(const bf16x8*)&PQe[(size_t)pf * 8] : zero8;
        aKn = lo ? *(const bf16x8*)&Ks[j0 + 16 + ml][quad * 8] : zero8;
      }

      // ---- phase B: consume tile T with the preloaded values ----
      float pe4[4];
#pragma unroll
      for (int r = 0; r < 4; ++r) {
        const int pcol = (PASS == 2) ? (pbase - r) : (pbase + r);
        const int hi = pcol >> 4;
        float s = St_p[r] + r2v[r] + (hi ? vb[r] : va[r]);
        pe4[r] = __expf(s);
        den += pe4[r];
      }
      unsigned d0, d1;
      asm("v_cvt_pk_bf16_f32 %0, %1, %2" : "=v"(d0) : "v"(pe4[0]), "v"(pe4[1]));
      asm("v_cvt_pk_bf16_f32 %0, %1, %2" : "=v"(d1) : "v"(pe4[2]), "v"(pe4[3]));
      if ((T & 1) == 0) {
        pA0 = d0;
        pA1 = d1;
      } else {
        unsigned b0 = pA0, b2 = d0, b1 = pA1, b3 = d1;
        asm("v_permlane32_swap_b32 %0, %1" : "+v"(b0), "+v"(b2));
        asm("v_permlane16_swap_b32 %0, %1" : "+v"(b0), "+v"(b2));
        asm("v_permlane32_swap_b32 %0, %1" : "+v"(b1), "+v"(b3));
        asm("v_permlane16_swap_b32 %0, %1" : "+v"(b1), "+v"(b3));
        union { unsigned u[4]; bf16x8 v8; } bp;
        bp.u[0] = b0; bp.u[1] = b1; bp.u[2] = b2; bp.u[3] = b3;
        Ot = __builtin_amdgcn_mfma_f32_16x16x32_bf16(aVT, bp.v8, Ot, 0, 0, 0);
      }
      *(f32x4*)&R2T[wv][i & 1][ml][quad * 4] = R2c;
      St_p = St_c; R3a_p = R3A; R3b_p = R3B;
    }

    // ---- epilogue: consume tile 15 (odd -> fires the last PV) ----
    {
      const int T = 15;
      float r2v[4], va[4], vb[4];
#pragma unroll
      for (int r = 0; r < 4; ++r) {
        const int pcol = (PASS == 2) ? (pbase - r) : (pbase + r);
        const int hi = pcol >> 4;
        const int bk = (T & 1) ^ hi ^ (PASS == 1 ? 1 : 0);
        const int ba = ((pcol & 15) << 2) | qsh;
        r2v[r] = R2T[wv][bk][pcol & 15][ml];
        va[r] = __int_as_float(
            __builtin_amdgcn_ds_bpermute(ba, __float_as_int(R3a_p[r])));
        vb[r] = __int_as_float(
            __builtin_amdgcn_ds_bpermute(ba, __float_as_int(R3b_p[r])));
      }
      bf16x8 aVT = *(const bf16x8*)&VTs[ml][(T >> 1) * 32 + quad * 8];
      float pe4[4];
#pragma unroll
      for (int r = 0; r < 4; ++r) {
        const int pcol = (PASS == 2) ? (pbase - r) : (pbase + r);
        const int hi = pcol >> 4;
        float s = St_p[r] + r2v[r] + (hi ? vb[r] : va[r]);
        pe4[r] = __expf(s);
        den += pe4[r];
      }
      unsigned d0, d1;
      asm("v_cvt_pk_bf16_f32 %0, %1, %2" : "=v"(d0) : "v"(pe4[0]), "v"(pe4[1]));
      asm("v_cvt_pk_bf16_f32 %0, %1, %2" : "=v"(d1) : "v"(pe4[2]), "v"(pe4[3]));
      unsigned b0 = pA0, b2 = d0, b1 = pA1, b3 = d1;
      asm("v_permlane32_swap_b32 %0, %1" : "+v"(b0), "+v"(b2));
      asm("v_permlane16_swap_b32 %0, %1" : "+v"(b0), "+v"(b2));
      asm("v_permlane32_swap_b32 %0, %1" : "+v"(b1), "+v"(b3));
      asm("v_permlane16_swap_b32 %0, %1" : "+v"(b1), "+v"(b3));
      union { unsigned u[4]; bf16x8 v8; } bp;
      bp.u[0] = b0; bp.u[1] = b1; bp.u[2] = b2; bp.u[3] = b3;
      Ot = __builtin_amdgcn_mfma_f32_16x16x32_bf16(aVT, bp.v8, Ot, 0, 0, 0);
    }

    den += __shfl_xor(den, 16);
    den += __shfl_xor(den, 32);
    float inv = 1.f / den;
    bf16x4 ob;
    ob[0] = f2bf(Ot[0] * inv); ob[1] = f2bf(Ot[1] * inv);
    ob[2] = f2bf(Ot[2] * inv); ob[3] = f2bf(Ot[3] * inv);
    // OT[n][e][i][cc]: 16 rows x 32B = 512B contiguous per wave store
    *(bf16x4*)&OTb[(size_t)(i0p + 16 * wv + ml) * 16 + quad * 4] = ob;
  }
}

// ---------------- raw = sum_e pre-softmax scores, dense K=128 ----------------
// Round-7 structure (coalesced LDS staging + PPT reads) -- unchanged.
__global__ __launch_bounds__(256, 3) void k_raw(
    const short* __restrict__ Qf, const short* __restrict__ Kf,
    const short* __restrict__ PPT, float* __restrict__ raw) {
  __shared__ float R2s[4][2][16][17];
  __shared__ float R3s[4][16][34];
  __shared__ short QSs[64][132];
  __shared__ short KSs[64][132];
  const int t = threadIdx.x;
  const int n = blockIdx.y;
  const int lane = t & 63, wv = t >> 6;
  const int ml = lane & 15, quad = lane >> 4;
  const int itb = blockIdx.x * 64;
  const int jtb = blockIdx.z * 64;
  const int it0 = itb + wv * 16;
  const int jt0 = blockIdx.z * 4;
  const f32x4 z4 = {0.f, 0.f, 0.f, 0.f};

  // coalesced staging: Q rows itb..itb+63, K rows jtb..jtb+63 (full 128 ch)
#pragma unroll
  for (int it = 0; it < 4; ++it) {
    int idx = t + it * 256;
    int r = idx >> 4, c8 = idx & 15;
    *(bf16x8*)&QSs[r][c8 * 8] =
        *(const bf16x8*)&Qf[((size_t)(itb + r) * NBd + n) * 384 + c8 * 8];
    *(bf16x8*)&KSs[r][c8 * 8] =
        *(const bf16x8*)&Kf[((size_t)(jtb + r) * NBd + n) * 256 + c8 * 8];
  }
  __syncthreads();

  bf16x8 aQ[4];
#pragma unroll
  for (int kc = 0; kc < 4; ++kc)
    aQ[kc] = *(const bf16x8*)&QSs[wv * 16 + ml][kc * 32 + quad * 8];

  float* rbase = &raw[(((size_t)(n & 1) * HNd + (n >> 1)) * Wd + it0) * Wd];

  // PPT bases: PQ chunk = kc*4+quad, PK chunk = 16+kc*4+quad
  const short* PQb = PPT + (size_t)quad * 511 * 8;
  const short* PKb = PQb + (size_t)16 * 511 * 8;

  bf16x8 fPQprev[4];
  {
    int pp = it0 - jt0 * 16 + 256 + ml;
    if (pp > 510) pp = 510;
    f32x4 R2i = z4;
#pragma unroll
    for (int kc = 0; kc < 4; ++kc) {
      bf16x8 fPK = *(const bf16x8*)&PKb[((size_t)kc * 4 * 511 + pp) * 8];
      R2i = __builtin_amdgcn_mfma_f32_16x16x32_bf16(aQ[kc], fPK, R2i, 0, 0, 0);
      fPQprev[kc] = *(const bf16x8*)&PQb[((size_t)kc * 4 * 511 + pp) * 8];
    }
#pragma unroll
    for (int r = 0; r < 4; ++r) R2s[wv][1][quad * 4 + r][ml] = R2i[r];
  }

#pragma unroll
  for (int jq = 0; jq < 4; ++jq) {
    const int j0 = (jt0 + jq) * 16;
    bf16x8 aK[4];
#pragma unroll
    for (int kc = 0; kc < 4; ++kc)
      aK[kc] = *(const bf16x8*)&KSs[jq * 16 + ml][kc * 32 + quad * 8];
    const int p0 = it0 - j0 + 240 + ml;  // in [0,495] always
    f32x4 St = z4, R2f = z4, R3a = z4, R3b = z4;
    bf16x8 fPQ0[4];
#pragma unroll
    for (int kc = 0; kc < 4; ++kc)
      St = __builtin_amdgcn_mfma_f32_16x16x32_bf16(aQ[kc], aK[kc], St, 0, 0, 0);
#pragma unroll
    for (int kc = 0; kc < 4; ++kc) {
      bf16x8 fPK0 = *(const bf16x8*)&PKb[((size_t)kc * 4 * 511 + p0) * 8];
      R2f = __builtin_amdgcn_mfma_f32_16x16x32_bf16(aQ[kc], fPK0, R2f, 0, 0, 0);
    }
#pragma unroll
    for (int kc = 0; kc < 4; ++kc) {
      fPQ0[kc] = *(const bf16x8*)&PQb[((size_t)kc * 4 * 511 + p0) * 8];
      R3a = __builtin_amdgcn_mfma_f32_16x16x32_bf16(aK[kc], fPQ0[kc], R3a, 0, 0, 0);
    }
#pragma unroll
    for (int kc = 0; kc < 4; ++kc)
      R3b = __builtin_amdgcn_mfma_f32_16x16x32_bf16(aK[kc], fPQprev[kc], R3b, 0, 0, 0);
#pragma unroll
    for (int kc = 0; kc < 4; ++kc) fPQprev[kc] = fPQ0[kc];
#pragma unroll
    for (int r = 0; r < 4; ++r) {
      R2s[wv][jq & 1][quad * 4 + r][ml] = R2f[r];
      R3s[wv][quad * 4 + r][ml]      = R3a[r];
      R3s[wv][quad * 4 + r][ml + 16] = R3b[r];
    }
#pragma unroll
    for (int r = 0; r < 4; ++r) {
      const int il = quad * 4 + r;
      const int pcol = il - ml + 15;
      const int hi = pcol >> 4, col = pcol & 15;
      const int bk = (jq & 1) ^ hi;
      rbase[(size_t)il * Wd + j0 + ml] = St[r] + R2s[wv][bk][il][col] + R3s[wv][ml][pcol];
    }
  }
}

extern "C" void kernel_launch(void* const* d_in, const int* in_sizes, int n_in,
                              void* d_out, int out_size, void* d_ws, size_t ws_size,
                              hipStream_t stream) {
  const float* feat_l = (const float*)d_in[0];
  const float* feat_r = (const float*)d_in[1];
  const float* pos    = (const float*)d_in[2];
  // d_in[3] = pos_indexes (int) -- structure known analytically, unused.
  const float* Wqkv = (const float*)d_in[4];
  const float* bqkv = (const float*)d_in[5];
  const float* Wo   = (const float*)d_in[6];
  const float* bo   = (const float*)d_in[7];
  const float* g1   = (const float*)d_in[8];
  const float* b1   = (const float*)d_in[9];
  const float* g2   = (const float*)d_in[10];
  const float* b2   = (const float*)d_in[11];
  float* out = (float*)d_out;

  float* ws = (float*)d_ws;
  float* fl_seq = ws;                 // fp32
  float* fr_seq = ws + SEQF;          // fp32
  float* fr2_f  = ws + 2 * SEQF;      // fp32 (fr_new)
  float* fl_new = ws + 3 * SEQF;      // fp32
  short* wsb    = (short*)(ws + 4 * SEQF);
  short* fl2_b   = wsb;               // SEQF bf16
  short* fr2_b   = wsb + SEQF;
  short* frb2_b  = wsb + 2 * SEQF;
  short* QKVl_b  = wsb + 3 * SEQF;    // 3*SEQF
  short* Qr_b    = wsb + 6 * SEQF;
  short* KVr2_b  = wsb + 7 * SEQF;    // 2*SEQF
  short* O_b     = wsb + 9 * SEQF;    // OT layout [n][e][i][cc]
  short* PP_b    = wsb + 10 * SEQF;   // 511*256
  short* Wb      = PP_b + 131072;     // Wqkv (49152) then Wo (16384)
  short* pos_b   = Wb + 65536;        // 511*128
  short* PPT_b   = pos_b + 65536;     // 32*511*8 = 130816 (chunk-major PP)

  // to_seq + LN(g1,b1) fused, both tensors
  k_to_seq_ln<<<dim3(8, 256), 256, 0, stream>>>(feat_l, feat_r, fl_seq, fr_seq,
                                                fl2_b, fr2_b, g1, b1);
  k_cvt<<<256, 256, 0, stream>>>(Wqkv, Wb, Wo, Wb + 49152, pos, pos_b);

  // PP = [PQ(scaled)|PK] projections of the 511 pos rows (bf16 out)
  k_gemm_bf<<<dim3(8, 2), 256, 0, stream>>>(pos_b, Wb, bqkv, nullptr, PP_b,
                                            511, 256, 128, 0.25f,
                                            nullptr, nullptr, 0, 999);
  // repack PP into chunk-major PPT (coalesced fragment loads)
  k_ppt<<<511, 256, 0, stream>>>(PP_b, PPT_b);

  // QKV of fl2 (Q scaled) + Q of fr2 (scaled), merged
  k_gemm_bf<<<dim3(512, 4), 256, 0, stream>>>(fl2_b, Wb, bqkv, nullptr, QKVl_b,
                                              32768, 384, 128, 0.25f,
                                              fr2_b, Qr_b, 128, 3);

  // mha1: q=fr2-proj, kv=fl2-proj, flipped pos => p = j-i+255
  k_attn_mfma<1><<<dim3(128, 8, 2), 256, 0, stream>>>(
      Qr_b, Cd, QKVl_b + 128, QKVl_b + 256, 384, PPT_b, O_b);
  // fr_new = fr_seq + O @ Wo^T + bo  (+ fused LN(g2,b2) -> frb2_b)
  k_gemm_wo_ln<<<512, 256, 0, stream>>>(O_b, Wb + 49152, bo, fr_seq, fr2_f,
                                        frb2_b, g2, b2);
  // KV of frb2
  k_gemm_bf<<<dim3(512, 2), 256, 0, stream>>>(frb2_b, Wb + 16384, bqkv + 128, nullptr,
                                              KVr2_b, 32768, 256, 0, 1.0f,
                                              nullptr, nullptr, 0, 999);
  // mha2: q=fl2-proj (in QKVl), kv=frb2-proj; p = i-j+255
  k_attn_mfma<2><<<dim3(128, 8, 2), 256, 0, stream>>>(
      QKVl_b, 384, KVr2_b, KVr2_b + 128, 256, PPT_b, O_b);
  // raw = sum over heads of pre-softmax scores (dense K=128 formulation)
  k_raw<<<dim3(4, 128, 4), 256, 0, stream>>>(QKVl_b, KVr2_b, PPT_b, out + 2 * SEQF);
  // fl_new = fl_seq + O @ Wo^T + bo (no LN)
  k_gemm_wo_ln<<<512, 256, 0, stream>>>(O_b, Wb + 49152, bo, fl_seq, fl_new,
                                        nullptr, nullptr, nullptr);

  k_from_seq2<<<dim3(8, 4, 256), dim3(32, 8), 0, stream>>>(fl_new, fr2_f, out, out + SEQF);

  (void)in_sizes; (void)n_in; (void)out_size; (void)ws_size;
}